// Round 6
// baseline (1519.891 us; speedup 1.0000x reference)
//
#include <hip/hip_runtime.h>

typedef unsigned short u16;
typedef _Float16 half8 __attribute__((ext_vector_type(8)));
typedef float f32x4 __attribute__((ext_vector_type(4)));

__device__ inline float bf2f(u16 b) { return __builtin_bit_cast(float, ((unsigned)b) << 16); }
__device__ inline float h2f(u16 h) { return (float)__builtin_bit_cast(_Float16, h); }
__device__ inline u16 f2h_bits(float f) { return __builtin_bit_cast(u16, (_Float16)f); }

__device__ inline int detect_bf16(const void* caps) {
    const u16* c = (const u16*)caps;
    int cnt = 0;
#pragma unroll
    for (int k = 0; k < 4; ++k) {
        float v = bf2f(c[2 * k]);
        if (v >= 20.f && v <= 200.f) cnt++;
    }
    return cnt >= 2;
}
__device__ inline float ldin(const void* p, size_t i, int flag) {
    return flag ? bf2f(((const u16*)p)[i]) : ((const float*)p)[i];
}

#define A_SRCW 0
#define A_SRCB 131584
#define A_CANDW 132096
#define A_CANDB 263680
#define A_DEPW 264192
#define A_DEPB 395776
#define A_FEASW 396288
#define A_FEASB 396800
#define A_PW 396801
#define A_PB 397825
#define A_BO 397827
#define A_B1 400899
#define A_B2 413187
#define A_TOTAL 416259

// ---------------------------------------------------------------------------
// Direct-fragment GEMM: NO LDS, NO barriers, NO explicit waitcnt. Each wave
// loads its MFMA A/B fragments straight from global (per-row 64B, full-line
// coalesced — the same pattern flash_k uses for K/V, which sustains rate).
// Tiles are L2-resident after the XCD swizzle (~200cyc loads); waves are
// fully independent so the CU scheduler hides latency with ~20 waves/CU
// (LDS=0, ~90 VGPR). This is the decisive A/B against the barrier-synced
// LDS-staged structure whose every variant (R1-R5) measured identically.
// ---------------------------------------------------------------------------
template <int CF, int BM, int BN>
__global__ __launch_bounds__(256) void gemm_f16(
    const u16* __restrict__ A, int lda,
    const u16* __restrict__ B, int ldb,
    void* __restrict__ Cv, int ldc,
    const float* __restrict__ bias, float* __restrict__ resid,
    u16* __restrict__ vtp,
    float scale, int relu, int N, int K)
{
    constexpr int FM = BM / 32;   // 16-row A-frags per wave (2x2 wave grid)
    constexpr int FN = BN / 32;   // 16-row B-frags per wave

    // XCD-aware remap (bijective; identity if gy % 8 != 0).
    const int gx = gridDim.x, gy = gridDim.y;
    int mb, nb;
    if ((gy & 7) == 0) {
        int id = blockIdx.x + blockIdx.y * gx;
        int xcd = id & 7, local = id >> 3;
        int mloc = local / gx;
        mb = xcd * (gy >> 3) + mloc;
        nb = local - mloc * gx;
    } else {
        mb = blockIdx.y;
        nb = blockIdx.x;
    }
    const int m0 = mb * BM;
    const int n0 = nb * BN;

    const int t = threadIdx.x, lane = t & 63, wid = t >> 6;
    const int qd = lane >> 4, ml = lane & 15;
    const int wm = (wid >> 1) * (BM / 2), wn = (wid & 1) * (BN / 2);

    const u16* Aw = A + (long long)(m0 + wm + ml) * lda + qd * 8;
    const u16* Bw = B + (long long)(n0 + wn + ml) * ldb + qd * 8;

    f32x4 acc[FM][FN] = {};

#pragma unroll 2
    for (int k0 = 0; k0 < K; k0 += 32) {
        half8 af[FM], bfv[FN];
#pragma unroll
        for (int mt = 0; mt < FM; ++mt)
            af[mt] = *(const half8*)(Aw + (long long)mt * 16 * lda + k0);
#pragma unroll
        for (int nt = 0; nt < FN; ++nt)
            bfv[nt] = *(const half8*)(Bw + (long long)nt * 16 * ldb + k0);
#pragma unroll
        for (int mt = 0; mt < FM; ++mt)
#pragma unroll
            for (int nt = 0; nt < FN; ++nt)
                acc[mt][nt] = __builtin_amdgcn_mfma_f32_16x16x32_f16(af[mt], bfv[nt], acc[mt][nt], 0, 0, 0);
    }

#pragma unroll
    for (int nt = 0; nt < FN; ++nt) {
        int col = n0 + wn + nt * 16 + ml;
        if (col >= N) continue;
        float bv = bias ? bias[col] : 0.f;
#pragma unroll
        for (int mt = 0; mt < FM; ++mt) {
#pragma unroll
            for (int r = 0; r < 4; ++r) {
                int rowg = m0 + wm + mt * 16 + qd * 4 + r;
                float v = acc[mt][nt][r] * scale + bv;
                if (relu) v = fmaxf(v, 0.f);
                long long off = (long long)rowg * ldc + col;
                if (CF == 1) {
                    ((float*)Cv)[off] = v;
                } else if (CF == 2) {
                    resid[off] = v;
                    ((u16*)Cv)[off] = f2h_bits(v);
                } else if (resid) {
                    float nv = resid[off] + v;
                    resid[off] = nv;
                    ((u16*)Cv)[off] = f2h_bits(nv);
                } else if (vtp && col >= 1024) {
                    // fused V-transpose: vt[(b*8+h)][vd][s]
                    int b = rowg >> 9, s = rowg & 511;
                    int cv2 = col - 1024;
                    vtp[(size_t)(((b << 3) + (cv2 >> 6)) * 32768 + (cv2 & 63) * 512 + s)] = f2h_bits(v);
                } else {
                    ((u16*)Cv)[off] = f2h_bits(v);
                }
            }
        }
    }
}

// ---------------------------------------------------------------------------
// Fused flash attention (128-row Q-tile): per (q-tile, b*8+h) block computes
// O = softmax(Q K^T / 8) V. 4 waves x 32 Q-rows, zero barriers; setprio(1)
// around MFMA clusters (m191). XCD swizzle keeps a head's q-tiles on one XCD.
// ---------------------------------------------------------------------------
__global__ __launch_bounds__(256) void flash_k(
    const u16* __restrict__ qkv,  // [4096][1536] fp16 (q|k|v)
    const u16* __restrict__ vt,   // [64][64][512] fp16  v^T per slice
    u16* __restrict__ ob)         // [4096][512] fp16
{
    __shared__ __attribute__((aligned(16))) u16 Ps[128 * 136];

    // grid is (4, 64) fixed: id -> (z, q-tile) with same-z tiles on one XCD.
    int id = blockIdx.x + (blockIdx.y << 2);
    int xcd = id & 7, local = id >> 3;
    const int z = (xcd << 3) + (local >> 2);  // b*8 + h
    const int q0 = (local & 3) * 128;

    const int b = z >> 3, h = z & 7;
    const long long qbase = (long long)b * 786432;
    const u16* Q  = qkv + qbase + (long long)q0 * 1536 + h * 64;
    const u16* Kg = qkv + qbase + 512 + h * 64;
    const u16* Vg = vt + (long long)z * 32768;

    const int t = threadIdx.x, lane = t & 63, wid = t >> 6;
    const int qd = lane >> 4, ml = lane & 15;
    const int wm = wid * 32;

    half8 qf[2][2];
#pragma unroll
    for (int mt = 0; mt < 2; ++mt)
#pragma unroll
        for (int kf = 0; kf < 2; ++kf)
            qf[mt][kf] = *(const half8*)(Q + (long long)(wm + mt * 16 + ml) * 1536 + kf * 32 + qd * 8);

    f32x4 oacc[2][4] = {};
    float mrow[2][4], lrow[2][4];
#pragma unroll
    for (int mt = 0; mt < 2; ++mt)
#pragma unroll
        for (int r = 0; r < 4; ++r) { mrow[mt][r] = -3.0e38f; lrow[mt][r] = 0.f; }

    for (int kb = 0; kb < 4; ++kb) {
        f32x4 sacc[2][8] = {};
        __builtin_amdgcn_s_setprio(1);
#pragma unroll
        for (int nt = 0; nt < 8; ++nt) {
#pragma unroll
            for (int kf = 0; kf < 2; ++kf) {
                half8 bf = *(const half8*)(Kg + (long long)(kb * 128 + nt * 16 + ml) * 1536 + kf * 32 + qd * 8);
#pragma unroll
                for (int mt = 0; mt < 2; ++mt)
                    sacc[mt][nt] = __builtin_amdgcn_mfma_f32_16x16x32_f16(qf[mt][kf], bf, sacc[mt][nt], 0, 0, 0);
            }
        }
        __builtin_amdgcn_s_setprio(0);
#pragma unroll
        for (int mt = 0; mt < 2; ++mt) {
#pragma unroll
            for (int r = 0; r < 4; ++r) {
                float mx = -3.0e38f;
#pragma unroll
                for (int nt = 0; nt < 8; ++nt) {
                    float s = sacc[mt][nt][r] * 0.125f;
                    sacc[mt][nt][r] = s;
                    mx = fmaxf(mx, s);
                }
#pragma unroll
                for (int o = 1; o < 16; o <<= 1) mx = fmaxf(mx, __shfl_xor(mx, o, 64));
                float mnew = fmaxf(mrow[mt][r], mx);
                float alpha = __expf(mrow[mt][r] - mnew);
                mrow[mt][r] = mnew;
                lrow[mt][r] *= alpha;
#pragma unroll
                for (int nt = 0; nt < 4; ++nt) oacc[mt][nt][r] *= alpha;
                float ps = 0.f;
#pragma unroll
                for (int nt = 0; nt < 8; ++nt) {
                    float p = __expf(sacc[mt][nt][r] - mnew);
                    sacc[mt][nt][r] = p;
                    ps += p;
                }
#pragma unroll
                for (int o = 1; o < 16; o <<= 1) ps += __shfl_xor(ps, o, 64);
                lrow[mt][r] += ps;
            }
        }
#pragma unroll
        for (int mt = 0; mt < 2; ++mt)
#pragma unroll
            for (int nt = 0; nt < 8; ++nt)
#pragma unroll
                for (int r = 0; r < 4; ++r)
                    Ps[(wm + mt * 16 + qd * 4 + r) * 136 + nt * 16 + ml] = f2h_bits(sacc[mt][nt][r]);
        __builtin_amdgcn_s_setprio(1);
#pragma unroll
        for (int kf = 0; kf < 4; ++kf) {
            half8 pf[2];
#pragma unroll
            for (int mt = 0; mt < 2; ++mt)
                pf[mt] = *(const half8*)(Ps + (wm + mt * 16 + ml) * 136 + kf * 32 + qd * 8);
#pragma unroll
            for (int nt = 0; nt < 4; ++nt) {
                half8 vf = *(const half8*)(Vg + (long long)(nt * 16 + ml) * 512 + kb * 128 + kf * 32 + qd * 8);
#pragma unroll
                for (int mt = 0; mt < 2; ++mt)
                    oacc[mt][nt] = __builtin_amdgcn_mfma_f32_16x16x32_f16(pf[mt], vf, oacc[mt][nt], 0, 0, 0);
            }
        }
        __builtin_amdgcn_s_setprio(0);
    }

#pragma unroll
    for (int mt = 0; mt < 2; ++mt) {
#pragma unroll
        for (int r = 0; r < 4; ++r) {
            float inv = 1.f / lrow[mt][r];
            long long rowg = (long long)b * 512 + q0 + wm + mt * 16 + qd * 4 + r;
#pragma unroll
            for (int nt = 0; nt < 4; ++nt)
                ob[rowg * 512 + h * 64 + nt * 16 + ml] = f2h_bits(oacc[mt][nt][r] * inv);
        }
    }
}

template <int MODE>
__global__ void transpose_k(const void* __restrict__ src_, int s_ld, long long s_off,
                            long long s_so, long long s_si,
                            u16* __restrict__ dst, int d_ld, long long d_so, long long d_si,
                            int R, int Rs, int C, const void* caps)
{
    __shared__ u16 tile[32][33];
    const int z = blockIdx.z;
    const long long sb = s_off + (long long)(z >> 3) * s_so + (long long)(z & 7) * s_si;
    dst += (long long)(z >> 3) * d_so + (long long)(z & 7) * d_si;
    const int c0 = blockIdx.x * 32, r0 = blockIdx.y * 32;
    const int tx = threadIdx.x, ty = threadIdx.y;
    const int flag = (MODE == 1) ? detect_bf16(caps) : 0;
#pragma unroll
    for (int i = 0; i < 4; ++i) {
        int r = r0 + ty + i * 8, c = c0 + tx;
        if (r < R && c < C) {
            u16 v = 0;
            if (r < Rs) {
                size_t idx = (size_t)(sb + (long long)r * s_ld + c);
                if (MODE == 1) v = f2h_bits(ldin(src_, idx, flag));
                else           v = ((const u16*)src_)[idx];
            }
            tile[ty + i * 8][tx] = v;
        }
    }
    __syncthreads();
#pragma unroll
    for (int i = 0; i < 4; ++i) {
        int r = r0 + tx, c = c0 + ty + i * 8;
        if (r < R && c < C) dst[(long long)c * d_ld + r] = tile[tx][ty + i * 8];
    }
}

__global__ void qkvoT6_k(const void* Wq, const void* Wk, const void* Wv, const void* Wo,
                         u16* __restrict__ wqkvT6, u16* __restrict__ woT6,
                         const void* caps)
{
    __shared__ u16 tile[32][33];
    const int z = blockIdx.z;
    const int layer = z >> 2, sel = z & 3;
    const void* src = (sel == 0) ? Wq : (sel == 1) ? Wk : (sel == 2) ? Wv : Wo;
    u16* dst = (sel < 3) ? (wqkvT6 + (long long)layer * 786432 + (long long)sel * 262144)
                         : (woT6 + (long long)layer * 262144);
    const long long oW = (long long)layer * 262144;
    const int c0 = blockIdx.x * 32, r0 = blockIdx.y * 32;
    const int tx = threadIdx.x, ty = threadIdx.y;
    const int flag = detect_bf16(caps);
#pragma unroll
    for (int i = 0; i < 4; ++i) {
        int r = r0 + ty + i * 8, c = c0 + tx;
        tile[ty + i * 8][tx] = f2h_bits(ldin(src, (size_t)(oW + (long long)r * 512 + c), flag));
    }
    __syncthreads();
#pragma unroll
    for (int i = 0; i < 4; ++i) {
        int r = r0 + tx, c = c0 + ty + i * 8;
        dst[(long long)c * 512 + r] = tile[tx][ty + i * 8];
    }
}

__global__ void cvt_small_k(const void* srcW, const void* srcB, const void* candW, const void* candB,
                            const void* depW, const void* depB, const void* feasW, const void* feasB,
                            const void* pW, const void* pb, const void* boi, const void* b1i,
                            const void* b2i, const void* caps, float* __restrict__ dst)
{
    int i = blockIdx.x * 256 + threadIdx.x;
    if (i >= A_TOTAL) return;
    int flag = detect_bf16(caps);
    const void* s; int j;
    if      (i < A_SRCB)  { s = srcW;  j = i - A_SRCW; }
    else if (i < A_CANDW) { s = srcB;  j = i - A_SRCB; }
    else if (i < A_CANDB) { s = candW; j = i - A_CANDW; }
    else if (i < A_DEPW)  { s = candB; j = i - A_CANDB; }
    else if (i < A_DEPB)  { s = depW;  j = i - A_DEPW; }
    else if (i < A_FEASW) { s = depB;  j = i - A_DEPB; }
    else if (i < A_FEASB) { s = feasW; j = i - A_FEASW; }
    else if (i < A_PW)    { s = feasB; j = i - A_FEASB; }
    else if (i < A_PB)    { s = pW;    j = i - A_PW; }
    else if (i < A_BO)    { s = pb;    j = i - A_PB; }
    else if (i < A_B1)    { s = boi;   j = i - A_BO; }
    else if (i < A_B2)    { s = b1i;   j = i - A_B1; }
    else                  { s = b2i;   j = i - A_B2; }
    dst[i] = ldin(s, j, flag);
}

__global__ void catbias_k(const void* bq, const void* bk, const void* bv,
                          const void* caps, float* __restrict__ dst)
{
    int t = blockIdx.x * 256 + threadIdx.x;
    if (t >= 6 * 1536) return;
    int flag = detect_bf16(caps);
    int l = t / 1536, j = t - l * 1536;
    float v = (j < 512) ? ldin(bq, l * 512 + j, flag)
            : (j < 1024) ? ldin(bk, l * 512 + j - 512, flag)
                         : ldin(bv, l * 512 + j - 1024, flag);
    dst[t] = v;
}

__global__ __launch_bounds__(256) void gather_xin_k(
    const void* __restrict__ sol, const void* __restrict__ caps, const void* __restrict__ emb,
    u16* __restrict__ xin)
{
    const int row = blockIdx.x;
    const int b = row >> 9, s = row & 511;
    const int t = threadIdx.x;
    const int flag = detect_bf16(caps);
    float idxf = ldin(sol, (size_t)row * 4, flag);
    int idx = (int)(idxf + 0.5f);
    if (idx < 0) idx = 0;
    if (idx > 9999) idx = 9999;
    xin[(size_t)row * 288 + t] = f2h_bits(ldin(emb, (size_t)idx * 256 + t, flag));
    if (t < 32) {
        float v = 0.f;
        if (t == 0 && s != 0) {
            float rem = ldin(sol, ((size_t)b * 512) * 4 + 3, flag);
            float cap = ldin(caps, b, flag);
            float dem = ldin(sol, (size_t)row * 4 + 2, flag);
            v = 2.f * (dem - rem) / cap;
        }
        xin[(size_t)row * 288 + 256 + t] = f2h_bits(v);
    }
}

__global__ __launch_bounds__(256) void fixup_enc_k(
    const void* __restrict__ sol, const void* __restrict__ caps, const void* __restrict__ emb,
    const float* __restrict__ arena, float* __restrict__ xf, u16* __restrict__ xb)
{
    const int blk = blockIdx.x;
    const int b = blk & 7;
    const int s = (blk >> 3) ? 511 : 0;
    const int row = b * 512 + s;
    const int t = threadIdx.x;
    __shared__ float e[256];
    __shared__ float nds;
    const int flag = detect_bf16(caps);
    float idxf = ldin(sol, (size_t)row * 4, flag);
    int idx = (int)(idxf + 0.5f);
    if (idx < 0) idx = 0;
    if (idx > 9999) idx = 9999;
    e[t] = ldin(emb, (size_t)idx * 256 + t, flag);
    if (t == 0) {
        float rem = ldin(sol, ((size_t)b * 512) * 4 + 3, flag);
        float cap = ldin(caps, b, flag);
        float dem = ldin(sol, (size_t)row * 4 + 2, flag);
        nds = (s == 0) ? 0.f : 2.f * (dem - rem) / cap;
    }
    __syncthreads();
    const float* W  = (s == 0) ? arena + A_SRCW : arena + A_DEPW;
    const float* Bb = (s == 0) ? arena + A_SRCB : arena + A_DEPB;
    float a0 = 0.f, a1 = 0.f;
    for (int c = 0; c < 256; ++c) {
        float ev = e[c];
        a0 += ev * W[(size_t)c * 512 + t];
        a1 += ev * W[(size_t)c * 512 + t + 256];
    }
    float nd = nds;
    a0 += nd * W[256 * 512 + t] + Bb[t];
    a1 += nd * W[256 * 512 + t + 256] + Bb[t + 256];
    size_t o = (size_t)row * 512;
    xf[o + t] = a0;        xb[o + t] = f2h_bits(a0);
    xf[o + t + 256] = a1;  xb[o + t + 256] = f2h_bits(a1);
}

__global__ __launch_bounds__(256) void feas_k(const float* __restrict__ xf,
                                              const float* __restrict__ arena,
                                              float* __restrict__ out)
{
    int w = blockIdx.x * 4 + (threadIdx.x >> 6);
    if (w >= 8 * 510) return;
    int lane = threadIdx.x & 63;
    int b = w / 510, j = w - b * 510;
    const float* xr = xf + ((size_t)(b * 512 + 1 + j)) * 512;
    const float* fW = arena + A_FEASW;
    float a = 0.f;
#pragma unroll
    for (int i = 0; i < 8; ++i) { int d = lane + 64 * i; a += xr[d] * fW[d]; }
#pragma unroll
    for (int o = 1; o < 64; o <<= 1) a += __shfl_xor(a, o, 64);
    if (lane == 0) out[8160 + b * 510 + j] = a + arena[A_FEASB];
}

__global__ __launch_bounds__(256) void ptr_k(const float* __restrict__ xf,
                                             const float* __restrict__ arena,
                                             float* __restrict__ out)
{
    int w = blockIdx.x * 4 + (threadIdx.x >> 6);
    if (w >= 8 * 510) return;
    int lane = threadIdx.x & 63;
    int b = w / 510, j = w - b * 510;
    const float* xr = xf + ((size_t)(b * 512 + 1 + j)) * 512;
    const float* pWa = arena + A_PW;
    float a0 = 0.f, a1 = 0.f;
#pragma unroll
    for (int i = 0; i < 8; ++i) {
        int d = lane + 64 * i;
        float x = xr[d];
        a0 += x * pWa[d * 2];
        a1 += x * pWa[d * 2 + 1];
    }
#pragma unroll
    for (int o = 1; o < 64; o <<= 1) { a0 += __shfl_xor(a0, o, 64); a1 += __shfl_xor(a1, o, 64); }
    if (lane == 0) {
        out[(size_t)b * 1020 + j]       = a0 + arena[A_PB];
        out[(size_t)b * 1020 + 510 + j] = a1 + arena[A_PB + 1];
    }
}

extern "C" void kernel_launch(void* const* d_in, const int* in_sizes, int n_in,
                              void* d_out, int out_size, void* d_ws, size_t ws_size,
                              hipStream_t stream)
{
    const void* sol   = d_in[0];
    const void* caps  = d_in[1];
    const void* emb   = d_in[2];
    const void* srcW  = d_in[3];
    const void* srcB  = d_in[4];
    const void* candW = d_in[5];
    const void* candB = d_in[6];
    const void* depW  = d_in[7];
    const void* depB  = d_in[8];
    const void* feasW = d_in[9];
    const void* feasB = d_in[10];
    const void* Wq  = d_in[11];
    const void* bq  = d_in[12];
    const void* Wk  = d_in[13];
    const void* bk  = d_in[14];
    const void* Wv  = d_in[15];
    const void* bv  = d_in[16];
    const void* Wo  = d_in[17];
    const void* boi = d_in[18];
    // d_in[19] = s_scale: softmax shift no-op
    const void* W1  = d_in[20];
    const void* b1i = d_in[21];
    const void* W2  = d_in[22];
    const void* b2i = d_in[23];
    const void* pW  = d_in[24];
    const void* pb  = d_in[25];
    float* out = (float*)d_out;

    // workspace
    char* w = (char*)d_ws;
    float* xf    = (float*)w; w += 8388608;   // 4096x512 fp32 residual master
    u16* xb      = (u16*)w;   w += 4194304;   // 4096x512 fp16
    u16* qkvb    = (u16*)w;   w += 12582912;  // 4096x1536 fp16 (q|k|v; v region unused)
    u16* vt      = (u16*)w;   w += 4194304;   // 64x64x512 fp16 (v^T per slice)
    u16* hb      = (u16*)w;   w += 16777216;  // 4096x2048 fp16 FFN hidden
    u16* xin     = hb;                        //  ALIAS: 4096x288 fp16 encoder input
    u16* encW    = hb + 4096 * 288;           //  ALIAS: 512x288 fp16 candW^T
    u16* ob      = (u16*)w;   w += 4194304;   // 4096x512 fp16 attention out
    u16* wqkvT6  = (u16*)w;   w += 9437184;   // 6x 1536x512 fp16
    u16* woT6    = (u16*)w;   w += 3145728;   // 6x 512x512 fp16
    u16* w1T6    = (u16*)w;   w += 12582912;  // 6x 2048x512 fp16
    u16* w2T6    = (u16*)w;   w += 12582912;  // 6x 512x2048 fp16
    float* bqkvf = (float*)w; w += 36864;     // 6x1536 fp32
    float* arena = (float*)w; w += A_TOTAL * 4;

    dim3 tb(32, 8);
    cvt_small_k<<<dim3((A_TOTAL + 255) / 256), 256, 0, stream>>>(
        srcW, srcB, candW, candB, depW, depB, feasW, feasB, pW, pb, boi, b1i, b2i, caps, arena);
    catbias_k<<<dim3(36), 256, 0, stream>>>(bq, bk, bv, caps, bqkvf);

    // Weight transposes hoisted (3 dispatches).
    qkvoT6_k<<<dim3(16, 16, 24), tb, 0, stream>>>(Wq, Wk, Wv, Wo, wqkvT6, woT6, caps);
    transpose_k<1><<<dim3(64, 16, 6), tb, 0, stream>>>(W1, 2048, 0, 0, 1048576,
                                                       w1T6, 512, 0, 1048576, 512, 512, 2048, caps);
    transpose_k<1><<<dim3(16, 64, 6), tb, 0, stream>>>(W2, 512, 0, 0, 1048576,
                                                       w2T6, 2048, 0, 1048576, 2048, 2048, 512, caps);

    // Encoder via MFMA + 16-row fixup.
    gather_xin_k<<<dim3(4096), 256, 0, stream>>>(sol, caps, emb, xin);
    transpose_k<1><<<dim3(16, 9, 1), tb, 0, stream>>>(candW, 512, 0, 0, 0,
                                                      encW, 288, 0, 0, 288, 257, 512, caps);
    gemm_f16<2, 64, 64><<<dim3(8, 64), 256, 0, stream>>>(
        xin, 288, encW, 288,
        xb, 512, arena + A_CANDB, xf, nullptr, 1.f, 0, 512, 288);
    fixup_enc_k<<<dim3(16), 256, 0, stream>>>(sol, caps, emb, arena, xf, xb);

    for (int i = 0; i < 6; ++i) {
        // QKV projection; V columns stream directly into vt (fused transpose).
        gemm_f16<0, 64, 64><<<dim3(24, 64), 256, 0, stream>>>(
            xb, 512, wqkvT6 + (long long)i * 786432, 512,
            qkvb, 1536, bqkvf + i * 1536, nullptr, vt, 1.f, 0, 1536, 512);

        // Fused attention: scores+softmax+PV in one dispatch, zero barriers.
        flash_k<<<dim3(4, 64), 256, 0, stream>>>(qkvb, vt, ob);

        // Wo projection + residual into xf/xb.
        gemm_f16<0, 64, 64><<<dim3(8, 64), 256, 0, stream>>>(
            ob, 512, woT6 + (long long)i * 262144, 512,
            xb, 512, arena + A_BO + i * 512, xf, nullptr, 1.f, 0, 512, 512);
        if (i == 0)
            feas_k<<<dim3(1020), 256, 0, stream>>>(xf, arena, out);

        // FFN1 (relu) -> hb.
        gemm_f16<0, 64, 128><<<dim3(16, 64), 256, 0, stream>>>(
            xb, 512, w1T6 + (long long)i * 1048576, 512,
            hb, 2048, arena + A_B1 + i * 2048, nullptr, nullptr, 1.f, 1, 2048, 512);

        // FFN2 full-K (no split-K, no reduce kernel): bias + residual in epilogue.
        gemm_f16<0, 64, 64><<<dim3(8, 64), 256, 0, stream>>>(
            hb, 2048, w2T6 + (long long)i * 1048576, 2048,
            xb, 512, arena + A_B2 + i * 512, xf, nullptr, 1.f, 0, 512, 2048);
    }
    ptr_k<<<dim3(1020), 256, 0, stream>>>(xf, arena, out);
}

// Round 7
// 1171.511 us; speedup vs baseline: 1.2974x; 1.2974x over previous
//
#include <hip/hip_runtime.h>

typedef unsigned short u16;
typedef _Float16 half8 __attribute__((ext_vector_type(8)));
typedef float f32x4 __attribute__((ext_vector_type(4)));

__device__ inline float bf2f(u16 b) { return __builtin_bit_cast(float, ((unsigned)b) << 16); }
__device__ inline float h2f(u16 h) { return (float)__builtin_bit_cast(_Float16, h); }
__device__ inline u16 f2h_bits(float f) { return __builtin_bit_cast(u16, (_Float16)f); }

__device__ inline int detect_bf16(const void* caps) {
    const u16* c = (const u16*)caps;
    int cnt = 0;
#pragma unroll
    for (int k = 0; k < 4; ++k) {
        float v = bf2f(c[2 * k]);
        if (v >= 20.f && v <= 200.f) cnt++;
    }
    return cnt >= 2;
}
__device__ inline float ldin(const void* p, size_t i, int flag) {
    return flag ? bf2f(((const u16*)p)[i]) : ((const float*)p)[i];
}

#define GLOAD_LDS16(g, l)                                                              \
    __builtin_amdgcn_global_load_lds((__attribute__((address_space(1))) const void*)(g), \
                                     (__attribute__((address_space(3))) void*)(l), 16, 0, 0)

// Counted vmcnt wait + compiler memory fence (prevents ds_read hoisting).
template <int N>
__device__ inline void waitv() {
    if constexpr (N == 0)      asm volatile("s_waitcnt vmcnt(0)" ::: "memory");
    else if constexpr (N == 2) asm volatile("s_waitcnt vmcnt(2)" ::: "memory");
    else if constexpr (N == 3) asm volatile("s_waitcnt vmcnt(3)" ::: "memory");
    else if constexpr (N == 4) asm volatile("s_waitcnt vmcnt(4)" ::: "memory");
    else if constexpr (N == 6) asm volatile("s_waitcnt vmcnt(6)" ::: "memory");
    else if constexpr (N == 8) asm volatile("s_waitcnt vmcnt(8)" ::: "memory");
}
__device__ inline void barrier_raw() {
    asm volatile("" ::: "memory");
    __builtin_amdgcn_s_barrier();
    asm volatile("" ::: "memory");
}

#define A_SRCW 0
#define A_SRCB 131584
#define A_CANDW 132096
#define A_CANDB 263680
#define A_DEPW 264192
#define A_DEPB 395776
#define A_FEASW 396288
#define A_FEASB 396800
#define A_PW 396801
#define A_PB 397825
#define A_BO 397827
#define A_B1 400899
#define A_B2 413187
#define A_TOTAL 416259

// ---------------------------------------------------------------------------
// GEMM, BM x BN = 128 x 128. Model (validated across R1-R6): kernel time ==
// staged_bytes/1KB x ~90cyc / 256 CU, i.e. global_load_lds DMA-instruction
// throughput bound. Staged bytes = 2*M*N*K*(1/BM + 1/BN) -> doubling both
// tile dims halves the DMA-instruction count per FLOP. Pipeline unchanged
// from R5: XCD-locality swizzle, 4-buffer depth-2 prefetch, counted vmcnt,
// single raw barrier per K-step, both-sides LDS chunk swizzle.
// ---------------------------------------------------------------------------
template <int CF, int BM, int BN>
__global__ __launch_bounds__(256) void gemm_f16(
    const u16* __restrict__ A, int lda,
    const u16* __restrict__ B, int ldb,
    void* __restrict__ Cv, int ldc,
    const float* __restrict__ bias, float* __restrict__ resid,
    u16* __restrict__ vtp,
    float scale, int relu, int N, int K)
{
    constexpr int MT = BM / 32;             // A-frags per wave (2x2 wave grid)
    constexpr int NT = BN / 32;             // B-frags per wave
    constexpr int S = BM / 64 + BN / 64;    // VMEM instrs per stage per wave
    __shared__ __attribute__((aligned(16))) u16 As[4][BM * 32];
    __shared__ __attribute__((aligned(16))) u16 Bs[4][BN * 32];

    // XCD-aware remap (bijective; falls back to identity if gy % 8 != 0).
    const int gx = gridDim.x, gy = gridDim.y;
    int mb, nb;
    if ((gy & 7) == 0) {
        int id = blockIdx.x + blockIdx.y * gx;
        int xcd = id & 7, local = id >> 3;
        int mloc = local / gx;
        mb = xcd * (gy >> 3) + mloc;
        nb = local - mloc * gx;
    } else {
        mb = blockIdx.y;
        nb = blockIdx.x;
    }
    const int m0 = mb * BM;
    const int n0 = nb * BN;

    const int t = threadIdx.x, lane = t & 63, wid = t >> 6;
    const int qd = lane >> 4, ml = lane & 15;
    const int wm = (wid >> 1) * (BM / 2), wn = (wid & 1) * (BN / 2);
    const int cs = (qd ^ (ml & 3)) * 8;  // swizzled read chunk (row&3 == ml&3)

    f32x4 acc[MT][NT] = {};

    auto stage = [&](int bf, int k0) {
#pragma unroll
        for (int r = 0; r < BM / 64; ++r) {
            int seg = r * 256 + t;
            int row = seg >> 2;
            int c8 = (((seg & 3) ^ (row & 3)) * 8);  // source-side swizzle
            const u16* ga = A + (long long)(m0 + row) * lda + k0 + c8;
            GLOAD_LDS16(ga, As[bf] + (size_t)(seg & ~63) * 8);
        }
#pragma unroll
        for (int r = 0; r < BN / 64; ++r) {
            int seg = r * 256 + t;
            int row = seg >> 2;
            int c8 = (((seg & 3) ^ (row & 3)) * 8);
            int rn = n0 + row;
            if (rn > N - 1) rn = N - 1;
            const u16* gb = B + (long long)rn * ldb + k0 + c8;
            GLOAD_LDS16(gb, Bs[bf] + (size_t)(seg & ~63) * 8);
        }
    };

    auto compute = [&](int bf) {
        half8 af[MT], bfv[NT];
#pragma unroll
        for (int mt = 0; mt < MT; ++mt)
            af[mt] = *(const half8*)(As[bf] + (wm + mt * 16 + ml) * 32 + cs);
#pragma unroll
        for (int nt = 0; nt < NT; ++nt)
            bfv[nt] = *(const half8*)(Bs[bf] + (wn + nt * 16 + ml) * 32 + cs);
#pragma unroll
        for (int mt = 0; mt < MT; ++mt)
#pragma unroll
            for (int nt = 0; nt < NT; ++nt)
                acc[mt][nt] = __builtin_amdgcn_mfma_f32_16x16x32_f16(af[mt], bfv[nt], acc[mt][nt], 0, 0, 0);
    };

    // Prologue: fill first two buffers.
    stage(0, 0);
    if (K > 32) stage(1, 32);

    int buf = 0, k0 = 0;
    // Main: depth-2 prefetch, counted vmcnt, one barrier per step.
    for (; k0 + 64 < K; k0 += 32) {
        stage((buf + 2) & 3, k0 + 64);
        waitv<2 * S>();
        barrier_raw();
        compute(buf);
        buf = (buf + 1) & 3;
    }
    if (k0 + 32 < K) {  // second-to-last tile (one stage still in flight)
        waitv<S>();
        barrier_raw();
        compute(buf);
        buf = (buf + 1) & 3;
        k0 += 32;
    }
    waitv<0>();
    barrier_raw();
    compute(buf);

#pragma unroll
    for (int nt = 0; nt < NT; ++nt) {
        int col = n0 + wn + nt * 16 + ml;
        if (col >= N) continue;
        float bv = bias ? bias[col] : 0.f;
#pragma unroll
        for (int mt = 0; mt < MT; ++mt) {
#pragma unroll
            for (int r = 0; r < 4; ++r) {
                int rowg = m0 + wm + mt * 16 + qd * 4 + r;
                float v = acc[mt][nt][r] * scale + bv;
                if (relu) v = fmaxf(v, 0.f);
                long long off = (long long)rowg * ldc + col;
                if (CF == 1) {
                    ((float*)Cv)[off] = v;
                } else if (CF == 2) {
                    resid[off] = v;
                    ((u16*)Cv)[off] = f2h_bits(v);
                } else if (resid) {
                    float nv = resid[off] + v;
                    resid[off] = nv;
                    ((u16*)Cv)[off] = f2h_bits(nv);
                } else if (vtp && col >= 1024) {
                    // fused V-transpose: vt[(b*8+h)][vd][s]
                    int b = rowg >> 9, s = rowg & 511;
                    int cv2 = col - 1024;
                    vtp[(size_t)(((b << 3) + (cv2 >> 6)) * 32768 + (cv2 & 63) * 512 + s)] = f2h_bits(v);
                } else {
                    ((u16*)Cv)[off] = f2h_bits(v);
                }
            }
        }
    }
}

// ---------------------------------------------------------------------------
// Fused flash attention (128-row Q-tile): per (q-tile, b*8+h) block computes
// O = softmax(Q K^T / 8) V. 4 waves x 32 Q-rows, zero barriers; setprio(1)
// around MFMA clusters (m191). XCD swizzle keeps a head's q-tiles on one XCD.
// ---------------------------------------------------------------------------
__global__ __launch_bounds__(256) void flash_k(
    const u16* __restrict__ qkv,  // [4096][1536] fp16 (q|k|v)
    const u16* __restrict__ vt,   // [64][64][512] fp16  v^T per slice
    u16* __restrict__ ob)         // [4096][512] fp16
{
    __shared__ __attribute__((aligned(16))) u16 Ps[128 * 136];

    // grid is (4, 64) fixed: id -> (z, q-tile) with same-z tiles on one XCD.
    int id = blockIdx.x + (blockIdx.y << 2);
    int xcd = id & 7, local = id >> 3;
    const int z = (xcd << 3) + (local >> 2);  // b*8 + h
    const int q0 = (local & 3) * 128;

    const int b = z >> 3, h = z & 7;
    const long long qbase = (long long)b * 786432;
    const u16* Q  = qkv + qbase + (long long)q0 * 1536 + h * 64;
    const u16* Kg = qkv + qbase + 512 + h * 64;
    const u16* Vg = vt + (long long)z * 32768;

    const int t = threadIdx.x, lane = t & 63, wid = t >> 6;
    const int qd = lane >> 4, ml = lane & 15;
    const int wm = wid * 32;

    half8 qf[2][2];
#pragma unroll
    for (int mt = 0; mt < 2; ++mt)
#pragma unroll
        for (int kf = 0; kf < 2; ++kf)
            qf[mt][kf] = *(const half8*)(Q + (long long)(wm + mt * 16 + ml) * 1536 + kf * 32 + qd * 8);

    f32x4 oacc[2][4] = {};
    float mrow[2][4], lrow[2][4];
#pragma unroll
    for (int mt = 0; mt < 2; ++mt)
#pragma unroll
        for (int r = 0; r < 4; ++r) { mrow[mt][r] = -3.0e38f; lrow[mt][r] = 0.f; }

    for (int kb = 0; kb < 4; ++kb) {
        f32x4 sacc[2][8] = {};
        __builtin_amdgcn_s_setprio(1);
#pragma unroll
        for (int nt = 0; nt < 8; ++nt) {
#pragma unroll
            for (int kf = 0; kf < 2; ++kf) {
                half8 bf = *(const half8*)(Kg + (long long)(kb * 128 + nt * 16 + ml) * 1536 + kf * 32 + qd * 8);
#pragma unroll
                for (int mt = 0; mt < 2; ++mt)
                    sacc[mt][nt] = __builtin_amdgcn_mfma_f32_16x16x32_f16(qf[mt][kf], bf, sacc[mt][nt], 0, 0, 0);
            }
        }
        __builtin_amdgcn_s_setprio(0);
#pragma unroll
        for (int mt = 0; mt < 2; ++mt) {
#pragma unroll
            for (int r = 0; r < 4; ++r) {
                float mx = -3.0e38f;
#pragma unroll
                for (int nt = 0; nt < 8; ++nt) {
                    float s = sacc[mt][nt][r] * 0.125f;
                    sacc[mt][nt][r] = s;
                    mx = fmaxf(mx, s);
                }
#pragma unroll
                for (int o = 1; o < 16; o <<= 1) mx = fmaxf(mx, __shfl_xor(mx, o, 64));
                float mnew = fmaxf(mrow[mt][r], mx);
                float alpha = __expf(mrow[mt][r] - mnew);
                mrow[mt][r] = mnew;
                lrow[mt][r] *= alpha;
#pragma unroll
                for (int nt = 0; nt < 4; ++nt) oacc[mt][nt][r] *= alpha;
                float ps = 0.f;
#pragma unroll
                for (int nt = 0; nt < 8; ++nt) {
                    float p = __expf(sacc[mt][nt][r] - mnew);
                    sacc[mt][nt][r] = p;
                    ps += p;
                }
#pragma unroll
                for (int o = 1; o < 16; o <<= 1) ps += __shfl_xor(ps, o, 64);
                lrow[mt][r] += ps;
            }
        }
#pragma unroll
        for (int mt = 0; mt < 2; ++mt)
#pragma unroll
            for (int nt = 0; nt < 8; ++nt)
#pragma unroll
                for (int r = 0; r < 4; ++r)
                    Ps[(wm + mt * 16 + qd * 4 + r) * 136 + nt * 16 + ml] = f2h_bits(sacc[mt][nt][r]);
        __builtin_amdgcn_s_setprio(1);
#pragma unroll
        for (int kf = 0; kf < 4; ++kf) {
            half8 pf[2];
#pragma unroll
            for (int mt = 0; mt < 2; ++mt)
                pf[mt] = *(const half8*)(Ps + (wm + mt * 16 + ml) * 136 + kf * 32 + qd * 8);
#pragma unroll
            for (int nt = 0; nt < 4; ++nt) {
                half8 vf = *(const half8*)(Vg + (long long)(nt * 16 + ml) * 512 + kb * 128 + kf * 32 + qd * 8);
#pragma unroll
                for (int mt = 0; mt < 2; ++mt)
                    oacc[mt][nt] = __builtin_amdgcn_mfma_f32_16x16x32_f16(pf[mt], vf, oacc[mt][nt], 0, 0, 0);
            }
        }
        __builtin_amdgcn_s_setprio(0);
    }

#pragma unroll
    for (int mt = 0; mt < 2; ++mt) {
#pragma unroll
        for (int r = 0; r < 4; ++r) {
            float inv = 1.f / lrow[mt][r];
            long long rowg = (long long)b * 512 + q0 + wm + mt * 16 + qd * 4 + r;
#pragma unroll
            for (int nt = 0; nt < 4; ++nt)
                ob[rowg * 512 + h * 64 + nt * 16 + ml] = f2h_bits(oacc[mt][nt][r] * inv);
        }
    }
}

template <int MODE>
__global__ void transpose_k(const void* __restrict__ src_, int s_ld, long long s_off,
                            long long s_so, long long s_si,
                            u16* __restrict__ dst, int d_ld, long long d_so, long long d_si,
                            int R, int Rs, int C, const void* caps)
{
    __shared__ u16 tile[32][33];
    const int z = blockIdx.z;
    const long long sb = s_off + (long long)(z >> 3) * s_so + (long long)(z & 7) * s_si;
    dst += (long long)(z >> 3) * d_so + (long long)(z & 7) * d_si;
    const int c0 = blockIdx.x * 32, r0 = blockIdx.y * 32;
    const int tx = threadIdx.x, ty = threadIdx.y;
    const int flag = (MODE == 1) ? detect_bf16(caps) : 0;
#pragma unroll
    for (int i = 0; i < 4; ++i) {
        int r = r0 + ty + i * 8, c = c0 + tx;
        if (r < R && c < C) {
            u16 v = 0;
            if (r < Rs) {
                size_t idx = (size_t)(sb + (long long)r * s_ld + c);
                if (MODE == 1) v = f2h_bits(ldin(src_, idx, flag));
                else           v = ((const u16*)src_)[idx];
            }
            tile[ty + i * 8][tx] = v;
        }
    }
    __syncthreads();
#pragma unroll
    for (int i = 0; i < 4; ++i) {
        int r = r0 + tx, c = c0 + ty + i * 8;
        if (r < R && c < C) dst[(long long)c * d_ld + r] = tile[tx][ty + i * 8];
    }
}

__global__ void qkvoT6_k(const void* Wq, const void* Wk, const void* Wv, const void* Wo,
                         u16* __restrict__ wqkvT6, u16* __restrict__ woT6,
                         const void* caps)
{
    __shared__ u16 tile[32][33];
    const int z = blockIdx.z;
    const int layer = z >> 2, sel = z & 3;
    const void* src = (sel == 0) ? Wq : (sel == 1) ? Wk : (sel == 2) ? Wv : Wo;
    u16* dst = (sel < 3) ? (wqkvT6 + (long long)layer * 786432 + (long long)sel * 262144)
                         : (woT6 + (long long)layer * 262144);
    const long long oW = (long long)layer * 262144;
    const int c0 = blockIdx.x * 32, r0 = blockIdx.y * 32;
    const int tx = threadIdx.x, ty = threadIdx.y;
    const int flag = detect_bf16(caps);
#pragma unroll
    for (int i = 0; i < 4; ++i) {
        int r = r0 + ty + i * 8, c = c0 + tx;
        tile[ty + i * 8][tx] = f2h_bits(ldin(src, (size_t)(oW + (long long)r * 512 + c), flag));
    }
    __syncthreads();
#pragma unroll
    for (int i = 0; i < 4; ++i) {
        int r = r0 + tx, c = c0 + ty + i * 8;
        dst[(long long)c * 512 + r] = tile[tx][ty + i * 8];
    }
}

__global__ void cvt_small_k(const void* srcW, const void* srcB, const void* candW, const void* candB,
                            const void* depW, const void* depB, const void* feasW, const void* feasB,
                            const void* pW, const void* pb, const void* boi, const void* b1i,
                            const void* b2i, const void* caps, float* __restrict__ dst)
{
    int i = blockIdx.x * 256 + threadIdx.x;
    if (i >= A_TOTAL) return;
    int flag = detect_bf16(caps);
    const void* s; int j;
    if      (i < A_SRCB)  { s = srcW;  j = i - A_SRCW; }
    else if (i < A_CANDW) { s = srcB;  j = i - A_SRCB; }
    else if (i < A_CANDB) { s = candW; j = i - A_CANDW; }
    else if (i < A_DEPW)  { s = candB; j = i - A_CANDB; }
    else if (i < A_DEPB)  { s = depW;  j = i - A_DEPW; }
    else if (i < A_FEASW) { s = depB;  j = i - A_DEPB; }
    else if (i < A_FEASB) { s = feasW; j = i - A_FEASW; }
    else if (i < A_PW)    { s = feasB; j = i - A_FEASB; }
    else if (i < A_PB)    { s = pW;    j = i - A_PW; }
    else if (i < A_BO)    { s = pb;    j = i - A_PB; }
    else if (i < A_B1)    { s = boi;   j = i - A_BO; }
    else if (i < A_B2)    { s = b1i;   j = i - A_B1; }
    else                  { s = b2i;   j = i - A_B2; }
    dst[i] = ldin(s, j, flag);
}

__global__ void catbias_k(const void* bq, const void* bk, const void* bv,
                          const void* caps, float* __restrict__ dst)
{
    int t = blockIdx.x * 256 + threadIdx.x;
    if (t >= 6 * 1536) return;
    int flag = detect_bf16(caps);
    int l = t / 1536, j = t - l * 1536;
    float v = (j < 512) ? ldin(bq, l * 512 + j, flag)
            : (j < 1024) ? ldin(bk, l * 512 + j - 512, flag)
                         : ldin(bv, l * 512 + j - 1024, flag);
    dst[t] = v;
}

__global__ __launch_bounds__(256) void gather_xin_k(
    const void* __restrict__ sol, const void* __restrict__ caps, const void* __restrict__ emb,
    u16* __restrict__ xin)
{
    const int row = blockIdx.x;
    const int b = row >> 9, s = row & 511;
    const int t = threadIdx.x;
    const int flag = detect_bf16(caps);
    float idxf = ldin(sol, (size_t)row * 4, flag);
    int idx = (int)(idxf + 0.5f);
    if (idx < 0) idx = 0;
    if (idx > 9999) idx = 9999;
    xin[(size_t)row * 288 + t] = f2h_bits(ldin(emb, (size_t)idx * 256 + t, flag));
    if (t < 32) {
        float v = 0.f;
        if (t == 0 && s != 0) {
            float rem = ldin(sol, ((size_t)b * 512) * 4 + 3, flag);
            float cap = ldin(caps, b, flag);
            float dem = ldin(sol, (size_t)row * 4 + 2, flag);
            v = 2.f * (dem - rem) / cap;
        }
        xin[(size_t)row * 288 + 256 + t] = f2h_bits(v);
    }
}

__global__ __launch_bounds__(256) void fixup_enc_k(
    const void* __restrict__ sol, const void* __restrict__ caps, const void* __restrict__ emb,
    const float* __restrict__ arena, float* __restrict__ xf, u16* __restrict__ xb)
{
    const int blk = blockIdx.x;
    const int b = blk & 7;
    const int s = (blk >> 3) ? 511 : 0;
    const int row = b * 512 + s;
    const int t = threadIdx.x;
    __shared__ float e[256];
    __shared__ float nds;
    const int flag = detect_bf16(caps);
    float idxf = ldin(sol, (size_t)row * 4, flag);
    int idx = (int)(idxf + 0.5f);
    if (idx < 0) idx = 0;
    if (idx > 9999) idx = 9999;
    e[t] = ldin(emb, (size_t)idx * 256 + t, flag);
    if (t == 0) {
        float rem = ldin(sol, ((size_t)b * 512) * 4 + 3, flag);
        float cap = ldin(caps, b, flag);
        float dem = ldin(sol, (size_t)row * 4 + 2, flag);
        nds = (s == 0) ? 0.f : 2.f * (dem - rem) / cap;
    }
    __syncthreads();
    const float* W  = (s == 0) ? arena + A_SRCW : arena + A_DEPW;
    const float* Bb = (s == 0) ? arena + A_SRCB : arena + A_DEPB;
    float a0 = 0.f, a1 = 0.f;
    for (int c = 0; c < 256; ++c) {
        float ev = e[c];
        a0 += ev * W[(size_t)c * 512 + t];
        a1 += ev * W[(size_t)c * 512 + t + 256];
    }
    float nd = nds;
    a0 += nd * W[256 * 512 + t] + Bb[t];
    a1 += nd * W[256 * 512 + t + 256] + Bb[t + 256];
    size_t o = (size_t)row * 512;
    xf[o + t] = a0;        xb[o + t] = f2h_bits(a0);
    xf[o + t + 256] = a1;  xb[o + t + 256] = f2h_bits(a1);
}

__global__ __launch_bounds__(256) void feas_k(const float* __restrict__ xf,
                                              const float* __restrict__ arena,
                                              float* __restrict__ out)
{
    int w = blockIdx.x * 4 + (threadIdx.x >> 6);
    if (w >= 8 * 510) return;
    int lane = threadIdx.x & 63;
    int b = w / 510, j = w - b * 510;
    const float* xr = xf + ((size_t)(b * 512 + 1 + j)) * 512;
    const float* fW = arena + A_FEASW;
    float a = 0.f;
#pragma unroll
    for (int i = 0; i < 8; ++i) { int d = lane + 64 * i; a += xr[d] * fW[d]; }
#pragma unroll
    for (int o = 1; o < 64; o <<= 1) a += __shfl_xor(a, o, 64);
    if (lane == 0) out[8160 + b * 510 + j] = a + arena[A_FEASB];
}

__global__ __launch_bounds__(256) void ptr_k(const float* __restrict__ xf,
                                             const float* __restrict__ arena,
                                             float* __restrict__ out)
{
    int w = blockIdx.x * 4 + (threadIdx.x >> 6);
    if (w >= 8 * 510) return;
    int lane = threadIdx.x & 63;
    int b = w / 510, j = w - b * 510;
    const float* xr = xf + ((size_t)(b * 512 + 1 + j)) * 512;
    const float* pWa = arena + A_PW;
    float a0 = 0.f, a1 = 0.f;
#pragma unroll
    for (int i = 0; i < 8; ++i) {
        int d = lane + 64 * i;
        float x = xr[d];
        a0 += x * pWa[d * 2];
        a1 += x * pWa[d * 2 + 1];
    }
#pragma unroll
    for (int o = 1; o < 64; o <<= 1) { a0 += __shfl_xor(a0, o, 64); a1 += __shfl_xor(a1, o, 64); }
    if (lane == 0) {
        out[(size_t)b * 1020 + j]       = a0 + arena[A_PB];
        out[(size_t)b * 1020 + 510 + j] = a1 + arena[A_PB + 1];
    }
}

extern "C" void kernel_launch(void* const* d_in, const int* in_sizes, int n_in,
                              void* d_out, int out_size, void* d_ws, size_t ws_size,
                              hipStream_t stream)
{
    const void* sol   = d_in[0];
    const void* caps  = d_in[1];
    const void* emb   = d_in[2];
    const void* srcW  = d_in[3];
    const void* srcB  = d_in[4];
    const void* candW = d_in[5];
    const void* candB = d_in[6];
    const void* depW  = d_in[7];
    const void* depB  = d_in[8];
    const void* feasW = d_in[9];
    const void* feasB = d_in[10];
    const void* Wq  = d_in[11];
    const void* bq  = d_in[12];
    const void* Wk  = d_in[13];
    const void* bk  = d_in[14];
    const void* Wv  = d_in[15];
    const void* bv  = d_in[16];
    const void* Wo  = d_in[17];
    const void* boi = d_in[18];
    // d_in[19] = s_scale: softmax shift no-op
    const void* W1  = d_in[20];
    const void* b1i = d_in[21];
    const void* W2  = d_in[22];
    const void* b2i = d_in[23];
    const void* pW  = d_in[24];
    const void* pb  = d_in[25];
    float* out = (float*)d_out;

    // workspace
    char* w = (char*)d_ws;
    float* xf    = (float*)w; w += 8388608;   // 4096x512 fp32 residual master
    u16* xb      = (u16*)w;   w += 4194304;   // 4096x512 fp16
    u16* qkvb    = (u16*)w;   w += 12582912;  // 4096x1536 fp16 (q|k|v; v region unused)
    u16* vt      = (u16*)w;   w += 4194304;   // 64x64x512 fp16 (v^T per slice)
    u16* hb      = (u16*)w;   w += 16777216;  // 4096x2048 fp16 FFN hidden
    u16* xin     = hb;                        //  ALIAS: 4096x288 fp16 encoder input
    u16* encW    = hb + 4096 * 288;           //  ALIAS: 512x288 fp16 candW^T
    u16* ob      = (u16*)w;   w += 4194304;   // 4096x512 fp16 attention out
    u16* wqkvT6  = (u16*)w;   w += 9437184;   // 6x 1536x512 fp16
    u16* woT6    = (u16*)w;   w += 3145728;   // 6x 512x512 fp16
    u16* w1T6    = (u16*)w;   w += 12582912;  // 6x 2048x512 fp16
    u16* w2T6    = (u16*)w;   w += 12582912;  // 6x 512x2048 fp16
    float* bqkvf = (float*)w; w += 36864;     // 6x1536 fp32
    float* arena = (float*)w; w += A_TOTAL * 4;

    dim3 tb(32, 8);
    cvt_small_k<<<dim3((A_TOTAL + 255) / 256), 256, 0, stream>>>(
        srcW, srcB, candW, candB, depW, depB, feasW, feasB, pW, pb, boi, b1i, b2i, caps, arena);
    catbias_k<<<dim3(36), 256, 0, stream>>>(bq, bk, bv, caps, bqkvf);

    // Weight transposes hoisted (3 dispatches).
    qkvoT6_k<<<dim3(16, 16, 24), tb, 0, stream>>>(Wq, Wk, Wv, Wo, wqkvT6, woT6, caps);
    transpose_k<1><<<dim3(64, 16, 6), tb, 0, stream>>>(W1, 2048, 0, 0, 1048576,
                                                       w1T6, 512, 0, 1048576, 512, 512, 2048, caps);
    transpose_k<1><<<dim3(16, 64, 6), tb, 0, stream>>>(W2, 512, 0, 0, 1048576,
                                                       w2T6, 2048, 0, 1048576, 2048, 2048, 512, caps);

    // Encoder via MFMA + 16-row fixup.
    gather_xin_k<<<dim3(4096), 256, 0, stream>>>(sol, caps, emb, xin);
    transpose_k<1><<<dim3(16, 9, 1), tb, 0, stream>>>(candW, 512, 0, 0, 0,
                                                      encW, 288, 0, 0, 288, 257, 512, caps);
    gemm_f16<2, 128, 128><<<dim3(4, 32), 256, 0, stream>>>(
        xin, 288, encW, 288,
        xb, 512, arena + A_CANDB, xf, nullptr, 1.f, 0, 512, 288);
    fixup_enc_k<<<dim3(16), 256, 0, stream>>>(sol, caps, emb, arena, xf, xb);

    for (int i = 0; i < 6; ++i) {
        // QKV projection; V columns stream directly into vt (fused transpose).
        gemm_f16<0, 128, 128><<<dim3(12, 32), 256, 0, stream>>>(
            xb, 512, wqkvT6 + (long long)i * 786432, 512,
            qkvb, 1536, bqkvf + i * 1536, nullptr, vt, 1.f, 0, 1536, 512);

        // Fused attention: scores+softmax+PV in one dispatch, zero barriers.
        flash_k<<<dim3(4, 64), 256, 0, stream>>>(qkvb, vt, ob);

        // Wo projection + residual into xf/xb.
        gemm_f16<0, 128, 128><<<dim3(4, 32), 256, 0, stream>>>(
            ob, 512, woT6 + (long long)i * 262144, 512,
            xb, 512, arena + A_BO + i * 512, xf, nullptr, 1.f, 0, 512, 512);
        if (i == 0)
            feas_k<<<dim3(1020), 256, 0, stream>>>(xf, arena, out);

        // FFN1 (relu) -> hb.
        gemm_f16<0, 128, 128><<<dim3(16, 32), 256, 0, stream>>>(
            xb, 512, w1T6 + (long long)i * 1048576, 512,
            hb, 2048, arena + A_B1 + i * 2048, nullptr, nullptr, 1.f, 1, 2048, 512);

        // FFN2 full-K (no split-K, no reduce kernel): bias + residual in epilogue.
        gemm_f16<0, 128, 128><<<dim3(4, 32), 256, 0, stream>>>(
            hb, 2048, w2T6 + (long long)i * 1048576, 2048,
            xb, 512, arena + A_B2 + i * 512, xf, nullptr, 1.f, 0, 512, 2048);
    }
    ptr_k<<<dim3(1020), 256, 0, stream>>>(xf, arena, out);
}

// Round 8
// 901.937 us; speedup vs baseline: 1.6851x; 1.2989x over previous
//
#include <hip/hip_runtime.h>

typedef unsigned short u16;
typedef _Float16 half8 __attribute__((ext_vector_type(8)));
typedef float f32x4 __attribute__((ext_vector_type(4)));

__device__ inline float bf2f(u16 b) { return __builtin_bit_cast(float, ((unsigned)b) << 16); }
__device__ inline float h2f(u16 h) { return (float)__builtin_bit_cast(_Float16, h); }
__device__ inline u16 f2h_bits(float f) { return __builtin_bit_cast(u16, (_Float16)f); }

__device__ inline int detect_bf16(const void* caps) {
    const u16* c = (const u16*)caps;
    int cnt = 0;
#pragma unroll
    for (int k = 0; k < 4; ++k) {
        float v = bf2f(c[2 * k]);
        if (v >= 20.f && v <= 200.f) cnt++;
    }
    return cnt >= 2;
}
__device__ inline float ldin(const void* p, size_t i, int flag) {
    return flag ? bf2f(((const u16*)p)[i]) : ((const float*)p)[i];
}

#define GLOAD_LDS16(g, l)                                                              \
    __builtin_amdgcn_global_load_lds((__attribute__((address_space(1))) const void*)(g), \
                                     (__attribute__((address_space(3))) void*)(l), 16, 0, 0)

// Counted vmcnt wait + compiler memory fence (prevents ds_read hoisting).
template <int N>
__device__ inline void waitv() {
    if constexpr (N == 0)       asm volatile("s_waitcnt vmcnt(0)" ::: "memory");
    else if constexpr (N == 2)  asm volatile("s_waitcnt vmcnt(2)" ::: "memory");
    else if constexpr (N == 4)  asm volatile("s_waitcnt vmcnt(4)" ::: "memory");
    else if constexpr (N == 6)  asm volatile("s_waitcnt vmcnt(6)" ::: "memory");
    else if constexpr (N == 8)  asm volatile("s_waitcnt vmcnt(8)" ::: "memory");
    else if constexpr (N == 12) asm volatile("s_waitcnt vmcnt(12)" ::: "memory");
}
__device__ inline void barrier_raw() {
    asm volatile("" ::: "memory");
    __builtin_amdgcn_s_barrier();
    asm volatile("" ::: "memory");
}

#define A_SRCW 0
#define A_SRCB 131584
#define A_CANDW 132096
#define A_CANDB 263680
#define A_DEPW 264192
#define A_DEPB 395776
#define A_FEASW 396288
#define A_FEASB 396800
#define A_PW 396801
#define A_PB 397825
#define A_BO 397827
#define A_B1 400899
#define A_B2 413187
#define A_TOTAL 416259

// ---------------------------------------------------------------------------
// GEMM with templated BM x BN x BK. Empirical law (R5/R7/m97): each K-step
// has a fixed ~750-cycle floor when >=2 blocks are resident per CU (~2000 if
// only 1), INDEPENDENT of per-step work. So: maximize work per step (big BK)
// subject to LDS <= 64KB (2 resident) and grid >= 512 WGs. 4-buffer depth-2
// prefetch, counted vmcnt, one raw barrier per step, XCD-locality swizzle,
// both-sides chunk swizzle (chunk ^= row & (BK/8-1)) to keep ds_read_b128 at
// 2-way bank conflicts for the 128B-row-stride BK=64 layout.
// ---------------------------------------------------------------------------
template <int CF, int BM, int BN, int BK>
__global__ __launch_bounds__(256) void gemm_f16(
    const u16* __restrict__ A, int lda,
    const u16* __restrict__ B, int ldb,
    void* __restrict__ Cv, int ldc,
    const float* __restrict__ bias, float* __restrict__ resid,
    u16* __restrict__ vtp,
    float scale, int relu, int N, int K)
{
    constexpr int MT = BM / 32;                    // A-frags per wave (2x2 wave grid)
    constexpr int NT = BN / 32;                    // B-frags per wave
    constexpr int CPR = BK / 8;                    // 16B chunks per row
    constexpr int S = (BM / 64 + BN / 64) * (BK / 32);  // VMEM instrs per stage per wave
    __shared__ __attribute__((aligned(16))) u16 As[4][BM * BK];
    __shared__ __attribute__((aligned(16))) u16 Bs[4][BN * BK];

    // XCD-aware remap (bijective; falls back to identity if gy % 8 != 0).
    const int gx = gridDim.x, gy = gridDim.y;
    int mb, nb;
    if ((gy & 7) == 0) {
        int id = blockIdx.x + blockIdx.y * gx;
        int xcd = id & 7, local = id >> 3;
        int mloc = local / gx;
        mb = xcd * (gy >> 3) + mloc;
        nb = local - mloc * gx;
    } else {
        mb = blockIdx.y;
        nb = blockIdx.x;
    }
    const int m0 = mb * BM;
    const int n0 = nb * BN;

    const int t = threadIdx.x, lane = t & 63, wid = t >> 6;
    const int qd = lane >> 4, ml = lane & 15;
    const int wm = (wid >> 1) * (BM / 2), wn = (wid & 1) * (BN / 2);

    f32x4 acc[MT][NT] = {};

    auto stage = [&](int bf, int k0) {
#pragma unroll
        for (int r = 0; r < BM * BK / 2048; ++r) {
            int seg = r * 256 + t;
            int row = seg / CPR;
            int chunk = seg & (CPR - 1);
            int c8 = ((chunk ^ (row & (CPR - 1))) * 8);   // source-side swizzle
            const u16* ga = A + (long long)(m0 + row) * lda + k0 + c8;
            GLOAD_LDS16(ga, As[bf] + (size_t)(seg & ~63) * 8);
        }
#pragma unroll
        for (int r = 0; r < BN * BK / 2048; ++r) {
            int seg = r * 256 + t;
            int row = seg / CPR;
            int chunk = seg & (CPR - 1);
            int c8 = ((chunk ^ (row & (CPR - 1))) * 8);
            int rn = n0 + row;
            if (rn > N - 1) rn = N - 1;
            const u16* gb = B + (long long)rn * ldb + k0 + c8;
            GLOAD_LDS16(gb, Bs[bf] + (size_t)(seg & ~63) * 8);
        }
    };

    auto compute = [&](int bf) {
#pragma unroll
        for (int kk = 0; kk < BK / 32; ++kk) {
            half8 af[MT], bfv[NT];
#pragma unroll
            for (int mt = 0; mt < MT; ++mt) {
                int row = wm + mt * 16 + ml;
                int c = (kk * 4 + qd) ^ (row & (CPR - 1));
                af[mt] = *(const half8*)(As[bf] + (size_t)row * BK + c * 8);
            }
#pragma unroll
            for (int nt = 0; nt < NT; ++nt) {
                int row = wn + nt * 16 + ml;
                int c = (kk * 4 + qd) ^ (row & (CPR - 1));
                bfv[nt] = *(const half8*)(Bs[bf] + (size_t)row * BK + c * 8);
            }
#pragma unroll
            for (int mt = 0; mt < MT; ++mt)
#pragma unroll
                for (int nt = 0; nt < NT; ++nt)
                    acc[mt][nt] = __builtin_amdgcn_mfma_f32_16x16x32_f16(af[mt], bfv[nt], acc[mt][nt], 0, 0, 0);
        }
    };

    // Prologue: fill first two buffers.
    stage(0, 0);
    if (K > BK) stage(1, BK);

    int buf = 0, k0 = 0;
    // Main: depth-2 prefetch, counted vmcnt, one barrier per step.
    for (; k0 + 2 * BK < K; k0 += BK) {
        stage((buf + 2) & 3, k0 + 2 * BK);
        waitv<2 * S>();
        barrier_raw();
        compute(buf);
        buf = (buf + 1) & 3;
    }
    if (k0 + BK < K) {  // second-to-last tile (one stage still in flight)
        waitv<S>();
        barrier_raw();
        compute(buf);
        buf = (buf + 1) & 3;
        k0 += BK;
    }
    waitv<0>();
    barrier_raw();
    compute(buf);

#pragma unroll
    for (int nt = 0; nt < NT; ++nt) {
        int col = n0 + wn + nt * 16 + ml;
        if (col >= N) continue;
        float bv = bias ? bias[col] : 0.f;
#pragma unroll
        for (int mt = 0; mt < MT; ++mt) {
#pragma unroll
            for (int r = 0; r < 4; ++r) {
                int rowg = m0 + wm + mt * 16 + qd * 4 + r;
                float v = acc[mt][nt][r] * scale + bv;
                if (relu) v = fmaxf(v, 0.f);
                long long off = (long long)rowg * ldc + col;
                if (CF == 1) {
                    ((float*)Cv)[off] = v;
                } else if (CF == 2) {
                    resid[off] = v;
                    ((u16*)Cv)[off] = f2h_bits(v);
                } else if (resid) {
                    float nv = resid[off] + v;
                    resid[off] = nv;
                    ((u16*)Cv)[off] = f2h_bits(nv);
                } else if (vtp && col >= 1024) {
                    // fused V-transpose: vt[(b*8+h)][vd][s]
                    int b = rowg >> 9, s = rowg & 511;
                    int cv2 = col - 1024;
                    vtp[(size_t)(((b << 3) + (cv2 >> 6)) * 32768 + (cv2 & 63) * 512 + s)] = f2h_bits(v);
                } else {
                    ((u16*)Cv)[off] = f2h_bits(v);
                }
            }
        }
    }
}

// ---------------------------------------------------------------------------
// Fused flash attention (128-row Q-tile): per (q-tile, b*8+h) block computes
// O = softmax(Q K^T / 8) V. 4 waves x 32 Q-rows, zero barriers; setprio(1)
// around MFMA clusters (m191). XCD swizzle keeps a head's q-tiles on one XCD.
// ---------------------------------------------------------------------------
__global__ __launch_bounds__(256) void flash_k(
    const u16* __restrict__ qkv,  // [4096][1536] fp16 (q|k|v)
    const u16* __restrict__ vt,   // [64][64][512] fp16  v^T per slice
    u16* __restrict__ ob)         // [4096][512] fp16
{
    __shared__ __attribute__((aligned(16))) u16 Ps[128 * 136];

    // grid is (4, 64) fixed: id -> (z, q-tile) with same-z tiles on one XCD.
    int id = blockIdx.x + (blockIdx.y << 2);
    int xcd = id & 7, local = id >> 3;
    const int z = (xcd << 3) + (local >> 2);  // b*8 + h
    const int q0 = (local & 3) * 128;

    const int b = z >> 3, h = z & 7;
    const long long qbase = (long long)b * 786432;
    const u16* Q  = qkv + qbase + (long long)q0 * 1536 + h * 64;
    const u16* Kg = qkv + qbase + 512 + h * 64;
    const u16* Vg = vt + (long long)z * 32768;

    const int t = threadIdx.x, lane = t & 63, wid = t >> 6;
    const int qd = lane >> 4, ml = lane & 15;
    const int wm = wid * 32;

    half8 qf[2][2];
#pragma unroll
    for (int mt = 0; mt < 2; ++mt)
#pragma unroll
        for (int kf = 0; kf < 2; ++kf)
            qf[mt][kf] = *(const half8*)(Q + (long long)(wm + mt * 16 + ml) * 1536 + kf * 32 + qd * 8);

    f32x4 oacc[2][4] = {};
    float mrow[2][4], lrow[2][4];
#pragma unroll
    for (int mt = 0; mt < 2; ++mt)
#pragma unroll
        for (int r = 0; r < 4; ++r) { mrow[mt][r] = -3.0e38f; lrow[mt][r] = 0.f; }

    for (int kb = 0; kb < 4; ++kb) {
        f32x4 sacc[2][8] = {};
        __builtin_amdgcn_s_setprio(1);
#pragma unroll
        for (int nt = 0; nt < 8; ++nt) {
#pragma unroll
            for (int kf = 0; kf < 2; ++kf) {
                half8 bf = *(const half8*)(Kg + (long long)(kb * 128 + nt * 16 + ml) * 1536 + kf * 32 + qd * 8);
#pragma unroll
                for (int mt = 0; mt < 2; ++mt)
                    sacc[mt][nt] = __builtin_amdgcn_mfma_f32_16x16x32_f16(qf[mt][kf], bf, sacc[mt][nt], 0, 0, 0);
            }
        }
        __builtin_amdgcn_s_setprio(0);
#pragma unroll
        for (int mt = 0; mt < 2; ++mt) {
#pragma unroll
            for (int r = 0; r < 4; ++r) {
                float mx = -3.0e38f;
#pragma unroll
                for (int nt = 0; nt < 8; ++nt) {
                    float s = sacc[mt][nt][r] * 0.125f;
                    sacc[mt][nt][r] = s;
                    mx = fmaxf(mx, s);
                }
#pragma unroll
                for (int o = 1; o < 16; o <<= 1) mx = fmaxf(mx, __shfl_xor(mx, o, 64));
                float mnew = fmaxf(mrow[mt][r], mx);
                float alpha = __expf(mrow[mt][r] - mnew);
                mrow[mt][r] = mnew;
                lrow[mt][r] *= alpha;
#pragma unroll
                for (int nt = 0; nt < 4; ++nt) oacc[mt][nt][r] *= alpha;
                float ps = 0.f;
#pragma unroll
                for (int nt = 0; nt < 8; ++nt) {
                    float p = __expf(sacc[mt][nt][r] - mnew);
                    sacc[mt][nt][r] = p;
                    ps += p;
                }
#pragma unroll
                for (int o = 1; o < 16; o <<= 1) ps += __shfl_xor(ps, o, 64);
                lrow[mt][r] += ps;
            }
        }
#pragma unroll
        for (int mt = 0; mt < 2; ++mt)
#pragma unroll
            for (int nt = 0; nt < 8; ++nt)
#pragma unroll
                for (int r = 0; r < 4; ++r)
                    Ps[(wm + mt * 16 + qd * 4 + r) * 136 + nt * 16 + ml] = f2h_bits(sacc[mt][nt][r]);
        __builtin_amdgcn_s_setprio(1);
#pragma unroll
        for (int kf = 0; kf < 4; ++kf) {
            half8 pf[2];
#pragma unroll
            for (int mt = 0; mt < 2; ++mt)
                pf[mt] = *(const half8*)(Ps + (wm + mt * 16 + ml) * 136 + kf * 32 + qd * 8);
#pragma unroll
            for (int nt = 0; nt < 4; ++nt) {
                half8 vf = *(const half8*)(Vg + (long long)(nt * 16 + ml) * 512 + kb * 128 + kf * 32 + qd * 8);
#pragma unroll
                for (int mt = 0; mt < 2; ++mt)
                    oacc[mt][nt] = __builtin_amdgcn_mfma_f32_16x16x32_f16(pf[mt], vf, oacc[mt][nt], 0, 0, 0);
            }
        }
        __builtin_amdgcn_s_setprio(0);
    }

#pragma unroll
    for (int mt = 0; mt < 2; ++mt) {
#pragma unroll
        for (int r = 0; r < 4; ++r) {
            float inv = 1.f / lrow[mt][r];
            long long rowg = (long long)b * 512 + q0 + wm + mt * 16 + qd * 4 + r;
#pragma unroll
            for (int nt = 0; nt < 4; ++nt)
                ob[rowg * 512 + h * 64 + nt * 16 + ml] = f2h_bits(oacc[mt][nt][r] * inv);
        }
    }
}

template <int MODE>
__global__ void transpose_k(const void* __restrict__ src_, int s_ld, long long s_off,
                            long long s_so, long long s_si,
                            u16* __restrict__ dst, int d_ld, long long d_so, long long d_si,
                            int R, int Rs, int C, const void* caps)
{
    __shared__ u16 tile[32][33];
    const int z = blockIdx.z;
    const long long sb = s_off + (long long)(z >> 3) * s_so + (long long)(z & 7) * s_si;
    dst += (long long)(z >> 3) * d_so + (long long)(z & 7) * d_si;
    const int c0 = blockIdx.x * 32, r0 = blockIdx.y * 32;
    const int tx = threadIdx.x, ty = threadIdx.y;
    const int flag = (MODE == 1) ? detect_bf16(caps) : 0;
#pragma unroll
    for (int i = 0; i < 4; ++i) {
        int r = r0 + ty + i * 8, c = c0 + tx;
        if (r < R && c < C) {
            u16 v = 0;
            if (r < Rs) {
                size_t idx = (size_t)(sb + (long long)r * s_ld + c);
                if (MODE == 1) v = f2h_bits(ldin(src_, idx, flag));
                else           v = ((const u16*)src_)[idx];
            }
            tile[ty + i * 8][tx] = v;
        }
    }
    __syncthreads();
#pragma unroll
    for (int i = 0; i < 4; ++i) {
        int r = r0 + tx, c = c0 + ty + i * 8;
        if (r < R && c < C) dst[(long long)c * d_ld + r] = tile[tx][ty + i * 8];
    }
}

__global__ void qkvoT6_k(const void* Wq, const void* Wk, const void* Wv, const void* Wo,
                         u16* __restrict__ wqkvT6, u16* __restrict__ woT6,
                         const void* caps)
{
    __shared__ u16 tile[32][33];
    const int z = blockIdx.z;
    const int layer = z >> 2, sel = z & 3;
    const void* src = (sel == 0) ? Wq : (sel == 1) ? Wk : (sel == 2) ? Wv : Wo;
    u16* dst = (sel < 3) ? (wqkvT6 + (long long)layer * 786432 + (long long)sel * 262144)
                         : (woT6 + (long long)layer * 262144);
    const long long oW = (long long)layer * 262144;
    const int c0 = blockIdx.x * 32, r0 = blockIdx.y * 32;
    const int tx = threadIdx.x, ty = threadIdx.y;
    const int flag = detect_bf16(caps);
#pragma unroll
    for (int i = 0; i < 4; ++i) {
        int r = r0 + ty + i * 8, c = c0 + tx;
        tile[ty + i * 8][tx] = f2h_bits(ldin(src, (size_t)(oW + (long long)r * 512 + c), flag));
    }
    __syncthreads();
#pragma unroll
    for (int i = 0; i < 4; ++i) {
        int r = r0 + tx, c = c0 + ty + i * 8;
        dst[(long long)c * 512 + r] = tile[tx][ty + i * 8];
    }
}

__global__ void cvt_small_k(const void* srcW, const void* srcB, const void* candW, const void* candB,
                            const void* depW, const void* depB, const void* feasW, const void* feasB,
                            const void* pW, const void* pb, const void* boi, const void* b1i,
                            const void* b2i, const void* caps, float* __restrict__ dst)
{
    int i = blockIdx.x * 256 + threadIdx.x;
    if (i >= A_TOTAL) return;
    int flag = detect_bf16(caps);
    const void* s; int j;
    if      (i < A_SRCB)  { s = srcW;  j = i - A_SRCW; }
    else if (i < A_CANDW) { s = srcB;  j = i - A_SRCB; }
    else if (i < A_CANDB) { s = candW; j = i - A_CANDW; }
    else if (i < A_DEPW)  { s = candB; j = i - A_CANDB; }
    else if (i < A_DEPB)  { s = depW;  j = i - A_DEPW; }
    else if (i < A_FEASW) { s = depB;  j = i - A_DEPB; }
    else if (i < A_FEASB) { s = feasW; j = i - A_FEASW; }
    else if (i < A_PW)    { s = feasB; j = i - A_FEASB; }
    else if (i < A_PB)    { s = pW;    j = i - A_PW; }
    else if (i < A_BO)    { s = pb;    j = i - A_PB; }
    else if (i < A_B1)    { s = boi;   j = i - A_BO; }
    else if (i < A_B2)    { s = b1i;   j = i - A_B1; }
    else                  { s = b2i;   j = i - A_B2; }
    dst[i] = ldin(s, j, flag);
}

__global__ void catbias_k(const void* bq, const void* bk, const void* bv,
                          const void* caps, float* __restrict__ dst)
{
    int t = blockIdx.x * 256 + threadIdx.x;
    if (t >= 6 * 1536) return;
    int flag = detect_bf16(caps);
    int l = t / 1536, j = t - l * 1536;
    float v = (j < 512) ? ldin(bq, l * 512 + j, flag)
            : (j < 1024) ? ldin(bk, l * 512 + j - 512, flag)
                         : ldin(bv, l * 512 + j - 1024, flag);
    dst[t] = v;
}

__global__ __launch_bounds__(256) void gather_xin_k(
    const void* __restrict__ sol, const void* __restrict__ caps, const void* __restrict__ emb,
    u16* __restrict__ xin)
{
    const int row = blockIdx.x;
    const int b = row >> 9, s = row & 511;
    const int t = threadIdx.x;
    const int flag = detect_bf16(caps);
    float idxf = ldin(sol, (size_t)row * 4, flag);
    int idx = (int)(idxf + 0.5f);
    if (idx < 0) idx = 0;
    if (idx > 9999) idx = 9999;
    xin[(size_t)row * 288 + t] = f2h_bits(ldin(emb, (size_t)idx * 256 + t, flag));
    if (t < 32) {
        float v = 0.f;
        if (t == 0 && s != 0) {
            float rem = ldin(sol, ((size_t)b * 512) * 4 + 3, flag);
            float cap = ldin(caps, b, flag);
            float dem = ldin(sol, (size_t)row * 4 + 2, flag);
            v = 2.f * (dem - rem) / cap;
        }
        xin[(size_t)row * 288 + 256 + t] = f2h_bits(v);
    }
}

__global__ __launch_bounds__(256) void fixup_enc_k(
    const void* __restrict__ sol, const void* __restrict__ caps, const void* __restrict__ emb,
    const float* __restrict__ arena, float* __restrict__ xf, u16* __restrict__ xb)
{
    const int blk = blockIdx.x;
    const int b = blk & 7;
    const int s = (blk >> 3) ? 511 : 0;
    const int row = b * 512 + s;
    const int t = threadIdx.x;
    __shared__ float e[256];
    __shared__ float nds;
    const int flag = detect_bf16(caps);
    float idxf = ldin(sol, (size_t)row * 4, flag);
    int idx = (int)(idxf + 0.5f);
    if (idx < 0) idx = 0;
    if (idx > 9999) idx = 9999;
    e[t] = ldin(emb, (size_t)idx * 256 + t, flag);
    if (t == 0) {
        float rem = ldin(sol, ((size_t)b * 512) * 4 + 3, flag);
        float cap = ldin(caps, b, flag);
        float dem = ldin(sol, (size_t)row * 4 + 2, flag);
        nds = (s == 0) ? 0.f : 2.f * (dem - rem) / cap;
    }
    __syncthreads();
    const float* W  = (s == 0) ? arena + A_SRCW : arena + A_DEPW;
    const float* Bb = (s == 0) ? arena + A_SRCB : arena + A_DEPB;
    float a0 = 0.f, a1 = 0.f;
    for (int c = 0; c < 256; ++c) {
        float ev = e[c];
        a0 += ev * W[(size_t)c * 512 + t];
        a1 += ev * W[(size_t)c * 512 + t + 256];
    }
    float nd = nds;
    a0 += nd * W[256 * 512 + t] + Bb[t];
    a1 += nd * W[256 * 512 + t + 256] + Bb[t + 256];
    size_t o = (size_t)row * 512;
    xf[o + t] = a0;        xb[o + t] = f2h_bits(a0);
    xf[o + t + 256] = a1;  xb[o + t + 256] = f2h_bits(a1);
}

__global__ __launch_bounds__(256) void feas_k(const float* __restrict__ xf,
                                              const float* __restrict__ arena,
                                              float* __restrict__ out)
{
    int w = blockIdx.x * 4 + (threadIdx.x >> 6);
    if (w >= 8 * 510) return;
    int lane = threadIdx.x & 63;
    int b = w / 510, j = w - b * 510;
    const float* xr = xf + ((size_t)(b * 512 + 1 + j)) * 512;
    const float* fW = arena + A_FEASW;
    float a = 0.f;
#pragma unroll
    for (int i = 0; i < 8; ++i) { int d = lane + 64 * i; a += xr[d] * fW[d]; }
#pragma unroll
    for (int o = 1; o < 64; o <<= 1) a += __shfl_xor(a, o, 64);
    if (lane == 0) out[8160 + b * 510 + j] = a + arena[A_FEASB];
}

__global__ __launch_bounds__(256) void ptr_k(const float* __restrict__ xf,
                                             const float* __restrict__ arena,
                                             float* __restrict__ out)
{
    int w = blockIdx.x * 4 + (threadIdx.x >> 6);
    if (w >= 8 * 510) return;
    int lane = threadIdx.x & 63;
    int b = w / 510, j = w - b * 510;
    const float* xr = xf + ((size_t)(b * 512 + 1 + j)) * 512;
    const float* pWa = arena + A_PW;
    float a0 = 0.f, a1 = 0.f;
#pragma unroll
    for (int i = 0; i < 8; ++i) {
        int d = lane + 64 * i;
        float x = xr[d];
        a0 += x * pWa[d * 2];
        a1 += x * pWa[d * 2 + 1];
    }
#pragma unroll
    for (int o = 1; o < 64; o <<= 1) { a0 += __shfl_xor(a0, o, 64); a1 += __shfl_xor(a1, o, 64); }
    if (lane == 0) {
        out[(size_t)b * 1020 + j]       = a0 + arena[A_PB];
        out[(size_t)b * 1020 + 510 + j] = a1 + arena[A_PB + 1];
    }
}

extern "C" void kernel_launch(void* const* d_in, const int* in_sizes, int n_in,
                              void* d_out, int out_size, void* d_ws, size_t ws_size,
                              hipStream_t stream)
{
    const void* sol   = d_in[0];
    const void* caps  = d_in[1];
    const void* emb   = d_in[2];
    const void* srcW  = d_in[3];
    const void* srcB  = d_in[4];
    const void* candW = d_in[5];
    const void* candB = d_in[6];
    const void* depW  = d_in[7];
    const void* depB  = d_in[8];
    const void* feasW = d_in[9];
    const void* feasB = d_in[10];
    const void* Wq  = d_in[11];
    const void* bq  = d_in[12];
    const void* Wk  = d_in[13];
    const void* bk  = d_in[14];
    const void* Wv  = d_in[15];
    const void* bv  = d_in[16];
    const void* Wo  = d_in[17];
    const void* boi = d_in[18];
    // d_in[19] = s_scale: softmax shift no-op
    const void* W1  = d_in[20];
    const void* b1i = d_in[21];
    const void* W2  = d_in[22];
    const void* b2i = d_in[23];
    const void* pW  = d_in[24];
    const void* pb  = d_in[25];
    float* out = (float*)d_out;

    // workspace
    char* w = (char*)d_ws;
    float* xf    = (float*)w; w += 8388608;   // 4096x512 fp32 residual master
    u16* xb      = (u16*)w;   w += 4194304;   // 4096x512 fp16
    u16* qkvb    = (u16*)w;   w += 12582912;  // 4096x1536 fp16 (q|k|v; v region unused)
    u16* vt      = (u16*)w;   w += 4194304;   // 64x64x512 fp16 (v^T per slice)
    u16* hb      = (u16*)w;   w += 16777216;  // 4096x2048 fp16 FFN hidden
    u16* xin     = hb;                        //  ALIAS: 4096x288 fp16 encoder input
    u16* encW    = hb + 4096 * 288;           //  ALIAS: 512x288 fp16 candW^T
    u16* ob      = (u16*)w;   w += 4194304;   // 4096x512 fp16 attention out
    u16* wqkvT6  = (u16*)w;   w += 9437184;   // 6x 1536x512 fp16
    u16* woT6    = (u16*)w;   w += 3145728;   // 6x 512x512 fp16
    u16* w1T6    = (u16*)w;   w += 12582912;  // 6x 2048x512 fp16
    u16* w2T6    = (u16*)w;   w += 12582912;  // 6x 512x2048 fp16
    float* bqkvf = (float*)w; w += 36864;     // 6x1536 fp32
    float* arena = (float*)w; w += A_TOTAL * 4;

    dim3 tb(32, 8);
    cvt_small_k<<<dim3((A_TOTAL + 255) / 256), 256, 0, stream>>>(
        srcW, srcB, candW, candB, depW, depB, feasW, feasB, pW, pb, boi, b1i, b2i, caps, arena);
    catbias_k<<<dim3(36), 256, 0, stream>>>(bq, bk, bv, caps, bqkvf);

    // Weight transposes hoisted (3 dispatches).
    qkvoT6_k<<<dim3(16, 16, 24), tb, 0, stream>>>(Wq, Wk, Wv, Wo, wqkvT6, woT6, caps);
    transpose_k<1><<<dim3(64, 16, 6), tb, 0, stream>>>(W1, 2048, 0, 0, 1048576,
                                                       w1T6, 512, 0, 1048576, 512, 512, 2048, caps);
    transpose_k<1><<<dim3(16, 64, 6), tb, 0, stream>>>(W2, 512, 0, 0, 1048576,
                                                       w2T6, 2048, 0, 1048576, 2048, 2048, 512, caps);

    // Encoder via MFMA + 16-row fixup.
    gather_xin_k<<<dim3(4096), 256, 0, stream>>>(sol, caps, emb, xin);
    transpose_k<1><<<dim3(16, 9, 1), tb, 0, stream>>>(candW, 512, 0, 0, 0,
                                                      encW, 288, 0, 0, 288, 257, 512, caps);
    gemm_f16<2, 64, 64, 32><<<dim3(8, 64), 256, 0, stream>>>(
        xin, 288, encW, 288,
        xb, 512, arena + A_CANDB, xf, nullptr, 1.f, 0, 512, 288);
    fixup_enc_k<<<dim3(16), 256, 0, stream>>>(sol, caps, emb, arena, xf, xb);

    for (int i = 0; i < 6; ++i) {
        // QKV projection; V columns stream directly into vt (fused transpose).
        gemm_f16<0, 64, 64, 64><<<dim3(24, 64), 256, 0, stream>>>(
            xb, 512, wqkvT6 + (long long)i * 786432, 512,
            qkvb, 1536, bqkvf + i * 1536, nullptr, vt, 1.f, 0, 1536, 512);

        // Fused attention: scores+softmax+PV in one dispatch, zero barriers.
        flash_k<<<dim3(4, 64), 256, 0, stream>>>(qkvb, vt, ob);

        // Wo projection + residual into xf/xb.
        gemm_f16<0, 64, 64, 64><<<dim3(8, 64), 256, 0, stream>>>(
            ob, 512, woT6 + (long long)i * 262144, 512,
            xb, 512, arena + A_BO + i * 512, xf, nullptr, 1.f, 0, 512, 512);
        if (i == 0)
            feas_k<<<dim3(1020), 256, 0, stream>>>(xf, arena, out);

        // FFN1 (relu) -> hb: 128x128xBK32 (m97 config: 512 WGs, 2 resident/CU).
        gemm_f16<0, 128, 128, 32><<<dim3(16, 32), 256, 0, stream>>>(
            xb, 512, w1T6 + (long long)i * 1048576, 512,
            hb, 2048, arena + A_B1 + i * 2048, nullptr, nullptr, 1.f, 1, 2048, 512);

        // FFN2 full-K: 64x64xBK64 (32 steps, 2 resident/CU).
        gemm_f16<0, 64, 64, 64><<<dim3(8, 64), 256, 0, stream>>>(
            hb, 2048, w2T6 + (long long)i * 1048576, 2048,
            xb, 512, arena + A_B2 + i * 512, xf, nullptr, 1.f, 0, 512, 2048);
    }
    ptr_k<<<dim3(1020), 256, 0, stream>>>(xf, arena, out);
}

// Round 9
// 860.065 us; speedup vs baseline: 1.7672x; 1.0487x over previous
//
#include <hip/hip_runtime.h>

typedef unsigned short u16;
typedef _Float16 half8 __attribute__((ext_vector_type(8)));
typedef float f32x4 __attribute__((ext_vector_type(4)));

__device__ inline float bf2f(u16 b) { return __builtin_bit_cast(float, ((unsigned)b) << 16); }
__device__ inline float h2f(u16 h) { return (float)__builtin_bit_cast(_Float16, h); }
__device__ inline u16 f2h_bits(float f) { return __builtin_bit_cast(u16, (_Float16)f); }

__device__ inline int detect_bf16(const void* caps) {
    const u16* c = (const u16*)caps;
    int cnt = 0;
#pragma unroll
    for (int k = 0; k < 4; ++k) {
        float v = bf2f(c[2 * k]);
        if (v >= 20.f && v <= 200.f) cnt++;
    }
    return cnt >= 2;
}
__device__ inline float ldin(const void* p, size_t i, int flag) {
    return flag ? bf2f(((const u16*)p)[i]) : ((const float*)p)[i];
}

#define GLOAD_LDS16(g, l)                                                              \
    __builtin_amdgcn_global_load_lds((__attribute__((address_space(1))) const void*)(g), \
                                     (__attribute__((address_space(3))) void*)(l), 16, 0, 0)

// Counted vmcnt wait + compiler memory fence (prevents ds_read hoisting).
template <int N>
__device__ inline void waitv() {
    if constexpr (N == 0)       asm volatile("s_waitcnt vmcnt(0)" ::: "memory");
    else if constexpr (N == 2)  asm volatile("s_waitcnt vmcnt(2)" ::: "memory");
    else if constexpr (N == 4)  asm volatile("s_waitcnt vmcnt(4)" ::: "memory");
    else if constexpr (N == 6)  asm volatile("s_waitcnt vmcnt(6)" ::: "memory");
    else if constexpr (N == 8)  asm volatile("s_waitcnt vmcnt(8)" ::: "memory");
    else if constexpr (N == 12) asm volatile("s_waitcnt vmcnt(12)" ::: "memory");
}
__device__ inline void barrier_raw() {
    asm volatile("" ::: "memory");
    __builtin_amdgcn_s_barrier();
    asm volatile("" ::: "memory");
}

#define A_SRCW 0
#define A_SRCB 131584
#define A_CANDW 132096
#define A_CANDB 263680
#define A_DEPW 264192
#define A_DEPB 395776
#define A_FEASW 396288
#define A_FEASB 396800
#define A_PW 396801
#define A_PB 397825
#define A_BO 397827
#define A_B1 400899
#define A_B2 413187
#define A_TOTAL 416259

// ---------------------------------------------------------------------------
// GEMM with templated BM x BN x BK. Law (R5/R7/R8): fixed ~750cyc/block-step
// floor at 2 resident blocks/CU, independent of per-step work -> maximize BK.
// BK=128 needs a 2-buffer structure to stay <= 64KB LDS (2 resident):
//   barrier            // all waves done reading buf^1 (prev compute)
//   stage(buf^1, next) // overwrite it with tile i+1
//   vmcnt(S)           // own stage(cur) loads drained; next stage in flight
//   barrier            // publish: every wave's stage(cur) landed (R8 pattern)
//   compute(buf)
// Counted vmcnt never drains the in-flight prefetch. Both-sides chunk swizzle
// (chunk ^= row & (BK/8-1)) keeps ds_read_b128 conflict-free at 256B row
// stride. XCD-locality block swizzle retained.
// ---------------------------------------------------------------------------
template <int CF, int BM, int BN, int BK>
__global__ __launch_bounds__(256) void gemm_f16(
    const u16* __restrict__ A, int lda,
    const u16* __restrict__ B, int ldb,
    void* __restrict__ Cv, int ldc,
    const float* __restrict__ bias, float* __restrict__ resid,
    u16* __restrict__ vtp,
    float scale, int relu, int N, int K)
{
    constexpr int MT = BM / 32;                    // A-frags per wave (2x2 wave grid)
    constexpr int NT = BN / 32;                    // B-frags per wave
    constexpr int CPR = BK / 8;                    // 16B chunks per row
    constexpr int S = (BM / 64 + BN / 64) * (BK / 32);  // VMEM instrs per stage per wave
    __shared__ __attribute__((aligned(16))) u16 As[2][BM * BK];
    __shared__ __attribute__((aligned(16))) u16 Bs[2][BN * BK];

    // XCD-aware remap (bijective; falls back to identity if gy % 8 != 0).
    const int gx = gridDim.x, gy = gridDim.y;
    int mb, nb;
    if ((gy & 7) == 0) {
        int id = blockIdx.x + blockIdx.y * gx;
        int xcd = id & 7, local = id >> 3;
        int mloc = local / gx;
        mb = xcd * (gy >> 3) + mloc;
        nb = local - mloc * gx;
    } else {
        mb = blockIdx.y;
        nb = blockIdx.x;
    }
    const int m0 = mb * BM;
    const int n0 = nb * BN;

    const int t = threadIdx.x, lane = t & 63, wid = t >> 6;
    const int qd = lane >> 4, ml = lane & 15;
    const int wm = (wid >> 1) * (BM / 2), wn = (wid & 1) * (BN / 2);

    f32x4 acc[MT][NT] = {};

    auto stage = [&](int bf, int k0) {
#pragma unroll
        for (int r = 0; r < BM * BK / 2048; ++r) {
            int seg = r * 256 + t;
            int row = seg / CPR;
            int chunk = seg & (CPR - 1);
            int c8 = ((chunk ^ (row & (CPR - 1))) * 8);   // source-side swizzle
            const u16* ga = A + (long long)(m0 + row) * lda + k0 + c8;
            GLOAD_LDS16(ga, As[bf] + (size_t)(seg & ~63) * 8);
        }
#pragma unroll
        for (int r = 0; r < BN * BK / 2048; ++r) {
            int seg = r * 256 + t;
            int row = seg / CPR;
            int chunk = seg & (CPR - 1);
            int c8 = ((chunk ^ (row & (CPR - 1))) * 8);
            int rn = n0 + row;
            if (rn > N - 1) rn = N - 1;
            const u16* gb = B + (long long)rn * ldb + k0 + c8;
            GLOAD_LDS16(gb, Bs[bf] + (size_t)(seg & ~63) * 8);
        }
    };

    auto compute = [&](int bf) {
#pragma unroll
        for (int kk = 0; kk < BK / 32; ++kk) {
            half8 af[MT], bfv[NT];
#pragma unroll
            for (int mt = 0; mt < MT; ++mt) {
                int row = wm + mt * 16 + ml;
                int c = (kk * 4 + qd) ^ (row & (CPR - 1));
                af[mt] = *(const half8*)(As[bf] + (size_t)row * BK + c * 8);
            }
#pragma unroll
            for (int nt = 0; nt < NT; ++nt) {
                int row = wn + nt * 16 + ml;
                int c = (kk * 4 + qd) ^ (row & (CPR - 1));
                bfv[nt] = *(const half8*)(Bs[bf] + (size_t)row * BK + c * 8);
            }
#pragma unroll
            for (int mt = 0; mt < MT; ++mt)
#pragma unroll
                for (int nt = 0; nt < NT; ++nt)
                    acc[mt][nt] = __builtin_amdgcn_mfma_f32_16x16x32_f16(af[mt], bfv[nt], acc[mt][nt], 0, 0, 0);
        }
    };

    // Prologue: fill buffer 0.
    stage(0, 0);

    int buf = 0;
    for (int k0 = 0; k0 < K; k0 += BK) {
        if (k0 > 0) barrier_raw();            // all waves done reading buf^1
        if (k0 + BK < K) {
            stage(buf ^ 1, k0 + BK);          // prefetch next tile
            waitv<S>();                       // own current-tile loads drained
        } else {
            waitv<0>();                       // last tile: drain everything
        }
        barrier_raw();                        // cross-wave publication
        compute(buf);
        buf ^= 1;
    }

#pragma unroll
    for (int nt = 0; nt < NT; ++nt) {
        int col = n0 + wn + nt * 16 + ml;
        if (col >= N) continue;
        float bv = bias ? bias[col] : 0.f;
#pragma unroll
        for (int mt = 0; mt < MT; ++mt) {
#pragma unroll
            for (int r = 0; r < 4; ++r) {
                int rowg = m0 + wm + mt * 16 + qd * 4 + r;
                float v = acc[mt][nt][r] * scale + bv;
                if (relu) v = fmaxf(v, 0.f);
                long long off = (long long)rowg * ldc + col;
                if (CF == 1) {
                    ((float*)Cv)[off] = v;
                } else if (CF == 2) {
                    resid[off] = v;
                    ((u16*)Cv)[off] = f2h_bits(v);
                } else if (resid) {
                    float nv = resid[off] + v;
                    resid[off] = nv;
                    ((u16*)Cv)[off] = f2h_bits(nv);
                } else if (vtp && col >= 1024) {
                    // fused V-transpose: vt[(b*8+h)][vd][s]
                    int b = rowg >> 9, s = rowg & 511;
                    int cv2 = col - 1024;
                    vtp[(size_t)(((b << 3) + (cv2 >> 6)) * 32768 + (cv2 & 63) * 512 + s)] = f2h_bits(v);
                } else {
                    ((u16*)Cv)[off] = f2h_bits(v);
                }
            }
        }
    }
}

// ---------------------------------------------------------------------------
// Fused flash attention (128-row Q-tile): per (q-tile, b*8+h) block computes
// O = softmax(Q K^T / 8) V. 4 waves x 32 Q-rows, zero barriers; setprio(1)
// around MFMA clusters (m191). XCD swizzle keeps a head's q-tiles on one XCD.
// ---------------------------------------------------------------------------
__global__ __launch_bounds__(256) void flash_k(
    const u16* __restrict__ qkv,  // [4096][1536] fp16 (q|k|v)
    const u16* __restrict__ vt,   // [64][64][512] fp16  v^T per slice
    u16* __restrict__ ob)         // [4096][512] fp16
{
    __shared__ __attribute__((aligned(16))) u16 Ps[128 * 136];

    // grid is (4, 64) fixed: id -> (z, q-tile) with same-z tiles on one XCD.
    int id = blockIdx.x + (blockIdx.y << 2);
    int xcd = id & 7, local = id >> 3;
    const int z = (xcd << 3) + (local >> 2);  // b*8 + h
    const int q0 = (local & 3) * 128;

    const int b = z >> 3, h = z & 7;
    const long long qbase = (long long)b * 786432;
    const u16* Q  = qkv + qbase + (long long)q0 * 1536 + h * 64;
    const u16* Kg = qkv + qbase + 512 + h * 64;
    const u16* Vg = vt + (long long)z * 32768;

    const int t = threadIdx.x, lane = t & 63, wid = t >> 6;
    const int qd = lane >> 4, ml = lane & 15;
    const int wm = wid * 32;

    half8 qf[2][2];
#pragma unroll
    for (int mt = 0; mt < 2; ++mt)
#pragma unroll
        for (int kf = 0; kf < 2; ++kf)
            qf[mt][kf] = *(const half8*)(Q + (long long)(wm + mt * 16 + ml) * 1536 + kf * 32 + qd * 8);

    f32x4 oacc[2][4] = {};
    float mrow[2][4], lrow[2][4];
#pragma unroll
    for (int mt = 0; mt < 2; ++mt)
#pragma unroll
        for (int r = 0; r < 4; ++r) { mrow[mt][r] = -3.0e38f; lrow[mt][r] = 0.f; }

    for (int kb = 0; kb < 4; ++kb) {
        f32x4 sacc[2][8] = {};
        __builtin_amdgcn_s_setprio(1);
#pragma unroll
        for (int nt = 0; nt < 8; ++nt) {
#pragma unroll
            for (int kf = 0; kf < 2; ++kf) {
                half8 bf = *(const half8*)(Kg + (long long)(kb * 128 + nt * 16 + ml) * 1536 + kf * 32 + qd * 8);
#pragma unroll
                for (int mt = 0; mt < 2; ++mt)
                    sacc[mt][nt] = __builtin_amdgcn_mfma_f32_16x16x32_f16(qf[mt][kf], bf, sacc[mt][nt], 0, 0, 0);
            }
        }
        __builtin_amdgcn_s_setprio(0);
#pragma unroll
        for (int mt = 0; mt < 2; ++mt) {
#pragma unroll
            for (int r = 0; r < 4; ++r) {
                float mx = -3.0e38f;
#pragma unroll
                for (int nt = 0; nt < 8; ++nt) {
                    float s = sacc[mt][nt][r] * 0.125f;
                    sacc[mt][nt][r] = s;
                    mx = fmaxf(mx, s);
                }
#pragma unroll
                for (int o = 1; o < 16; o <<= 1) mx = fmaxf(mx, __shfl_xor(mx, o, 64));
                float mnew = fmaxf(mrow[mt][r], mx);
                float alpha = __expf(mrow[mt][r] - mnew);
                mrow[mt][r] = mnew;
                lrow[mt][r] *= alpha;
#pragma unroll
                for (int nt = 0; nt < 4; ++nt) oacc[mt][nt][r] *= alpha;
                float ps = 0.f;
#pragma unroll
                for (int nt = 0; nt < 8; ++nt) {
                    float p = __expf(sacc[mt][nt][r] - mnew);
                    sacc[mt][nt][r] = p;
                    ps += p;
                }
#pragma unroll
                for (int o = 1; o < 16; o <<= 1) ps += __shfl_xor(ps, o, 64);
                lrow[mt][r] += ps;
            }
        }
#pragma unroll
        for (int mt = 0; mt < 2; ++mt)
#pragma unroll
            for (int nt = 0; nt < 8; ++nt)
#pragma unroll
                for (int r = 0; r < 4; ++r)
                    Ps[(wm + mt * 16 + qd * 4 + r) * 136 + nt * 16 + ml] = f2h_bits(sacc[mt][nt][r]);
        __builtin_amdgcn_s_setprio(1);
#pragma unroll
        for (int kf = 0; kf < 4; ++kf) {
            half8 pf[2];
#pragma unroll
            for (int mt = 0; mt < 2; ++mt)
                pf[mt] = *(const half8*)(Ps + (wm + mt * 16 + ml) * 136 + kf * 32 + qd * 8);
#pragma unroll
            for (int nt = 0; nt < 4; ++nt) {
                half8 vf = *(const half8*)(Vg + (long long)(nt * 16 + ml) * 512 + kb * 128 + kf * 32 + qd * 8);
#pragma unroll
                for (int mt = 0; mt < 2; ++mt)
                    oacc[mt][nt] = __builtin_amdgcn_mfma_f32_16x16x32_f16(pf[mt], vf, oacc[mt][nt], 0, 0, 0);
            }
        }
        __builtin_amdgcn_s_setprio(0);
    }

#pragma unroll
    for (int mt = 0; mt < 2; ++mt) {
#pragma unroll
        for (int r = 0; r < 4; ++r) {
            float inv = 1.f / lrow[mt][r];
            long long rowg = (long long)b * 512 + q0 + wm + mt * 16 + qd * 4 + r;
#pragma unroll
            for (int nt = 0; nt < 4; ++nt)
                ob[rowg * 512 + h * 64 + nt * 16 + ml] = f2h_bits(oacc[mt][nt][r] * inv);
        }
    }
}

template <int MODE>
__global__ void transpose_k(const void* __restrict__ src_, int s_ld, long long s_off,
                            long long s_so, long long s_si,
                            u16* __restrict__ dst, int d_ld, long long d_so, long long d_si,
                            int R, int Rs, int C, const void* caps)
{
    __shared__ u16 tile[32][33];
    const int z = blockIdx.z;
    const long long sb = s_off + (long long)(z >> 3) * s_so + (long long)(z & 7) * s_si;
    dst += (long long)(z >> 3) * d_so + (long long)(z & 7) * d_si;
    const int c0 = blockIdx.x * 32, r0 = blockIdx.y * 32;
    const int tx = threadIdx.x, ty = threadIdx.y;
    const int flag = (MODE == 1) ? detect_bf16(caps) : 0;
#pragma unroll
    for (int i = 0; i < 4; ++i) {
        int r = r0 + ty + i * 8, c = c0 + tx;
        if (r < R && c < C) {
            u16 v = 0;
            if (r < Rs) {
                size_t idx = (size_t)(sb + (long long)r * s_ld + c);
                if (MODE == 1) v = f2h_bits(ldin(src_, idx, flag));
                else           v = ((const u16*)src_)[idx];
            }
            tile[ty + i * 8][tx] = v;
        }
    }
    __syncthreads();
#pragma unroll
    for (int i = 0; i < 4; ++i) {
        int r = r0 + tx, c = c0 + ty + i * 8;
        if (r < R && c < C) dst[(long long)c * d_ld + r] = tile[tx][ty + i * 8];
    }
}

__global__ void qkvoT6_k(const void* Wq, const void* Wk, const void* Wv, const void* Wo,
                         u16* __restrict__ wqkvT6, u16* __restrict__ woT6,
                         const void* caps)
{
    __shared__ u16 tile[32][33];
    const int z = blockIdx.z;
    const int layer = z >> 2, sel = z & 3;
    const void* src = (sel == 0) ? Wq : (sel == 1) ? Wk : (sel == 2) ? Wv : Wo;
    u16* dst = (sel < 3) ? (wqkvT6 + (long long)layer * 786432 + (long long)sel * 262144)
                         : (woT6 + (long long)layer * 262144);
    const long long oW = (long long)layer * 262144;
    const int c0 = blockIdx.x * 32, r0 = blockIdx.y * 32;
    const int tx = threadIdx.x, ty = threadIdx.y;
    const int flag = detect_bf16(caps);
#pragma unroll
    for (int i = 0; i < 4; ++i) {
        int r = r0 + ty + i * 8, c = c0 + tx;
        tile[ty + i * 8][tx] = f2h_bits(ldin(src, (size_t)(oW + (long long)r * 512 + c), flag));
    }
    __syncthreads();
#pragma unroll
    for (int i = 0; i < 4; ++i) {
        int r = r0 + tx, c = c0 + ty + i * 8;
        dst[(long long)c * 512 + r] = tile[tx][ty + i * 8];
    }
}

__global__ void cvt_small_k(const void* srcW, const void* srcB, const void* candW, const void* candB,
                            const void* depW, const void* depB, const void* feasW, const void* feasB,
                            const void* pW, const void* pb, const void* boi, const void* b1i,
                            const void* b2i, const void* caps, float* __restrict__ dst)
{
    int i = blockIdx.x * 256 + threadIdx.x;
    if (i >= A_TOTAL) return;
    int flag = detect_bf16(caps);
    const void* s; int j;
    if      (i < A_SRCB)  { s = srcW;  j = i - A_SRCW; }
    else if (i < A_CANDW) { s = srcB;  j = i - A_SRCB; }
    else if (i < A_CANDB) { s = candW; j = i - A_CANDW; }
    else if (i < A_DEPW)  { s = candB; j = i - A_CANDB; }
    else if (i < A_DEPB)  { s = depW;  j = i - A_DEPW; }
    else if (i < A_FEASW) { s = depB;  j = i - A_DEPB; }
    else if (i < A_FEASB) { s = feasW; j = i - A_FEASW; }
    else if (i < A_PW)    { s = feasB; j = i - A_FEASB; }
    else if (i < A_PB)    { s = pW;    j = i - A_PW; }
    else if (i < A_BO)    { s = pb;    j = i - A_PB; }
    else if (i < A_B1)    { s = boi;   j = i - A_BO; }
    else if (i < A_B2)    { s = b1i;   j = i - A_B1; }
    else                  { s = b2i;   j = i - A_B2; }
    dst[i] = ldin(s, j, flag);
}

__global__ void catbias_k(const void* bq, const void* bk, const void* bv,
                          const void* caps, float* __restrict__ dst)
{
    int t = blockIdx.x * 256 + threadIdx.x;
    if (t >= 6 * 1536) return;
    int flag = detect_bf16(caps);
    int l = t / 1536, j = t - l * 1536;
    float v = (j < 512) ? ldin(bq, l * 512 + j, flag)
            : (j < 1024) ? ldin(bk, l * 512 + j - 512, flag)
                         : ldin(bv, l * 512 + j - 1024, flag);
    dst[t] = v;
}

__global__ __launch_bounds__(256) void gather_xin_k(
    const void* __restrict__ sol, const void* __restrict__ caps, const void* __restrict__ emb,
    u16* __restrict__ xin)
{
    const int row = blockIdx.x;
    const int b = row >> 9, s = row & 511;
    const int t = threadIdx.x;
    const int flag = detect_bf16(caps);
    float idxf = ldin(sol, (size_t)row * 4, flag);
    int idx = (int)(idxf + 0.5f);
    if (idx < 0) idx = 0;
    if (idx > 9999) idx = 9999;
    xin[(size_t)row * 288 + t] = f2h_bits(ldin(emb, (size_t)idx * 256 + t, flag));
    if (t < 32) {
        float v = 0.f;
        if (t == 0 && s != 0) {
            float rem = ldin(sol, ((size_t)b * 512) * 4 + 3, flag);
            float cap = ldin(caps, b, flag);
            float dem = ldin(sol, (size_t)row * 4 + 2, flag);
            v = 2.f * (dem - rem) / cap;
        }
        xin[(size_t)row * 288 + 256 + t] = f2h_bits(v);
    }
}

__global__ __launch_bounds__(256) void fixup_enc_k(
    const void* __restrict__ sol, const void* __restrict__ caps, const void* __restrict__ emb,
    const float* __restrict__ arena, float* __restrict__ xf, u16* __restrict__ xb)
{
    const int blk = blockIdx.x;
    const int b = blk & 7;
    const int s = (blk >> 3) ? 511 : 0;
    const int row = b * 512 + s;
    const int t = threadIdx.x;
    __shared__ float e[256];
    __shared__ float nds;
    const int flag = detect_bf16(caps);
    float idxf = ldin(sol, (size_t)row * 4, flag);
    int idx = (int)(idxf + 0.5f);
    if (idx < 0) idx = 0;
    if (idx > 9999) idx = 9999;
    e[t] = ldin(emb, (size_t)idx * 256 + t, flag);
    if (t == 0) {
        float rem = ldin(sol, ((size_t)b * 512) * 4 + 3, flag);
        float cap = ldin(caps, b, flag);
        float dem = ldin(sol, (size_t)row * 4 + 2, flag);
        nds = (s == 0) ? 0.f : 2.f * (dem - rem) / cap;
    }
    __syncthreads();
    const float* W  = (s == 0) ? arena + A_SRCW : arena + A_DEPW;
    const float* Bb = (s == 0) ? arena + A_SRCB : arena + A_DEPB;
    float a0 = 0.f, a1 = 0.f;
    for (int c = 0; c < 256; ++c) {
        float ev = e[c];
        a0 += ev * W[(size_t)c * 512 + t];
        a1 += ev * W[(size_t)c * 512 + t + 256];
    }
    float nd = nds;
    a0 += nd * W[256 * 512 + t] + Bb[t];
    a1 += nd * W[256 * 512 + t + 256] + Bb[t + 256];
    size_t o = (size_t)row * 512;
    xf[o + t] = a0;        xb[o + t] = f2h_bits(a0);
    xf[o + t + 256] = a1;  xb[o + t + 256] = f2h_bits(a1);
}

__global__ __launch_bounds__(256) void feas_k(const float* __restrict__ xf,
                                              const float* __restrict__ arena,
                                              float* __restrict__ out)
{
    int w = blockIdx.x * 4 + (threadIdx.x >> 6);
    if (w >= 8 * 510) return;
    int lane = threadIdx.x & 63;
    int b = w / 510, j = w - b * 510;
    const float* xr = xf + ((size_t)(b * 512 + 1 + j)) * 512;
    const float* fW = arena + A_FEASW;
    float a = 0.f;
#pragma unroll
    for (int i = 0; i < 8; ++i) { int d = lane + 64 * i; a += xr[d] * fW[d]; }
#pragma unroll
    for (int o = 1; o < 64; o <<= 1) a += __shfl_xor(a, o, 64);
    if (lane == 0) out[8160 + b * 510 + j] = a + arena[A_FEASB];
}

__global__ __launch_bounds__(256) void ptr_k(const float* __restrict__ xf,
                                             const float* __restrict__ arena,
                                             float* __restrict__ out)
{
    int w = blockIdx.x * 4 + (threadIdx.x >> 6);
    if (w >= 8 * 510) return;
    int lane = threadIdx.x & 63;
    int b = w / 510, j = w - b * 510;
    const float* xr = xf + ((size_t)(b * 512 + 1 + j)) * 512;
    const float* pWa = arena + A_PW;
    float a0 = 0.f, a1 = 0.f;
#pragma unroll
    for (int i = 0; i < 8; ++i) {
        int d = lane + 64 * i;
        float x = xr[d];
        a0 += x * pWa[d * 2];
        a1 += x * pWa[d * 2 + 1];
    }
#pragma unroll
    for (int o = 1; o < 64; o <<= 1) { a0 += __shfl_xor(a0, o, 64); a1 += __shfl_xor(a1, o, 64); }
    if (lane == 0) {
        out[(size_t)b * 1020 + j]       = a0 + arena[A_PB];
        out[(size_t)b * 1020 + 510 + j] = a1 + arena[A_PB + 1];
    }
}

extern "C" void kernel_launch(void* const* d_in, const int* in_sizes, int n_in,
                              void* d_out, int out_size, void* d_ws, size_t ws_size,
                              hipStream_t stream)
{
    const void* sol   = d_in[0];
    const void* caps  = d_in[1];
    const void* emb   = d_in[2];
    const void* srcW  = d_in[3];
    const void* srcB  = d_in[4];
    const void* candW = d_in[5];
    const void* candB = d_in[6];
    const void* depW  = d_in[7];
    const void* depB  = d_in[8];
    const void* feasW = d_in[9];
    const void* feasB = d_in[10];
    const void* Wq  = d_in[11];
    const void* bq  = d_in[12];
    const void* Wk  = d_in[13];
    const void* bk  = d_in[14];
    const void* Wv  = d_in[15];
    const void* bv  = d_in[16];
    const void* Wo  = d_in[17];
    const void* boi = d_in[18];
    // d_in[19] = s_scale: softmax shift no-op
    const void* W1  = d_in[20];
    const void* b1i = d_in[21];
    const void* W2  = d_in[22];
    const void* b2i = d_in[23];
    const void* pW  = d_in[24];
    const void* pb  = d_in[25];
    float* out = (float*)d_out;

    // workspace
    char* w = (char*)d_ws;
    float* xf    = (float*)w; w += 8388608;   // 4096x512 fp32 residual master
    u16* xb      = (u16*)w;   w += 4194304;   // 4096x512 fp16
    u16* qkvb    = (u16*)w;   w += 12582912;  // 4096x1536 fp16 (q|k|v; v region unused)
    u16* vt      = (u16*)w;   w += 4194304;   // 64x64x512 fp16 (v^T per slice)
    u16* hb      = (u16*)w;   w += 16777216;  // 4096x2048 fp16 FFN hidden
    u16* xin     = hb;                        //  ALIAS: 4096x288 fp16 encoder input
    u16* encW    = hb + 4096 * 288;           //  ALIAS: 512x288 fp16 candW^T
    u16* ob      = (u16*)w;   w += 4194304;   // 4096x512 fp16 attention out
    u16* wqkvT6  = (u16*)w;   w += 9437184;   // 6x 1536x512 fp16
    u16* woT6    = (u16*)w;   w += 3145728;   // 6x 512x512 fp16
    u16* w1T6    = (u16*)w;   w += 12582912;  // 6x 2048x512 fp16
    u16* w2T6    = (u16*)w;   w += 12582912;  // 6x 512x2048 fp16
    float* bqkvf = (float*)w; w += 36864;     // 6x1536 fp32
    float* arena = (float*)w; w += A_TOTAL * 4;

    dim3 tb(32, 8);
    cvt_small_k<<<dim3((A_TOTAL + 255) / 256), 256, 0, stream>>>(
        srcW, srcB, candW, candB, depW, depB, feasW, feasB, pW, pb, boi, b1i, b2i, caps, arena);
    catbias_k<<<dim3(36), 256, 0, stream>>>(bq, bk, bv, caps, bqkvf);

    // Weight transposes hoisted (3 dispatches).
    qkvoT6_k<<<dim3(16, 16, 24), tb, 0, stream>>>(Wq, Wk, Wv, Wo, wqkvT6, woT6, caps);
    transpose_k<1><<<dim3(64, 16, 6), tb, 0, stream>>>(W1, 2048, 0, 0, 1048576,
                                                       w1T6, 512, 0, 1048576, 512, 512, 2048, caps);
    transpose_k<1><<<dim3(16, 64, 6), tb, 0, stream>>>(W2, 512, 0, 0, 1048576,
                                                       w2T6, 2048, 0, 1048576, 2048, 2048, 512, caps);

    // Encoder via MFMA + 16-row fixup.
    gather_xin_k<<<dim3(4096), 256, 0, stream>>>(sol, caps, emb, xin);
    transpose_k<1><<<dim3(16, 9, 1), tb, 0, stream>>>(candW, 512, 0, 0, 0,
                                                      encW, 288, 0, 0, 288, 257, 512, caps);
    gemm_f16<2, 64, 64, 32><<<dim3(8, 64), 256, 0, stream>>>(
        xin, 288, encW, 288,
        xb, 512, arena + A_CANDB, xf, nullptr, 1.f, 0, 512, 288);
    fixup_enc_k<<<dim3(16), 256, 0, stream>>>(sol, caps, emb, arena, xf, xb);

    for (int i = 0; i < 6; ++i) {
        // QKV projection; V columns stream directly into vt (fused transpose).
        // 64x64xBK128: 4 K-steps.
        gemm_f16<0, 64, 64, 128><<<dim3(24, 64), 256, 0, stream>>>(
            xb, 512, wqkvT6 + (long long)i * 786432, 512,
            qkvb, 1536, bqkvf + i * 1536, nullptr, vt, 1.f, 0, 1536, 512);

        // Fused attention: scores+softmax+PV in one dispatch, zero barriers.
        flash_k<<<dim3(4, 64), 256, 0, stream>>>(qkvb, vt, ob);

        // Wo projection + residual into xf/xb. 4 K-steps.
        gemm_f16<0, 64, 64, 128><<<dim3(8, 64), 256, 0, stream>>>(
            ob, 512, woT6 + (long long)i * 262144, 512,
            xb, 512, arena + A_BO + i * 512, xf, nullptr, 1.f, 0, 512, 512);
        if (i == 0)
            feas_k<<<dim3(1020), 256, 0, stream>>>(xf, arena, out);

        // FFN1 (relu) -> hb: 128x128xBK64 (512 WGs, 2 resident/CU, 8 K-steps).
        gemm_f16<0, 128, 128, 64><<<dim3(16, 32), 256, 0, stream>>>(
            xb, 512, w1T6 + (long long)i * 1048576, 512,
            hb, 2048, arena + A_B1 + i * 2048, nullptr, nullptr, 1.f, 1, 2048, 512);

        // FFN2 full-K: 64x64xBK128 (16 K-steps, 2 resident/CU).
        gemm_f16<0, 64, 64, 128><<<dim3(8, 64), 256, 0, stream>>>(
            hb, 2048, w2T6 + (long long)i * 1048576, 2048,
            xb, 512, arena + A_B2 + i * 512, xf, nullptr, 1.f, 0, 512, 2048);
    }
    ptr_k<<<dim3(1020), 256, 0, stream>>>(xf, arena, out);
}

// Round 10
// 858.307 us; speedup vs baseline: 1.7708x; 1.0020x over previous
//
#include <hip/hip_runtime.h>

typedef unsigned short u16;
typedef _Float16 half8 __attribute__((ext_vector_type(8)));
typedef float f32x4 __attribute__((ext_vector_type(4)));

__device__ inline float bf2f(u16 b) { return __builtin_bit_cast(float, ((unsigned)b) << 16); }
__device__ inline float h2f(u16 h) { return (float)__builtin_bit_cast(_Float16, h); }
__device__ inline u16 f2h_bits(float f) { return __builtin_bit_cast(u16, (_Float16)f); }

__device__ inline int detect_bf16(const void* caps) {
    const u16* c = (const u16*)caps;
    int cnt = 0;
#pragma unroll
    for (int k = 0; k < 4; ++k) {
        float v = bf2f(c[2 * k]);
        if (v >= 20.f && v <= 200.f) cnt++;
    }
    return cnt >= 2;
}
__device__ inline float ldin(const void* p, size_t i, int flag) {
    return flag ? bf2f(((const u16*)p)[i]) : ((const float*)p)[i];
}

#define GLOAD_LDS16(g, l)                                                              \
    __builtin_amdgcn_global_load_lds((__attribute__((address_space(1))) const void*)(g), \
                                     (__attribute__((address_space(3))) void*)(l), 16, 0, 0)

// Counted vmcnt wait + compiler memory fence (prevents ds_read hoisting).
template <int N>
__device__ inline void waitv() {
    if constexpr (N == 0)       asm volatile("s_waitcnt vmcnt(0)" ::: "memory");
    else if constexpr (N == 2)  asm volatile("s_waitcnt vmcnt(2)" ::: "memory");
    else if constexpr (N == 4)  asm volatile("s_waitcnt vmcnt(4)" ::: "memory");
    else if constexpr (N == 6)  asm volatile("s_waitcnt vmcnt(6)" ::: "memory");
    else if constexpr (N == 8)  asm volatile("s_waitcnt vmcnt(8)" ::: "memory");
    else if constexpr (N == 12) asm volatile("s_waitcnt vmcnt(12)" ::: "memory");
}
__device__ inline void barrier_raw() {
    asm volatile("" ::: "memory");
    __builtin_amdgcn_s_barrier();
    asm volatile("" ::: "memory");
}

#define A_SRCW 0
#define A_SRCB 131584
#define A_CANDW 132096
#define A_CANDB 263680
#define A_DEPW 264192
#define A_DEPB 395776
#define A_FEASW 396288
#define A_FEASB 396800
#define A_PW 396801
#define A_PB 397825
#define A_BO 397827
#define A_B1 400899
#define A_B2 413187
#define A_TOTAL 416259

// ---------------------------------------------------------------------------
// GEMM with templated BM x BN x BK (unchanged from R9 — at model optimum).
// Law (R5/R7/R8/R9): fixed ~750cyc/block-step floor at 2 resident blocks/CU,
// independent of per-step work -> minimize block-steps/CU = MNK/(256*BM*BN*BK)
// s.t. 2-buffer LDS <= 80KB and grid >= 512. 2-buffer counted-vmcnt pipeline,
// both-sides chunk swizzle, XCD-locality block swizzle.
// ---------------------------------------------------------------------------
template <int CF, int BM, int BN, int BK>
__global__ __launch_bounds__(256) void gemm_f16(
    const u16* __restrict__ A, int lda,
    const u16* __restrict__ B, int ldb,
    void* __restrict__ Cv, int ldc,
    const float* __restrict__ bias, float* __restrict__ resid,
    u16* __restrict__ vtp,
    float scale, int relu, int N, int K)
{
    constexpr int MT = BM / 32;                    // A-frags per wave (2x2 wave grid)
    constexpr int NT = BN / 32;                    // B-frags per wave
    constexpr int CPR = BK / 8;                    // 16B chunks per row
    constexpr int S = (BM / 64 + BN / 64) * (BK / 32);  // VMEM instrs per stage per wave
    __shared__ __attribute__((aligned(16))) u16 As[2][BM * BK];
    __shared__ __attribute__((aligned(16))) u16 Bs[2][BN * BK];

    // XCD-aware remap (bijective; falls back to identity if gy % 8 != 0).
    const int gx = gridDim.x, gy = gridDim.y;
    int mb, nb;
    if ((gy & 7) == 0) {
        int id = blockIdx.x + blockIdx.y * gx;
        int xcd = id & 7, local = id >> 3;
        int mloc = local / gx;
        mb = xcd * (gy >> 3) + mloc;
        nb = local - mloc * gx;
    } else {
        mb = blockIdx.y;
        nb = blockIdx.x;
    }
    const int m0 = mb * BM;
    const int n0 = nb * BN;

    const int t = threadIdx.x, lane = t & 63, wid = t >> 6;
    const int qd = lane >> 4, ml = lane & 15;
    const int wm = (wid >> 1) * (BM / 2), wn = (wid & 1) * (BN / 2);

    f32x4 acc[MT][NT] = {};

    auto stage = [&](int bf, int k0) {
#pragma unroll
        for (int r = 0; r < BM * BK / 2048; ++r) {
            int seg = r * 256 + t;
            int row = seg / CPR;
            int chunk = seg & (CPR - 1);
            int c8 = ((chunk ^ (row & (CPR - 1))) * 8);   // source-side swizzle
            const u16* ga = A + (long long)(m0 + row) * lda + k0 + c8;
            GLOAD_LDS16(ga, As[bf] + (size_t)(seg & ~63) * 8);
        }
#pragma unroll
        for (int r = 0; r < BN * BK / 2048; ++r) {
            int seg = r * 256 + t;
            int row = seg / CPR;
            int chunk = seg & (CPR - 1);
            int c8 = ((chunk ^ (row & (CPR - 1))) * 8);
            int rn = n0 + row;
            if (rn > N - 1) rn = N - 1;
            const u16* gb = B + (long long)rn * ldb + k0 + c8;
            GLOAD_LDS16(gb, Bs[bf] + (size_t)(seg & ~63) * 8);
        }
    };

    auto compute = [&](int bf) {
#pragma unroll
        for (int kk = 0; kk < BK / 32; ++kk) {
            half8 af[MT], bfv[NT];
#pragma unroll
            for (int mt = 0; mt < MT; ++mt) {
                int row = wm + mt * 16 + ml;
                int c = (kk * 4 + qd) ^ (row & (CPR - 1));
                af[mt] = *(const half8*)(As[bf] + (size_t)row * BK + c * 8);
            }
#pragma unroll
            for (int nt = 0; nt < NT; ++nt) {
                int row = wn + nt * 16 + ml;
                int c = (kk * 4 + qd) ^ (row & (CPR - 1));
                bfv[nt] = *(const half8*)(Bs[bf] + (size_t)row * BK + c * 8);
            }
#pragma unroll
            for (int mt = 0; mt < MT; ++mt)
#pragma unroll
                for (int nt = 0; nt < NT; ++nt)
                    acc[mt][nt] = __builtin_amdgcn_mfma_f32_16x16x32_f16(af[mt], bfv[nt], acc[mt][nt], 0, 0, 0);
        }
    };

    // Prologue: fill buffer 0.
    stage(0, 0);

    int buf = 0;
    for (int k0 = 0; k0 < K; k0 += BK) {
        if (k0 > 0) barrier_raw();            // all waves done reading buf^1
        if (k0 + BK < K) {
            stage(buf ^ 1, k0 + BK);          // prefetch next tile
            waitv<S>();                       // own current-tile loads drained
        } else {
            waitv<0>();                       // last tile: drain everything
        }
        barrier_raw();                        // cross-wave publication
        compute(buf);
        buf ^= 1;
    }

#pragma unroll
    for (int nt = 0; nt < NT; ++nt) {
        int col = n0 + wn + nt * 16 + ml;
        if (col >= N) continue;
        float bv = bias ? bias[col] : 0.f;
#pragma unroll
        for (int mt = 0; mt < MT; ++mt) {
#pragma unroll
            for (int r = 0; r < 4; ++r) {
                int rowg = m0 + wm + mt * 16 + qd * 4 + r;
                float v = acc[mt][nt][r] * scale + bv;
                if (relu) v = fmaxf(v, 0.f);
                long long off = (long long)rowg * ldc + col;
                if (CF == 1) {
                    ((float*)Cv)[off] = v;
                } else if (CF == 2) {
                    resid[off] = v;
                    ((u16*)Cv)[off] = f2h_bits(v);
                } else if (resid) {
                    float nv = resid[off] + v;
                    resid[off] = nv;
                    ((u16*)Cv)[off] = f2h_bits(nv);
                } else if (vtp && col >= 1024) {
                    // fused V-transpose: vt[(b*8+h)][vd][s]
                    int b = rowg >> 9, s = rowg & 511;
                    int cv2 = col - 1024;
                    vtp[(size_t)(((b << 3) + (cv2 >> 6)) * 32768 + (cv2 & 63) * 512 + s)] = f2h_bits(v);
                } else {
                    ((u16*)Cv)[off] = f2h_bits(v);
                }
            }
        }
    }
}

// ---------------------------------------------------------------------------
// Fused flash attention, 8 waves x 16 Q-rows over a 128-row tile (R10):
// same blocks (256), same K/V traffic, same Ps footprint as the 4-wave
// version, but 2 waves/SIMD so one wave's MFMA issues under another's
// softmax VALU and per-wave dependency chains halve. Zero barriers (each
// wave touches only its own 16-row Ps slab). setprio(1) around MFMA
// clusters; XCD swizzle keeps a head's q-tiles on one XCD.
// ---------------------------------------------------------------------------
__global__ __launch_bounds__(512) void flash_k(
    const u16* __restrict__ qkv,  // [4096][1536] fp16 (q|k|v)
    const u16* __restrict__ vt,   // [64][64][512] fp16  v^T per slice
    u16* __restrict__ ob)         // [4096][512] fp16
{
    __shared__ __attribute__((aligned(16))) u16 Ps[128 * 136];

    // grid is (4, 64) fixed: id -> (z, q-tile) with same-z tiles on one XCD.
    int id = blockIdx.x + (blockIdx.y << 2);
    int xcd = id & 7, local = id >> 3;
    const int z = (xcd << 3) + (local >> 2);  // b*8 + h
    const int q0 = (local & 3) * 128;

    const int b = z >> 3, h = z & 7;
    const long long qbase = (long long)b * 786432;
    const u16* Q  = qkv + qbase + (long long)q0 * 1536 + h * 64;
    const u16* Kg = qkv + qbase + 512 + h * 64;
    const u16* Vg = vt + (long long)z * 32768;

    const int t = threadIdx.x, lane = t & 63, wid = t >> 6;  // wid 0..7
    const int qd = lane >> 4, ml = lane & 15;
    const int wm = wid * 16;  // this wave's 16 Q-rows

    half8 qf[2];
#pragma unroll
    for (int kf = 0; kf < 2; ++kf)
        qf[kf] = *(const half8*)(Q + (long long)(wm + ml) * 1536 + kf * 32 + qd * 8);

    f32x4 oacc[4] = {};
    float mrow[4], lrow[4];
#pragma unroll
    for (int r = 0; r < 4; ++r) { mrow[r] = -3.0e38f; lrow[r] = 0.f; }

    for (int kb = 0; kb < 4; ++kb) {
        f32x4 sacc[8] = {};
        __builtin_amdgcn_s_setprio(1);
#pragma unroll
        for (int nt = 0; nt < 8; ++nt) {
#pragma unroll
            for (int kf = 0; kf < 2; ++kf) {
                half8 bf = *(const half8*)(Kg + (long long)(kb * 128 + nt * 16 + ml) * 1536 + kf * 32 + qd * 8);
                sacc[nt] = __builtin_amdgcn_mfma_f32_16x16x32_f16(qf[kf], bf, sacc[nt], 0, 0, 0);
            }
        }
        __builtin_amdgcn_s_setprio(0);
#pragma unroll
        for (int r = 0; r < 4; ++r) {
            float mx = -3.0e38f;
#pragma unroll
            for (int nt = 0; nt < 8; ++nt) {
                float s = sacc[nt][r] * 0.125f;
                sacc[nt][r] = s;
                mx = fmaxf(mx, s);
            }
#pragma unroll
            for (int o = 1; o < 16; o <<= 1) mx = fmaxf(mx, __shfl_xor(mx, o, 64));
            float mnew = fmaxf(mrow[r], mx);
            float alpha = __expf(mrow[r] - mnew);
            mrow[r] = mnew;
            lrow[r] *= alpha;
#pragma unroll
            for (int nt = 0; nt < 4; ++nt) oacc[nt][r] *= alpha;
            float ps = 0.f;
#pragma unroll
            for (int nt = 0; nt < 8; ++nt) {
                float p = __expf(sacc[nt][r] - mnew);
                sacc[nt][r] = p;
                ps += p;
            }
#pragma unroll
            for (int o = 1; o < 16; o <<= 1) ps += __shfl_xor(ps, o, 64);
            lrow[r] += ps;
        }
        // P -> LDS (wave-private 16-row slab: no barrier).
#pragma unroll
        for (int nt = 0; nt < 8; ++nt)
#pragma unroll
            for (int r = 0; r < 4; ++r)
                Ps[(wm + qd * 4 + r) * 136 + nt * 16 + ml] = f2h_bits(sacc[nt][r]);
        __builtin_amdgcn_s_setprio(1);
#pragma unroll
        for (int kf = 0; kf < 4; ++kf) {
            half8 pf = *(const half8*)(Ps + (wm + ml) * 136 + kf * 32 + qd * 8);
#pragma unroll
            for (int nt = 0; nt < 4; ++nt) {
                half8 vf = *(const half8*)(Vg + (long long)(nt * 16 + ml) * 512 + kb * 128 + kf * 32 + qd * 8);
                oacc[nt] = __builtin_amdgcn_mfma_f32_16x16x32_f16(pf, vf, oacc[nt], 0, 0, 0);
            }
        }
        __builtin_amdgcn_s_setprio(0);
    }

#pragma unroll
    for (int r = 0; r < 4; ++r) {
        float inv = 1.f / lrow[r];
        long long rowg = (long long)b * 512 + q0 + wm + qd * 4 + r;
#pragma unroll
        for (int nt = 0; nt < 4; ++nt)
            ob[rowg * 512 + h * 64 + nt * 16 + ml] = f2h_bits(oacc[nt][r] * inv);
    }
}

template <int MODE>
__global__ void transpose_k(const void* __restrict__ src_, int s_ld, long long s_off,
                            long long s_so, long long s_si,
                            u16* __restrict__ dst, int d_ld, long long d_so, long long d_si,
                            int R, int Rs, int C, const void* caps)
{
    __shared__ u16 tile[32][33];
    const int z = blockIdx.z;
    const long long sb = s_off + (long long)(z >> 3) * s_so + (long long)(z & 7) * s_si;
    dst += (long long)(z >> 3) * d_so + (long long)(z & 7) * d_si;
    const int c0 = blockIdx.x * 32, r0 = blockIdx.y * 32;
    const int tx = threadIdx.x, ty = threadIdx.y;
    const int flag = (MODE == 1) ? detect_bf16(caps) : 0;
#pragma unroll
    for (int i = 0; i < 4; ++i) {
        int r = r0 + ty + i * 8, c = c0 + tx;
        if (r < R && c < C) {
            u16 v = 0;
            if (r < Rs) {
                size_t idx = (size_t)(sb + (long long)r * s_ld + c);
                if (MODE == 1) v = f2h_bits(ldin(src_, idx, flag));
                else           v = ((const u16*)src_)[idx];
            }
            tile[ty + i * 8][tx] = v;
        }
    }
    __syncthreads();
#pragma unroll
    for (int i = 0; i < 4; ++i) {
        int r = r0 + tx, c = c0 + ty + i * 8;
        if (r < R && c < C) dst[(long long)c * d_ld + r] = tile[tx][ty + i * 8];
    }
}

__global__ void qkvoT6_k(const void* Wq, const void* Wk, const void* Wv, const void* Wo,
                         u16* __restrict__ wqkvT6, u16* __restrict__ woT6,
                         const void* caps)
{
    __shared__ u16 tile[32][33];
    const int z = blockIdx.z;
    const int layer = z >> 2, sel = z & 3;
    const void* src = (sel == 0) ? Wq : (sel == 1) ? Wk : (sel == 2) ? Wv : Wo;
    u16* dst = (sel < 3) ? (wqkvT6 + (long long)layer * 786432 + (long long)sel * 262144)
                         : (woT6 + (long long)layer * 262144);
    const long long oW = (long long)layer * 262144;
    const int c0 = blockIdx.x * 32, r0 = blockIdx.y * 32;
    const int tx = threadIdx.x, ty = threadIdx.y;
    const int flag = detect_bf16(caps);
#pragma unroll
    for (int i = 0; i < 4; ++i) {
        int r = r0 + ty + i * 8, c = c0 + tx;
        tile[ty + i * 8][tx] = f2h_bits(ldin(src, (size_t)(oW + (long long)r * 512 + c), flag));
    }
    __syncthreads();
#pragma unroll
    for (int i = 0; i < 4; ++i) {
        int r = r0 + tx, c = c0 + ty + i * 8;
        dst[(long long)c * 512 + r] = tile[tx][ty + i * 8];
    }
}

__global__ void cvt_small_k(const void* srcW, const void* srcB, const void* candW, const void* candB,
                            const void* depW, const void* depB, const void* feasW, const void* feasB,
                            const void* pW, const void* pb, const void* boi, const void* b1i,
                            const void* b2i, const void* caps, float* __restrict__ dst)
{
    int i = blockIdx.x * 256 + threadIdx.x;
    if (i >= A_TOTAL) return;
    int flag = detect_bf16(caps);
    const void* s; int j;
    if      (i < A_SRCB)  { s = srcW;  j = i - A_SRCW; }
    else if (i < A_CANDW) { s = srcB;  j = i - A_SRCB; }
    else if (i < A_CANDB) { s = candW; j = i - A_CANDW; }
    else if (i < A_DEPW)  { s = candB; j = i - A_CANDB; }
    else if (i < A_DEPB)  { s = depW;  j = i - A_DEPW; }
    else if (i < A_FEASW) { s = depB;  j = i - A_DEPB; }
    else if (i < A_FEASB) { s = feasW; j = i - A_FEASW; }
    else if (i < A_PW)    { s = feasB; j = i - A_FEASB; }
    else if (i < A_PB)    { s = pW;    j = i - A_PW; }
    else if (i < A_BO)    { s = pb;    j = i - A_PB; }
    else if (i < A_B1)    { s = boi;   j = i - A_BO; }
    else if (i < A_B2)    { s = b1i;   j = i - A_B1; }
    else                  { s = b2i;   j = i - A_B2; }
    dst[i] = ldin(s, j, flag);
}

__global__ void catbias_k(const void* bq, const void* bk, const void* bv,
                          const void* caps, float* __restrict__ dst)
{
    int t = blockIdx.x * 256 + threadIdx.x;
    if (t >= 6 * 1536) return;
    int flag = detect_bf16(caps);
    int l = t / 1536, j = t - l * 1536;
    float v = (j < 512) ? ldin(bq, l * 512 + j, flag)
            : (j < 1024) ? ldin(bk, l * 512 + j - 512, flag)
                         : ldin(bv, l * 512 + j - 1024, flag);
    dst[t] = v;
}

__global__ __launch_bounds__(256) void gather_xin_k(
    const void* __restrict__ sol, const void* __restrict__ caps, const void* __restrict__ emb,
    u16* __restrict__ xin)
{
    const int row = blockIdx.x;
    const int b = row >> 9, s = row & 511;
    const int t = threadIdx.x;
    const int flag = detect_bf16(caps);
    float idxf = ldin(sol, (size_t)row * 4, flag);
    int idx = (int)(idxf + 0.5f);
    if (idx < 0) idx = 0;
    if (idx > 9999) idx = 9999;
    xin[(size_t)row * 288 + t] = f2h_bits(ldin(emb, (size_t)idx * 256 + t, flag));
    if (t < 32) {
        float v = 0.f;
        if (t == 0 && s != 0) {
            float rem = ldin(sol, ((size_t)b * 512) * 4 + 3, flag);
            float cap = ldin(caps, b, flag);
            float dem = ldin(sol, (size_t)row * 4 + 2, flag);
            v = 2.f * (dem - rem) / cap;
        }
        xin[(size_t)row * 288 + 256 + t] = f2h_bits(v);
    }
}

__global__ __launch_bounds__(256) void fixup_enc_k(
    const void* __restrict__ sol, const void* __restrict__ caps, const void* __restrict__ emb,
    const float* __restrict__ arena, float* __restrict__ xf, u16* __restrict__ xb)
{
    const int blk = blockIdx.x;
    const int b = blk & 7;
    const int s = (blk >> 3) ? 511 : 0;
    const int row = b * 512 + s;
    const int t = threadIdx.x;
    __shared__ float e[256];
    __shared__ float nds;
    const int flag = detect_bf16(caps);
    float idxf = ldin(sol, (size_t)row * 4, flag);
    int idx = (int)(idxf + 0.5f);
    if (idx < 0) idx = 0;
    if (idx > 9999) idx = 9999;
    e[t] = ldin(emb, (size_t)idx * 256 + t, flag);
    if (t == 0) {
        float rem = ldin(sol, ((size_t)b * 512) * 4 + 3, flag);
        float cap = ldin(caps, b, flag);
        float dem = ldin(sol, (size_t)row * 4 + 2, flag);
        nds = (s == 0) ? 0.f : 2.f * (dem - rem) / cap;
    }
    __syncthreads();
    const float* W  = (s == 0) ? arena + A_SRCW : arena + A_DEPW;
    const float* Bb = (s == 0) ? arena + A_SRCB : arena + A_DEPB;
    float a0 = 0.f, a1 = 0.f;
    for (int c = 0; c < 256; ++c) {
        float ev = e[c];
        a0 += ev * W[(size_t)c * 512 + t];
        a1 += ev * W[(size_t)c * 512 + t + 256];
    }
    float nd = nds;
    a0 += nd * W[256 * 512 + t] + Bb[t];
    a1 += nd * W[256 * 512 + t + 256] + Bb[t + 256];
    size_t o = (size_t)row * 512;
    xf[o + t] = a0;        xb[o + t] = f2h_bits(a0);
    xf[o + t + 256] = a1;  xb[o + t + 256] = f2h_bits(a1);
}

__global__ __launch_bounds__(256) void feas_k(const float* __restrict__ xf,
                                              const float* __restrict__ arena,
                                              float* __restrict__ out)
{
    int w = blockIdx.x * 4 + (threadIdx.x >> 6);
    if (w >= 8 * 510) return;
    int lane = threadIdx.x & 63;
    int b = w / 510, j = w - b * 510;
    const float* xr = xf + ((size_t)(b * 512 + 1 + j)) * 512;
    const float* fW = arena + A_FEASW;
    float a = 0.f;
#pragma unroll
    for (int i = 0; i < 8; ++i) { int d = lane + 64 * i; a += xr[d] * fW[d]; }
#pragma unroll
    for (int o = 1; o < 64; o <<= 1) a += __shfl_xor(a, o, 64);
    if (lane == 0) out[8160 + b * 510 + j] = a + arena[A_FEASB];
}

__global__ __launch_bounds__(256) void ptr_k(const float* __restrict__ xf,
                                             const float* __restrict__ arena,
                                             float* __restrict__ out)
{
    int w = blockIdx.x * 4 + (threadIdx.x >> 6);
    if (w >= 8 * 510) return;
    int lane = threadIdx.x & 63;
    int b = w / 510, j = w - b * 510;
    const float* xr = xf + ((size_t)(b * 512 + 1 + j)) * 512;
    const float* pWa = arena + A_PW;
    float a0 = 0.f, a1 = 0.f;
#pragma unroll
    for (int i = 0; i < 8; ++i) {
        int d = lane + 64 * i;
        float x = xr[d];
        a0 += x * pWa[d * 2];
        a1 += x * pWa[d * 2 + 1];
    }
#pragma unroll
    for (int o = 1; o < 64; o <<= 1) { a0 += __shfl_xor(a0, o, 64); a1 += __shfl_xor(a1, o, 64); }
    if (lane == 0) {
        out[(size_t)b * 1020 + j]       = a0 + arena[A_PB];
        out[(size_t)b * 1020 + 510 + j] = a1 + arena[A_PB + 1];
    }
}

extern "C" void kernel_launch(void* const* d_in, const int* in_sizes, int n_in,
                              void* d_out, int out_size, void* d_ws, size_t ws_size,
                              hipStream_t stream)
{
    const void* sol   = d_in[0];
    const void* caps  = d_in[1];
    const void* emb   = d_in[2];
    const void* srcW  = d_in[3];
    const void* srcB  = d_in[4];
    const void* candW = d_in[5];
    const void* candB = d_in[6];
    const void* depW  = d_in[7];
    const void* depB  = d_in[8];
    const void* feasW = d_in[9];
    const void* feasB = d_in[10];
    const void* Wq  = d_in[11];
    const void* bq  = d_in[12];
    const void* Wk  = d_in[13];
    const void* bk  = d_in[14];
    const void* Wv  = d_in[15];
    const void* bv  = d_in[16];
    const void* Wo  = d_in[17];
    const void* boi = d_in[18];
    // d_in[19] = s_scale: softmax shift no-op
    const void* W1  = d_in[20];
    const void* b1i = d_in[21];
    const void* W2  = d_in[22];
    const void* b2i = d_in[23];
    const void* pW  = d_in[24];
    const void* pb  = d_in[25];
    float* out = (float*)d_out;

    // workspace
    char* w = (char*)d_ws;
    float* xf    = (float*)w; w += 8388608;   // 4096x512 fp32 residual master
    u16* xb      = (u16*)w;   w += 4194304;   // 4096x512 fp16
    u16* qkvb    = (u16*)w;   w += 12582912;  // 4096x1536 fp16 (q|k|v; v region unused)
    u16* vt      = (u16*)w;   w += 4194304;   // 64x64x512 fp16 (v^T per slice)
    u16* hb      = (u16*)w;   w += 16777216;  // 4096x2048 fp16 FFN hidden
    u16* xin     = hb;                        //  ALIAS: 4096x288 fp16 encoder input
    u16* encW    = hb + 4096 * 288;           //  ALIAS: 512x288 fp16 candW^T
    u16* ob      = (u16*)w;   w += 4194304;   // 4096x512 fp16 attention out
    u16* wqkvT6  = (u16*)w;   w += 9437184;   // 6x 1536x512 fp16
    u16* woT6    = (u16*)w;   w += 3145728;   // 6x 512x512 fp16
    u16* w1T6    = (u16*)w;   w += 12582912;  // 6x 2048x512 fp16
    u16* w2T6    = (u16*)w;   w += 12582912;  // 6x 512x2048 fp16
    float* bqkvf = (float*)w; w += 36864;     // 6x1536 fp32
    float* arena = (float*)w; w += A_TOTAL * 4;

    dim3 tb(32, 8);
    cvt_small_k<<<dim3((A_TOTAL + 255) / 256), 256, 0, stream>>>(
        srcW, srcB, candW, candB, depW, depB, feasW, feasB, pW, pb, boi, b1i, b2i, caps, arena);
    catbias_k<<<dim3(36), 256, 0, stream>>>(bq, bk, bv, caps, bqkvf);

    // Weight transposes hoisted (3 dispatches).
    qkvoT6_k<<<dim3(16, 16, 24), tb, 0, stream>>>(Wq, Wk, Wv, Wo, wqkvT6, woT6, caps);
    transpose_k<1><<<dim3(64, 16, 6), tb, 0, stream>>>(W1, 2048, 0, 0, 1048576,
                                                       w1T6, 512, 0, 1048576, 512, 512, 2048, caps);
    transpose_k<1><<<dim3(16, 64, 6), tb, 0, stream>>>(W2, 512, 0, 0, 1048576,
                                                       w2T6, 2048, 0, 1048576, 2048, 2048, 512, caps);

    // Encoder via MFMA + 16-row fixup.
    gather_xin_k<<<dim3(4096), 256, 0, stream>>>(sol, caps, emb, xin);
    transpose_k<1><<<dim3(16, 9, 1), tb, 0, stream>>>(candW, 512, 0, 0, 0,
                                                      encW, 288, 0, 0, 288, 257, 512, caps);
    gemm_f16<2, 64, 64, 32><<<dim3(8, 64), 256, 0, stream>>>(
        xin, 288, encW, 288,
        xb, 512, arena + A_CANDB, xf, nullptr, 1.f, 0, 512, 288);
    fixup_enc_k<<<dim3(16), 256, 0, stream>>>(sol, caps, emb, arena, xf, xb);

    for (int i = 0; i < 6; ++i) {
        // QKV projection; V columns stream directly into vt (fused transpose).
        // 64x64xBK128: 4 K-steps.
        gemm_f16<0, 64, 64, 128><<<dim3(24, 64), 256, 0, stream>>>(
            xb, 512, wqkvT6 + (long long)i * 786432, 512,
            qkvb, 1536, bqkvf + i * 1536, nullptr, vt, 1.f, 0, 1536, 512);

        // Fused attention: scores+softmax+PV in one dispatch, zero barriers.
        // 8 waves x 16 Q-rows (2 waves/SIMD TLP).
        flash_k<<<dim3(4, 64), 512, 0, stream>>>(qkvb, vt, ob);

        // Wo projection + residual into xf/xb. 4 K-steps.
        gemm_f16<0, 64, 64, 128><<<dim3(8, 64), 256, 0, stream>>>(
            ob, 512, woT6 + (long long)i * 262144, 512,
            xb, 512, arena + A_BO + i * 512, xf, nullptr, 1.f, 0, 512, 512);
        if (i == 0)
            feas_k<<<dim3(1020), 256, 0, stream>>>(xf, arena, out);

        // FFN1 (relu) -> hb: 128x128xBK64 (512 WGs, 2 resident/CU, 8 K-steps).
        gemm_f16<0, 128, 128, 64><<<dim3(16, 32), 256, 0, stream>>>(
            xb, 512, w1T6 + (long long)i * 1048576, 512,
            hb, 2048, arena + A_B1 + i * 2048, nullptr, nullptr, 1.f, 1, 2048, 512);

        // FFN2 full-K: 64x64xBK128 (16 K-steps, 2 resident/CU).
        gemm_f16<0, 64, 64, 128><<<dim3(8, 64), 256, 0, stream>>>(
            hb, 2048, w2T6 + (long long)i * 1048576, 2048,
            xb, 512, arena + A_B2 + i * 512, xf, nullptr, 1.f, 0, 512, 2048);
    }
    ptr_k<<<dim3(1020), 256, 0, stream>>>(xf, arena, out);
}

// Round 11
// 846.321 us; speedup vs baseline: 1.7959x; 1.0142x over previous
//
#include <hip/hip_runtime.h>

typedef unsigned short u16;
typedef _Float16 half8 __attribute__((ext_vector_type(8)));
typedef float f32x4 __attribute__((ext_vector_type(4)));

__device__ inline float bf2f(u16 b) { return __builtin_bit_cast(float, ((unsigned)b) << 16); }
__device__ inline float h2f(u16 h) { return (float)__builtin_bit_cast(_Float16, h); }
__device__ inline u16 f2h_bits(float f) { return __builtin_bit_cast(u16, (_Float16)f); }

__device__ inline int detect_bf16(const void* caps) {
    const u16* c = (const u16*)caps;
    int cnt = 0;
#pragma unroll
    for (int k = 0; k < 4; ++k) {
        float v = bf2f(c[2 * k]);
        if (v >= 20.f && v <= 200.f) cnt++;
    }
    return cnt >= 2;
}
__device__ inline float ldin(const void* p, size_t i, int flag) {
    return flag ? bf2f(((const u16*)p)[i]) : ((const float*)p)[i];
}

#define GLOAD_LDS16(g, l)                                                              \
    __builtin_amdgcn_global_load_lds((__attribute__((address_space(1))) const void*)(g), \
                                     (__attribute__((address_space(3))) void*)(l), 16, 0, 0)

// Counted vmcnt wait + compiler memory fence (prevents ds_read hoisting).
template <int N>
__device__ inline void waitv() {
    if constexpr (N == 0)       asm volatile("s_waitcnt vmcnt(0)" ::: "memory");
    else if constexpr (N == 2)  asm volatile("s_waitcnt vmcnt(2)" ::: "memory");
    else if constexpr (N == 4)  asm volatile("s_waitcnt vmcnt(4)" ::: "memory");
    else if constexpr (N == 6)  asm volatile("s_waitcnt vmcnt(6)" ::: "memory");
    else if constexpr (N == 8)  asm volatile("s_waitcnt vmcnt(8)" ::: "memory");
    else if constexpr (N == 12) asm volatile("s_waitcnt vmcnt(12)" ::: "memory");
}
__device__ inline void barrier_raw() {
    asm volatile("" ::: "memory");
    __builtin_amdgcn_s_barrier();
    asm volatile("" ::: "memory");
}

#define A_SRCW 0
#define A_SRCB 131584
#define A_CANDW 132096
#define A_CANDB 263680
#define A_DEPW 264192
#define A_DEPB 395776
#define A_FEASW 396288
#define A_FEASB 396800
#define A_PW 396801
#define A_PB 397825
#define A_BO 397827
#define A_B1 400899
#define A_B2 413187
#define A_TOTAL 416259

// ---------------------------------------------------------------------------
// GEMM with templated BM x BN x BK (unchanged from R9 — at model optimum).
// Law (R5/R7/R8/R9): fixed ~750cyc/block-step floor at 2 resident blocks/CU,
// independent of per-step work -> minimize block-steps/CU = MNK/(256*BM*BN*BK)
// s.t. 2-buffer LDS <= 80KB and grid >= 512. 2-buffer counted-vmcnt pipeline,
// both-sides chunk swizzle, XCD-locality block swizzle.
// ---------------------------------------------------------------------------
template <int CF, int BM, int BN, int BK>
__global__ __launch_bounds__(256) void gemm_f16(
    const u16* __restrict__ A, int lda,
    const u16* __restrict__ B, int ldb,
    void* __restrict__ Cv, int ldc,
    const float* __restrict__ bias, float* __restrict__ resid,
    u16* __restrict__ vtp,
    float scale, int relu, int N, int K)
{
    constexpr int MT = BM / 32;                    // A-frags per wave (2x2 wave grid)
    constexpr int NT = BN / 32;                    // B-frags per wave
    constexpr int CPR = BK / 8;                    // 16B chunks per row
    constexpr int S = (BM / 64 + BN / 64) * (BK / 32);  // VMEM instrs per stage per wave
    __shared__ __attribute__((aligned(16))) u16 As[2][BM * BK];
    __shared__ __attribute__((aligned(16))) u16 Bs[2][BN * BK];

    // XCD-aware remap (bijective; falls back to identity if gy % 8 != 0).
    const int gx = gridDim.x, gy = gridDim.y;
    int mb, nb;
    if ((gy & 7) == 0) {
        int id = blockIdx.x + blockIdx.y * gx;
        int xcd = id & 7, local = id >> 3;
        int mloc = local / gx;
        mb = xcd * (gy >> 3) + mloc;
        nb = local - mloc * gx;
    } else {
        mb = blockIdx.y;
        nb = blockIdx.x;
    }
    const int m0 = mb * BM;
    const int n0 = nb * BN;

    const int t = threadIdx.x, lane = t & 63, wid = t >> 6;
    const int qd = lane >> 4, ml = lane & 15;
    const int wm = (wid >> 1) * (BM / 2), wn = (wid & 1) * (BN / 2);

    f32x4 acc[MT][NT] = {};

    auto stage = [&](int bf, int k0) {
#pragma unroll
        for (int r = 0; r < BM * BK / 2048; ++r) {
            int seg = r * 256 + t;
            int row = seg / CPR;
            int chunk = seg & (CPR - 1);
            int c8 = ((chunk ^ (row & (CPR - 1))) * 8);   // source-side swizzle
            const u16* ga = A + (long long)(m0 + row) * lda + k0 + c8;
            GLOAD_LDS16(ga, As[bf] + (size_t)(seg & ~63) * 8);
        }
#pragma unroll
        for (int r = 0; r < BN * BK / 2048; ++r) {
            int seg = r * 256 + t;
            int row = seg / CPR;
            int chunk = seg & (CPR - 1);
            int c8 = ((chunk ^ (row & (CPR - 1))) * 8);
            int rn = n0 + row;
            if (rn > N - 1) rn = N - 1;
            const u16* gb = B + (long long)rn * ldb + k0 + c8;
            GLOAD_LDS16(gb, Bs[bf] + (size_t)(seg & ~63) * 8);
        }
    };

    auto compute = [&](int bf) {
#pragma unroll
        for (int kk = 0; kk < BK / 32; ++kk) {
            half8 af[MT], bfv[NT];
#pragma unroll
            for (int mt = 0; mt < MT; ++mt) {
                int row = wm + mt * 16 + ml;
                int c = (kk * 4 + qd) ^ (row & (CPR - 1));
                af[mt] = *(const half8*)(As[bf] + (size_t)row * BK + c * 8);
            }
#pragma unroll
            for (int nt = 0; nt < NT; ++nt) {
                int row = wn + nt * 16 + ml;
                int c = (kk * 4 + qd) ^ (row & (CPR - 1));
                bfv[nt] = *(const half8*)(Bs[bf] + (size_t)row * BK + c * 8);
            }
#pragma unroll
            for (int mt = 0; mt < MT; ++mt)
#pragma unroll
                for (int nt = 0; nt < NT; ++nt)
                    acc[mt][nt] = __builtin_amdgcn_mfma_f32_16x16x32_f16(af[mt], bfv[nt], acc[mt][nt], 0, 0, 0);
        }
    };

    // Prologue: fill buffer 0.
    stage(0, 0);

    int buf = 0;
    for (int k0 = 0; k0 < K; k0 += BK) {
        if (k0 > 0) barrier_raw();            // all waves done reading buf^1
        if (k0 + BK < K) {
            stage(buf ^ 1, k0 + BK);          // prefetch next tile
            waitv<S>();                       // own current-tile loads drained
        } else {
            waitv<0>();                       // last tile: drain everything
        }
        barrier_raw();                        // cross-wave publication
        compute(buf);
        buf ^= 1;
    }

#pragma unroll
    for (int nt = 0; nt < NT; ++nt) {
        int col = n0 + wn + nt * 16 + ml;
        if (col >= N) continue;
        float bv = bias ? bias[col] : 0.f;
#pragma unroll
        for (int mt = 0; mt < MT; ++mt) {
#pragma unroll
            for (int r = 0; r < 4; ++r) {
                int rowg = m0 + wm + mt * 16 + qd * 4 + r;
                float v = acc[mt][nt][r] * scale + bv;
                if (relu) v = fmaxf(v, 0.f);
                long long off = (long long)rowg * ldc + col;
                if (CF == 1) {
                    ((float*)Cv)[off] = v;
                } else if (CF == 2) {
                    resid[off] = v;
                    ((u16*)Cv)[off] = f2h_bits(v);
                } else if (resid) {
                    float nv = resid[off] + v;
                    resid[off] = nv;
                    ((u16*)Cv)[off] = f2h_bits(nv);
                } else if (vtp && col >= 1024) {
                    // fused V-transpose: vt[(b*8+h)][vd][s]
                    int b = rowg >> 9, s = rowg & 511;
                    int cv2 = col - 1024;
                    vtp[(size_t)(((b << 3) + (cv2 >> 6)) * 32768 + (cv2 & 63) * 512 + s)] = f2h_bits(v);
                } else {
                    ((u16*)Cv)[off] = f2h_bits(v);
                }
            }
        }
    }
}

// ---------------------------------------------------------------------------
// Fused flash attention, 8 waves x 16 Q-rows over a 128-row tile (R10).
// Zero barriers; setprio(1) around MFMA clusters; XCD swizzle.
// ---------------------------------------------------------------------------
__global__ __launch_bounds__(512) void flash_k(
    const u16* __restrict__ qkv,  // [4096][1536] fp16 (q|k|v)
    const u16* __restrict__ vt,   // [64][64][512] fp16  v^T per slice
    u16* __restrict__ ob)         // [4096][512] fp16
{
    __shared__ __attribute__((aligned(16))) u16 Ps[128 * 136];

    int id = blockIdx.x + (blockIdx.y << 2);
    int xcd = id & 7, local = id >> 3;
    const int z = (xcd << 3) + (local >> 2);  // b*8 + h
    const int q0 = (local & 3) * 128;

    const int b = z >> 3, h = z & 7;
    const long long qbase = (long long)b * 786432;
    const u16* Q  = qkv + qbase + (long long)q0 * 1536 + h * 64;
    const u16* Kg = qkv + qbase + 512 + h * 64;
    const u16* Vg = vt + (long long)z * 32768;

    const int t = threadIdx.x, lane = t & 63, wid = t >> 6;  // wid 0..7
    const int qd = lane >> 4, ml = lane & 15;
    const int wm = wid * 16;  // this wave's 16 Q-rows

    half8 qf[2];
#pragma unroll
    for (int kf = 0; kf < 2; ++kf)
        qf[kf] = *(const half8*)(Q + (long long)(wm + ml) * 1536 + kf * 32 + qd * 8);

    f32x4 oacc[4] = {};
    float mrow[4], lrow[4];
#pragma unroll
    for (int r = 0; r < 4; ++r) { mrow[r] = -3.0e38f; lrow[r] = 0.f; }

    for (int kb = 0; kb < 4; ++kb) {
        f32x4 sacc[8] = {};
        __builtin_amdgcn_s_setprio(1);
#pragma unroll
        for (int nt = 0; nt < 8; ++nt) {
#pragma unroll
            for (int kf = 0; kf < 2; ++kf) {
                half8 bf = *(const half8*)(Kg + (long long)(kb * 128 + nt * 16 + ml) * 1536 + kf * 32 + qd * 8);
                sacc[nt] = __builtin_amdgcn_mfma_f32_16x16x32_f16(qf[kf], bf, sacc[nt], 0, 0, 0);
            }
        }
        __builtin_amdgcn_s_setprio(0);
#pragma unroll
        for (int r = 0; r < 4; ++r) {
            float mx = -3.0e38f;
#pragma unroll
            for (int nt = 0; nt < 8; ++nt) {
                float s = sacc[nt][r] * 0.125f;
                sacc[nt][r] = s;
                mx = fmaxf(mx, s);
            }
#pragma unroll
            for (int o = 1; o < 16; o <<= 1) mx = fmaxf(mx, __shfl_xor(mx, o, 64));
            float mnew = fmaxf(mrow[r], mx);
            float alpha = __expf(mrow[r] - mnew);
            mrow[r] = mnew;
            lrow[r] *= alpha;
#pragma unroll
            for (int nt = 0; nt < 4; ++nt) oacc[nt][r] *= alpha;
            float ps = 0.f;
#pragma unroll
            for (int nt = 0; nt < 8; ++nt) {
                float p = __expf(sacc[nt][r] - mnew);
                sacc[nt][r] = p;
                ps += p;
            }
#pragma unroll
            for (int o = 1; o < 16; o <<= 1) ps += __shfl_xor(ps, o, 64);
            lrow[r] += ps;
        }
        // P -> LDS (wave-private 16-row slab: no barrier).
#pragma unroll
        for (int nt = 0; nt < 8; ++nt)
#pragma unroll
            for (int r = 0; r < 4; ++r)
                Ps[(wm + qd * 4 + r) * 136 + nt * 16 + ml] = f2h_bits(sacc[nt][r]);
        __builtin_amdgcn_s_setprio(1);
#pragma unroll
        for (int kf = 0; kf < 4; ++kf) {
            half8 pf = *(const half8*)(Ps + (wm + ml) * 136 + kf * 32 + qd * 8);
#pragma unroll
            for (int nt = 0; nt < 4; ++nt) {
                half8 vf = *(const half8*)(Vg + (long long)(nt * 16 + ml) * 512 + kb * 128 + kf * 32 + qd * 8);
                oacc[nt] = __builtin_amdgcn_mfma_f32_16x16x32_f16(pf, vf, oacc[nt], 0, 0, 0);
            }
        }
        __builtin_amdgcn_s_setprio(0);
    }

#pragma unroll
    for (int r = 0; r < 4; ++r) {
        float inv = 1.f / lrow[r];
        long long rowg = (long long)b * 512 + q0 + wm + qd * 4 + r;
#pragma unroll
        for (int nt = 0; nt < 4; ++nt)
            ob[rowg * 512 + h * 64 + nt * 16 + ml] = f2h_bits(oacc[nt][r] * inv);
    }
}

// ---------------------------------------------------------------------------
// prep_k: ALL setup work in ONE dispatch (R11). Sub-tasks are mutually
// independent; merging removes 6 launch gaps and lets the BW-bound
// transposes/gather fill the machine concurrently. Block-range switch,
// block-uniform branches.
//   [0,1627)        cvt_small  (arena fp32)
//   [1627,1663)     catbias    (bqkvf)
//   [1663,7807)     Wq/Wk/Wv/Wo transpose -> wqkvT6 / woT6   (24 z x 256)
//   [7807,13951)    W1 transpose -> w1T6   (6 z x 64x16)
//   [13951,20095)   W2 transpose -> w2T6   (6 z x 16x64)
//   [20095,20239)   candW transpose -> encW (16x9)
//   [20239,24335)   gather_xin (4096 rows)
// ---------------------------------------------------------------------------
__device__ inline void tr_body(const void* src_, int s_ld, long long sb,
                               u16* __restrict__ dst, int d_ld,
                               int R, int Rs, int C, int flag, int raw16,
                               int c0, int r0, int tx, int ty,
                               u16 tile[32][33])
{
#pragma unroll
    for (int i = 0; i < 4; ++i) {
        int r = r0 + ty + i * 8, c = c0 + tx;
        if (r < R && c < C) {
            u16 v = 0;
            if (r < Rs) {
                size_t idx = (size_t)(sb + (long long)r * s_ld + c);
                v = raw16 ? ((const u16*)src_)[idx] : f2h_bits(ldin(src_, idx, flag));
            }
            tile[ty + i * 8][tx] = v;
        }
    }
    __syncthreads();
#pragma unroll
    for (int i = 0; i < 4; ++i) {
        int r = r0 + tx, c = c0 + ty + i * 8;
        if (r < R && c < C) dst[(long long)c * d_ld + r] = tile[tx][ty + i * 8];
    }
}

__global__ __launch_bounds__(256) void prep_k(
    const void* srcW, const void* srcB, const void* candW, const void* candB,
    const void* depW, const void* depB, const void* feasW, const void* feasB,
    const void* pW, const void* pb, const void* boi, const void* b1i, const void* b2i,
    const void* bq, const void* bk, const void* bv,
    const void* Wq, const void* Wk, const void* Wv, const void* Wo,
    const void* W1, const void* W2,
    const void* sol, const void* caps, const void* emb,
    float* __restrict__ arena, float* __restrict__ bqkvf,
    u16* __restrict__ wqkvT6, u16* __restrict__ woT6,
    u16* __restrict__ w1T6, u16* __restrict__ w2T6,
    u16* __restrict__ encW, u16* __restrict__ xin)
{
    __shared__ u16 tile[32][33];
    const int t = threadIdx.x;
    const int tx = t & 31, ty = t >> 5;
    const int flag = detect_bf16(caps);
    long long blk = blockIdx.x;

    if (blk < 1627) {  // ---- cvt_small ----
        int i = (int)blk * 256 + t;
        if (i >= A_TOTAL) return;
        const void* s; int j;
        if      (i < A_SRCB)  { s = srcW;  j = i - A_SRCW; }
        else if (i < A_CANDW) { s = srcB;  j = i - A_SRCB; }
        else if (i < A_CANDB) { s = candW; j = i - A_CANDW; }
        else if (i < A_DEPW)  { s = candB; j = i - A_CANDB; }
        else if (i < A_DEPB)  { s = depW;  j = i - A_DEPW; }
        else if (i < A_FEASW) { s = depB;  j = i - A_DEPB; }
        else if (i < A_FEASB) { s = feasW; j = i - A_FEASW; }
        else if (i < A_PW)    { s = feasB; j = i - A_FEASB; }
        else if (i < A_PB)    { s = pW;    j = i - A_PW; }
        else if (i < A_BO)    { s = pb;    j = i - A_PB; }
        else if (i < A_B1)    { s = boi;   j = i - A_BO; }
        else if (i < A_B2)    { s = b1i;   j = i - A_B1; }
        else                  { s = b2i;   j = i - A_B2; }
        arena[i] = ldin(s, j, flag);
        return;
    }
    blk -= 1627;
    if (blk < 36) {  // ---- catbias ----
        int tt = (int)blk * 256 + t;
        if (tt >= 6 * 1536) return;
        int l = tt / 1536, j = tt - l * 1536;
        float v = (j < 512) ? ldin(bq, l * 512 + j, flag)
                : (j < 1024) ? ldin(bk, l * 512 + j - 512, flag)
                             : ldin(bv, l * 512 + j - 1024, flag);
        bqkvf[tt] = v;
        return;
    }
    blk -= 36;
    if (blk < 6144) {  // ---- Wq/Wk/Wv/Wo transposes ----
        int z = (int)(blk >> 8);         // 0..23
        int rem = (int)(blk & 255);
        int bx = rem & 15, by = rem >> 4;
        int layer = z >> 2, sel = z & 3;
        const void* src = (sel == 0) ? Wq : (sel == 1) ? Wk : (sel == 2) ? Wv : Wo;
        u16* dst = (sel < 3) ? (wqkvT6 + (long long)layer * 786432 + (long long)sel * 262144)
                             : (woT6 + (long long)layer * 262144);
        tr_body(src, 512, (long long)layer * 262144, dst, 512,
                512, 512, 512, flag, 0, bx * 32, by * 32, tx, ty, tile);
        return;
    }
    blk -= 6144;
    if (blk < 6144) {  // ---- W1 transpose (grid 64x16x6) ----
        int z = (int)(blk / 1024);
        int rem = (int)(blk - (long long)z * 1024);
        int bx = rem & 63, by = rem >> 6;
        tr_body(W1, 2048, (long long)z * 1048576, w1T6 + (long long)z * 1048576, 512,
                512, 512, 2048, flag, 0, bx * 32, by * 32, tx, ty, tile);
        return;
    }
    blk -= 6144;
    if (blk < 6144) {  // ---- W2 transpose (grid 16x64x6) ----
        int z = (int)(blk / 1024);
        int rem = (int)(blk - (long long)z * 1024);
        int bx = rem & 15, by = rem >> 4;
        tr_body(W2, 512, (long long)z * 1048576, w2T6 + (long long)z * 1048576, 2048,
                2048, 2048, 512, flag, 0, bx * 32, by * 32, tx, ty, tile);
        return;
    }
    blk -= 6144;
    if (blk < 144) {  // ---- candW -> encW transpose (grid 16x9) ----
        int bx = (int)(blk & 15), by = (int)(blk >> 4);
        tr_body(candW, 512, 0, encW, 288,
                288, 257, 512, flag, 0, bx * 32, by * 32, tx, ty, tile);
        return;
    }
    blk -= 144;
    {  // ---- gather_xin (4096 rows) ----
        int row = (int)blk;
        int b = row >> 9, s = row & 511;
        float idxf = ldin(sol, (size_t)row * 4, flag);
        int idx = (int)(idxf + 0.5f);
        if (idx < 0) idx = 0;
        if (idx > 9999) idx = 9999;
        xin[(size_t)row * 288 + t] = f2h_bits(ldin(emb, (size_t)idx * 256 + t, flag));
        if (t < 32) {
            float v = 0.f;
            if (t == 0 && s != 0) {
                float rem = ldin(sol, ((size_t)b * 512) * 4 + 3, flag);
                float cap = ldin(caps, b, flag);
                float dem = ldin(sol, (size_t)row * 4 + 2, flag);
                v = 2.f * (dem - rem) / cap;
            }
            xin[(size_t)row * 288 + 256 + t] = f2h_bits(v);
        }
    }
}

__global__ __launch_bounds__(256) void fixup_enc_k(
    const void* __restrict__ sol, const void* __restrict__ caps, const void* __restrict__ emb,
    const float* __restrict__ arena, float* __restrict__ xf, u16* __restrict__ xb)
{
    const int blk = blockIdx.x;
    const int b = blk & 7;
    const int s = (blk >> 3) ? 511 : 0;
    const int row = b * 512 + s;
    const int t = threadIdx.x;
    __shared__ float e[256];
    __shared__ float nds;
    const int flag = detect_bf16(caps);
    float idxf = ldin(sol, (size_t)row * 4, flag);
    int idx = (int)(idxf + 0.5f);
    if (idx < 0) idx = 0;
    if (idx > 9999) idx = 9999;
    e[t] = ldin(emb, (size_t)idx * 256 + t, flag);
    if (t == 0) {
        float rem = ldin(sol, ((size_t)b * 512) * 4 + 3, flag);
        float cap = ldin(caps, b, flag);
        float dem = ldin(sol, (size_t)row * 4 + 2, flag);
        nds = (s == 0) ? 0.f : 2.f * (dem - rem) / cap;
    }
    __syncthreads();
    const float* W  = (s == 0) ? arena + A_SRCW : arena + A_DEPW;
    const float* Bb = (s == 0) ? arena + A_SRCB : arena + A_DEPB;
    float a0 = 0.f, a1 = 0.f;
    for (int c = 0; c < 256; ++c) {
        float ev = e[c];
        a0 += ev * W[(size_t)c * 512 + t];
        a1 += ev * W[(size_t)c * 512 + t + 256];
    }
    float nd = nds;
    a0 += nd * W[256 * 512 + t] + Bb[t];
    a1 += nd * W[256 * 512 + t + 256] + Bb[t + 256];
    size_t o = (size_t)row * 512;
    xf[o + t] = a0;        xb[o + t] = f2h_bits(a0);
    xf[o + t + 256] = a1;  xb[o + t + 256] = f2h_bits(a1);
}

__global__ __launch_bounds__(256) void feas_k(const float* __restrict__ xf,
                                              const float* __restrict__ arena,
                                              float* __restrict__ out)
{
    int w = blockIdx.x * 4 + (threadIdx.x >> 6);
    if (w >= 8 * 510) return;
    int lane = threadIdx.x & 63;
    int b = w / 510, j = w - b * 510;
    const float* xr = xf + ((size_t)(b * 512 + 1 + j)) * 512;
    const float* fW = arena + A_FEASW;
    float a = 0.f;
#pragma unroll
    for (int i = 0; i < 8; ++i) { int d = lane + 64 * i; a += xr[d] * fW[d]; }
#pragma unroll
    for (int o = 1; o < 64; o <<= 1) a += __shfl_xor(a, o, 64);
    if (lane == 0) out[8160 + b * 510 + j] = a + arena[A_FEASB];
}

__global__ __launch_bounds__(256) void ptr_k(const float* __restrict__ xf,
                                             const float* __restrict__ arena,
                                             float* __restrict__ out)
{
    int w = blockIdx.x * 4 + (threadIdx.x >> 6);
    if (w >= 8 * 510) return;
    int lane = threadIdx.x & 63;
    int b = w / 510, j = w - b * 510;
    const float* xr = xf + ((size_t)(b * 512 + 1 + j)) * 512;
    const float* pWa = arena + A_PW;
    float a0 = 0.f, a1 = 0.f;
#pragma unroll
    for (int i = 0; i < 8; ++i) {
        int d = lane + 64 * i;
        float x = xr[d];
        a0 += x * pWa[d * 2];
        a1 += x * pWa[d * 2 + 1];
    }
#pragma unroll
    for (int o = 1; o < 64; o <<= 1) { a0 += __shfl_xor(a0, o, 64); a1 += __shfl_xor(a1, o, 64); }
    if (lane == 0) {
        out[(size_t)b * 1020 + j]       = a0 + arena[A_PB];
        out[(size_t)b * 1020 + 510 + j] = a1 + arena[A_PB + 1];
    }
}

extern "C" void kernel_launch(void* const* d_in, const int* in_sizes, int n_in,
                              void* d_out, int out_size, void* d_ws, size_t ws_size,
                              hipStream_t stream)
{
    const void* sol   = d_in[0];
    const void* caps  = d_in[1];
    const void* emb   = d_in[2];
    const void* srcW  = d_in[3];
    const void* srcB  = d_in[4];
    const void* candW = d_in[5];
    const void* candB = d_in[6];
    const void* depW  = d_in[7];
    const void* depB  = d_in[8];
    const void* feasW = d_in[9];
    const void* feasB = d_in[10];
    const void* Wq  = d_in[11];
    const void* bq  = d_in[12];
    const void* Wk  = d_in[13];
    const void* bk  = d_in[14];
    const void* Wv  = d_in[15];
    const void* bv  = d_in[16];
    const void* Wo  = d_in[17];
    const void* boi = d_in[18];
    // d_in[19] = s_scale: softmax shift no-op
    const void* W1  = d_in[20];
    const void* b1i = d_in[21];
    const void* W2  = d_in[22];
    const void* b2i = d_in[23];
    const void* pW  = d_in[24];
    const void* pb  = d_in[25];
    float* out = (float*)d_out;

    // workspace
    char* w = (char*)d_ws;
    float* xf    = (float*)w; w += 8388608;   // 4096x512 fp32 residual master
    u16* xb      = (u16*)w;   w += 4194304;   // 4096x512 fp16
    u16* qkvb    = (u16*)w;   w += 12582912;  // 4096x1536 fp16 (q|k|v; v region unused)
    u16* vt      = (u16*)w;   w += 4194304;   // 64x64x512 fp16 (v^T per slice)
    u16* hb      = (u16*)w;   w += 16777216;  // 4096x2048 fp16 FFN hidden
    u16* xin     = hb;                        //  ALIAS: 4096x288 fp16 encoder input
    u16* encW    = hb + 4096 * 288;           //  ALIAS: 512x288 fp16 candW^T
    u16* ob      = (u16*)w;   w += 4194304;   // 4096x512 fp16 attention out
    u16* wqkvT6  = (u16*)w;   w += 9437184;   // 6x 1536x512 fp16
    u16* woT6    = (u16*)w;   w += 3145728;   // 6x 512x512 fp16
    u16* w1T6    = (u16*)w;   w += 12582912;  // 6x 2048x512 fp16
    u16* w2T6    = (u16*)w;   w += 12582912;  // 6x 512x2048 fp16
    float* bqkvf = (float*)w; w += 36864;     // 6x1536 fp32
    float* arena = (float*)w; w += A_TOTAL * 4;

    // ALL setup work (converts, 4 weight-transpose families, encoder gather)
    // in one dispatch: 1627+36+6144+6144+6144+144+4096 = 24335 blocks.
    prep_k<<<dim3(24335), 256, 0, stream>>>(
        srcW, srcB, candW, candB, depW, depB, feasW, feasB, pW, pb, boi, b1i, b2i,
        bq, bk, bv, Wq, Wk, Wv, Wo, W1, W2, sol, caps, emb,
        arena, bqkvf, wqkvT6, woT6, w1T6, w2T6, encW, xin);

    // Encoder via MFMA + 16-row fixup.
    gemm_f16<2, 64, 64, 32><<<dim3(8, 64), 256, 0, stream>>>(
        xin, 288, encW, 288,
        xb, 512, arena + A_CANDB, xf, nullptr, 1.f, 0, 512, 288);
    fixup_enc_k<<<dim3(16), 256, 0, stream>>>(sol, caps, emb, arena, xf, xb);

    for (int i = 0; i < 6; ++i) {
        // QKV projection; V columns stream directly into vt (fused transpose).
        // 64x64xBK128: 4 K-steps.
        gemm_f16<0, 64, 64, 128><<<dim3(24, 64), 256, 0, stream>>>(
            xb, 512, wqkvT6 + (long long)i * 786432, 512,
            qkvb, 1536, bqkvf + i * 1536, nullptr, vt, 1.f, 0, 1536, 512);

        // Fused attention: scores+softmax+PV in one dispatch, zero barriers.
        // 8 waves x 16 Q-rows (2 waves/SIMD TLP).
        flash_k<<<dim3(4, 64), 512, 0, stream>>>(qkvb, vt, ob);

        // Wo projection + residual into xf/xb. 4 K-steps.
        gemm_f16<0, 64, 64, 128><<<dim3(8, 64), 256, 0, stream>>>(
            ob, 512, woT6 + (long long)i * 262144, 512,
            xb, 512, arena + A_BO + i * 512, xf, nullptr, 1.f, 0, 512, 512);
        if (i == 0)
            feas_k<<<dim3(1020), 256, 0, stream>>>(xf, arena, out);

        // FFN1 (relu) -> hb: 128x128xBK64 (512 WGs, 2 resident/CU, 8 K-steps).
        gemm_f16<0, 128, 128, 64><<<dim3(16, 32), 256, 0, stream>>>(
            xb, 512, w1T6 + (long long)i * 1048576, 512,
            hb, 2048, arena + A_B1 + i * 2048, nullptr, nullptr, 1.f, 1, 2048, 512);

        // FFN2 full-K: 64x64xBK128 (16 K-steps, 2 resident/CU).
        gemm_f16<0, 64, 64, 128><<<dim3(8, 64), 256, 0, stream>>>(
            hb, 2048, w2T6 + (long long)i * 1048576, 2048,
            xb, 512, arena + A_B2 + i * 512, xf, nullptr, 1.f, 0, 512, 2048);
    }
    ptr_k<<<dim3(1020), 256, 0, stream>>>(xf, arena, out);
}

// Round 12
// 827.692 us; speedup vs baseline: 1.8363x; 1.0225x over previous
//
#include <hip/hip_runtime.h>

typedef unsigned short u16;
typedef _Float16 half8 __attribute__((ext_vector_type(8)));
typedef float f32x4 __attribute__((ext_vector_type(4)));
typedef unsigned short us8 __attribute__((ext_vector_type(8)));

__device__ inline float bf2f(u16 b) { return __builtin_bit_cast(float, ((unsigned)b) << 16); }
__device__ inline float h2f(u16 h) { return (float)__builtin_bit_cast(_Float16, h); }
__device__ inline u16 f2h_bits(float f) { return __builtin_bit_cast(u16, (_Float16)f); }

__device__ inline int detect_bf16(const void* caps) {
    const u16* c = (const u16*)caps;
    int cnt = 0;
#pragma unroll
    for (int k = 0; k < 4; ++k) {
        float v = bf2f(c[2 * k]);
        if (v >= 20.f && v <= 200.f) cnt++;
    }
    return cnt >= 2;
}
__device__ inline float ldin(const void* p, size_t i, int flag) {
    return flag ? bf2f(((const u16*)p)[i]) : ((const float*)p)[i];
}

#define GLOAD_LDS16(g, l)                                                              \
    __builtin_amdgcn_global_load_lds((__attribute__((address_space(1))) const void*)(g), \
                                     (__attribute__((address_space(3))) void*)(l), 16, 0, 0)

// Counted vmcnt wait + compiler memory fence (prevents ds_read hoisting).
template <int N>
__device__ inline void waitv() {
    if constexpr (N == 0)       asm volatile("s_waitcnt vmcnt(0)" ::: "memory");
    else if constexpr (N == 2)  asm volatile("s_waitcnt vmcnt(2)" ::: "memory");
    else if constexpr (N == 4)  asm volatile("s_waitcnt vmcnt(4)" ::: "memory");
    else if constexpr (N == 6)  asm volatile("s_waitcnt vmcnt(6)" ::: "memory");
    else if constexpr (N == 8)  asm volatile("s_waitcnt vmcnt(8)" ::: "memory");
    else if constexpr (N == 12) asm volatile("s_waitcnt vmcnt(12)" ::: "memory");
}
__device__ inline void barrier_raw() {
    asm volatile("" ::: "memory");
    __builtin_amdgcn_s_barrier();
    asm volatile("" ::: "memory");
}

#define A_SRCW 0
#define A_SRCB 131584
#define A_CANDW 132096
#define A_CANDB 263680
#define A_DEPW 264192
#define A_DEPB 395776
#define A_FEASW 396288
#define A_FEASB 396800
#define A_PW 396801
#define A_PB 397825
#define A_BO 397827
#define A_B1 400899
#define A_B2 413187
#define A_TOTAL 416259

// ---------------------------------------------------------------------------
// GEMM with templated BM x BN x BK (unchanged from R9 — at model optimum).
// ---------------------------------------------------------------------------
template <int CF, int BM, int BN, int BK>
__global__ __launch_bounds__(256) void gemm_f16(
    const u16* __restrict__ A, int lda,
    const u16* __restrict__ B, int ldb,
    void* __restrict__ Cv, int ldc,
    const float* __restrict__ bias, float* __restrict__ resid,
    u16* __restrict__ vtp,
    float scale, int relu, int N, int K)
{
    constexpr int MT = BM / 32;
    constexpr int NT = BN / 32;
    constexpr int CPR = BK / 8;
    constexpr int S = (BM / 64 + BN / 64) * (BK / 32);
    __shared__ __attribute__((aligned(16))) u16 As[2][BM * BK];
    __shared__ __attribute__((aligned(16))) u16 Bs[2][BN * BK];

    const int gx = gridDim.x, gy = gridDim.y;
    int mb, nb;
    if ((gy & 7) == 0) {
        int id = blockIdx.x + blockIdx.y * gx;
        int xcd = id & 7, local = id >> 3;
        int mloc = local / gx;
        mb = xcd * (gy >> 3) + mloc;
        nb = local - mloc * gx;
    } else {
        mb = blockIdx.y;
        nb = blockIdx.x;
    }
    const int m0 = mb * BM;
    const int n0 = nb * BN;

    const int t = threadIdx.x, lane = t & 63, wid = t >> 6;
    const int qd = lane >> 4, ml = lane & 15;
    const int wm = (wid >> 1) * (BM / 2), wn = (wid & 1) * (BN / 2);

    f32x4 acc[MT][NT] = {};

    auto stage = [&](int bf, int k0) {
#pragma unroll
        for (int r = 0; r < BM * BK / 2048; ++r) {
            int seg = r * 256 + t;
            int row = seg / CPR;
            int chunk = seg & (CPR - 1);
            int c8 = ((chunk ^ (row & (CPR - 1))) * 8);
            const u16* ga = A + (long long)(m0 + row) * lda + k0 + c8;
            GLOAD_LDS16(ga, As[bf] + (size_t)(seg & ~63) * 8);
        }
#pragma unroll
        for (int r = 0; r < BN * BK / 2048; ++r) {
            int seg = r * 256 + t;
            int row = seg / CPR;
            int chunk = seg & (CPR - 1);
            int c8 = ((chunk ^ (row & (CPR - 1))) * 8);
            int rn = n0 + row;
            if (rn > N - 1) rn = N - 1;
            const u16* gb = B + (long long)rn * ldb + k0 + c8;
            GLOAD_LDS16(gb, Bs[bf] + (size_t)(seg & ~63) * 8);
        }
    };

    auto compute = [&](int bf) {
#pragma unroll
        for (int kk = 0; kk < BK / 32; ++kk) {
            half8 af[MT], bfv[NT];
#pragma unroll
            for (int mt = 0; mt < MT; ++mt) {
                int row = wm + mt * 16 + ml;
                int c = (kk * 4 + qd) ^ (row & (CPR - 1));
                af[mt] = *(const half8*)(As[bf] + (size_t)row * BK + c * 8);
            }
#pragma unroll
            for (int nt = 0; nt < NT; ++nt) {
                int row = wn + nt * 16 + ml;
                int c = (kk * 4 + qd) ^ (row & (CPR - 1));
                bfv[nt] = *(const half8*)(Bs[bf] + (size_t)row * BK + c * 8);
            }
#pragma unroll
            for (int mt = 0; mt < MT; ++mt)
#pragma unroll
                for (int nt = 0; nt < NT; ++nt)
                    acc[mt][nt] = __builtin_amdgcn_mfma_f32_16x16x32_f16(af[mt], bfv[nt], acc[mt][nt], 0, 0, 0);
        }
    };

    stage(0, 0);

    int buf = 0;
    for (int k0 = 0; k0 < K; k0 += BK) {
        if (k0 > 0) barrier_raw();
        if (k0 + BK < K) {
            stage(buf ^ 1, k0 + BK);
            waitv<S>();
        } else {
            waitv<0>();
        }
        barrier_raw();
        compute(buf);
        buf ^= 1;
    }

#pragma unroll
    for (int nt = 0; nt < NT; ++nt) {
        int col = n0 + wn + nt * 16 + ml;
        if (col >= N) continue;
        float bv = bias ? bias[col] : 0.f;
#pragma unroll
        for (int mt = 0; mt < MT; ++mt) {
#pragma unroll
            for (int r = 0; r < 4; ++r) {
                int rowg = m0 + wm + mt * 16 + qd * 4 + r;
                float v = acc[mt][nt][r] * scale + bv;
                if (relu) v = fmaxf(v, 0.f);
                long long off = (long long)rowg * ldc + col;
                if (CF == 1) {
                    ((float*)Cv)[off] = v;
                } else if (CF == 2) {
                    resid[off] = v;
                    ((u16*)Cv)[off] = f2h_bits(v);
                } else if (resid) {
                    float nv = resid[off] + v;
                    resid[off] = nv;
                    ((u16*)Cv)[off] = f2h_bits(nv);
                } else if (vtp && col >= 1024) {
                    int b = rowg >> 9, s = rowg & 511;
                    int cv2 = col - 1024;
                    vtp[(size_t)(((b << 3) + (cv2 >> 6)) * 32768 + (cv2 & 63) * 512 + s)] = f2h_bits(v);
                } else {
                    ((u16*)Cv)[off] = f2h_bits(v);
                }
            }
        }
    }
}

// ---------------------------------------------------------------------------
// Fused flash attention, 8 waves x 16 Q-rows over a 128-row tile (R10).
// ---------------------------------------------------------------------------
__global__ __launch_bounds__(512) void flash_k(
    const u16* __restrict__ qkv,
    const u16* __restrict__ vt,
    u16* __restrict__ ob)
{
    __shared__ __attribute__((aligned(16))) u16 Ps[128 * 136];

    int id = blockIdx.x + (blockIdx.y << 2);
    int xcd = id & 7, local = id >> 3;
    const int z = (xcd << 3) + (local >> 2);
    const int q0 = (local & 3) * 128;

    const int b = z >> 3, h = z & 7;
    const long long qbase = (long long)b * 786432;
    const u16* Q  = qkv + qbase + (long long)q0 * 1536 + h * 64;
    const u16* Kg = qkv + qbase + 512 + h * 64;
    const u16* Vg = vt + (long long)z * 32768;

    const int t = threadIdx.x, lane = t & 63, wid = t >> 6;
    const int qd = lane >> 4, ml = lane & 15;
    const int wm = wid * 16;

    half8 qf[2];
#pragma unroll
    for (int kf = 0; kf < 2; ++kf)
        qf[kf] = *(const half8*)(Q + (long long)(wm + ml) * 1536 + kf * 32 + qd * 8);

    f32x4 oacc[4] = {};
    float mrow[4], lrow[4];
#pragma unroll
    for (int r = 0; r < 4; ++r) { mrow[r] = -3.0e38f; lrow[r] = 0.f; }

    for (int kb = 0; kb < 4; ++kb) {
        f32x4 sacc[8] = {};
        __builtin_amdgcn_s_setprio(1);
#pragma unroll
        for (int nt = 0; nt < 8; ++nt) {
#pragma unroll
            for (int kf = 0; kf < 2; ++kf) {
                half8 bf = *(const half8*)(Kg + (long long)(kb * 128 + nt * 16 + ml) * 1536 + kf * 32 + qd * 8);
                sacc[nt] = __builtin_amdgcn_mfma_f32_16x16x32_f16(qf[kf], bf, sacc[nt], 0, 0, 0);
            }
        }
        __builtin_amdgcn_s_setprio(0);
#pragma unroll
        for (int r = 0; r < 4; ++r) {
            float mx = -3.0e38f;
#pragma unroll
            for (int nt = 0; nt < 8; ++nt) {
                float s = sacc[nt][r] * 0.125f;
                sacc[nt][r] = s;
                mx = fmaxf(mx, s);
            }
#pragma unroll
            for (int o = 1; o < 16; o <<= 1) mx = fmaxf(mx, __shfl_xor(mx, o, 64));
            float mnew = fmaxf(mrow[r], mx);
            float alpha = __expf(mrow[r] - mnew);
            mrow[r] = mnew;
            lrow[r] *= alpha;
#pragma unroll
            for (int nt = 0; nt < 4; ++nt) oacc[nt][r] *= alpha;
            float ps = 0.f;
#pragma unroll
            for (int nt = 0; nt < 8; ++nt) {
                float p = __expf(sacc[nt][r] - mnew);
                sacc[nt][r] = p;
                ps += p;
            }
#pragma unroll
            for (int o = 1; o < 16; o <<= 1) ps += __shfl_xor(ps, o, 64);
            lrow[r] += ps;
        }
#pragma unroll
        for (int nt = 0; nt < 8; ++nt)
#pragma unroll
            for (int r = 0; r < 4; ++r)
                Ps[(wm + qd * 4 + r) * 136 + nt * 16 + ml] = f2h_bits(sacc[nt][r]);
        __builtin_amdgcn_s_setprio(1);
#pragma unroll
        for (int kf = 0; kf < 4; ++kf) {
            half8 pf = *(const half8*)(Ps + (wm + ml) * 136 + kf * 32 + qd * 8);
#pragma unroll
            for (int nt = 0; nt < 4; ++nt) {
                half8 vf = *(const half8*)(Vg + (long long)(nt * 16 + ml) * 512 + kb * 128 + kf * 32 + qd * 8);
                oacc[nt] = __builtin_amdgcn_mfma_f32_16x16x32_f16(pf, vf, oacc[nt], 0, 0, 0);
            }
        }
        __builtin_amdgcn_s_setprio(0);
    }

#pragma unroll
    for (int r = 0; r < 4; ++r) {
        float inv = 1.f / lrow[r];
        long long rowg = (long long)b * 512 + q0 + wm + qd * 4 + r;
#pragma unroll
        for (int nt = 0; nt < 4; ++nt)
            ob[rowg * 512 + h * 64 + nt * 16 + ml] = f2h_bits(oacc[nt][r] * inv);
    }
}

// ---------------------------------------------------------------------------
// Vectorized 64x64 transpose tile body (R12): 16 B/lane global loads
// (ushort8 bf16 / float4 fp32), LDS staging [64][72] (b128-aligned rows,
// bank-balanced writes), diagonal-rotated column gather (jj = (j+t&7)&7
// -> 32 distinct banks per read instruction = conflict-free), 16 B/lane
// coalesced ushort8 global writes.
// ---------------------------------------------------------------------------
__device__ inline void tr64(const void* src_, int s_ld, long long sb,
                            u16* __restrict__ dst, int d_ld,
                            int R, int Rs, int C,
                            int flag, int c0, int r0, int t,
                            u16 (*tile)[72])
{
    if (flag) {  // bf16 source: 2 x ushort8 per thread
#pragma unroll
        for (int p = 0; p < 2; ++p) {
            int ch = t + p * 256;
            int row = ch >> 3, c8 = (ch & 7) * 8;
            int r = r0 + row;
            us8 v = {0, 0, 0, 0, 0, 0, 0, 0};
            if (r < Rs)
                v = *(const us8*)((const u16*)src_ + sb + (long long)r * s_ld + c0 + c8);
            u16* d = &tile[row][c8];
#pragma unroll
            for (int j = 0; j < 8; ++j) d[j] = f2h_bits(bf2f(v[j]));
        }
    } else {     // fp32 source: 4 x float4 per thread
#pragma unroll
        for (int p = 0; p < 4; ++p) {
            int q = t + p * 256;
            int row = q >> 4, c4 = (q & 15) * 4;
            int r = r0 + row;
            f32x4 v = {0.f, 0.f, 0.f, 0.f};
            if (r < Rs)
                v = *(const f32x4*)((const float*)src_ + sb + (long long)r * s_ld + c0 + c4);
            u16* d = &tile[row][c4];
#pragma unroll
            for (int j = 0; j < 4; ++j) d[j] = f2h_bits(v[j]);
        }
    }
    __syncthreads();
    const int m = t & 7;
#pragma unroll
    for (int p = 0; p < 2; ++p) {
        int ch = t + p * 256;
        int oc = ch >> 3, o8 = (ch & 7) * 8;
        if (r0 + o8 >= R) continue;   // (chunks are 8-aligned; R % 8 == 0 for all uses)
        u16 vv[8];
#pragma unroll
        for (int j = 0; j < 8; ++j) {
            int jj = (j + m) & 7;     // diagonal order: conflict-free column gather
            vv[jj] = tile[o8 + jj][oc];
        }
        us8 ov;
#pragma unroll
        for (int j = 0; j < 8; ++j) ov[j] = vv[j];
        *(us8*)(dst + (long long)(c0 + oc) * d_ld + r0 + o8) = ov;
    }
}

// ---------------------------------------------------------------------------
// prep_k: ALL setup work in ONE dispatch. 64x64 vectorized transposes.
//   [0,1627)        cvt_small  (arena fp32)
//   [1627,1663)     catbias    (bqkvf)
//   [1663,3199)     Wq/Wk/Wv/Wo transpose  (24 z x 8x8 tiles)
//   [3199,4735)     W1 transpose           (6 z x 8x32)
//   [4735,6271)     W2 transpose           (6 z x 32x8)
//   [6271,6311)     candW -> encW          (5x8)
//   [6311,10407)    gather_xin (4096 rows)
// ---------------------------------------------------------------------------
__global__ __launch_bounds__(256) void prep_k(
    const void* srcW, const void* srcB, const void* candW, const void* candB,
    const void* depW, const void* depB, const void* feasW, const void* feasB,
    const void* pW, const void* pb, const void* boi, const void* b1i, const void* b2i,
    const void* bq, const void* bk, const void* bv,
    const void* Wq, const void* Wk, const void* Wv, const void* Wo,
    const void* W1, const void* W2,
    const void* sol, const void* caps, const void* emb,
    float* __restrict__ arena, float* __restrict__ bqkvf,
    u16* __restrict__ wqkvT6, u16* __restrict__ woT6,
    u16* __restrict__ w1T6, u16* __restrict__ w2T6,
    u16* __restrict__ encW, u16* __restrict__ xin)
{
    __shared__ u16 tile[64][72];
    const int t = threadIdx.x;
    const int flag = detect_bf16(caps);
    long long blk = blockIdx.x;

    if (blk < 1627) {  // ---- cvt_small ----
        int i = (int)blk * 256 + t;
        if (i >= A_TOTAL) return;
        const void* s; int j;
        if      (i < A_SRCB)  { s = srcW;  j = i - A_SRCW; }
        else if (i < A_CANDW) { s = srcB;  j = i - A_SRCB; }
        else if (i < A_CANDB) { s = candW; j = i - A_CANDW; }
        else if (i < A_DEPW)  { s = candB; j = i - A_CANDB; }
        else if (i < A_DEPB)  { s = depW;  j = i - A_DEPW; }
        else if (i < A_FEASW) { s = depB;  j = i - A_DEPB; }
        else if (i < A_FEASB) { s = feasW; j = i - A_FEASW; }
        else if (i < A_PW)    { s = feasB; j = i - A_FEASB; }
        else if (i < A_PB)    { s = pW;    j = i - A_PW; }
        else if (i < A_BO)    { s = pb;    j = i - A_PB; }
        else if (i < A_B1)    { s = boi;   j = i - A_BO; }
        else if (i < A_B2)    { s = b1i;   j = i - A_B1; }
        else                  { s = b2i;   j = i - A_B2; }
        arena[i] = ldin(s, j, flag);
        return;
    }
    blk -= 1627;
    if (blk < 36) {  // ---- catbias ----
        int tt = (int)blk * 256 + t;
        if (tt >= 6 * 1536) return;
        int l = tt / 1536, j = tt - l * 1536;
        float v = (j < 512) ? ldin(bq, l * 512 + j, flag)
                : (j < 1024) ? ldin(bk, l * 512 + j - 512, flag)
                             : ldin(bv, l * 512 + j - 1024, flag);
        bqkvf[tt] = v;
        return;
    }
    blk -= 36;
    if (blk < 1536) {  // ---- Wq/Wk/Wv/Wo transposes (24 z x 64 tiles) ----
        int z = (int)(blk >> 6);
        int rem = (int)(blk & 63);
        int bx = rem & 7, by = rem >> 3;
        int layer = z >> 2, sel = z & 3;
        const void* src = (sel == 0) ? Wq : (sel == 1) ? Wk : (sel == 2) ? Wv : Wo;
        u16* dst = (sel < 3) ? (wqkvT6 + (long long)layer * 786432 + (long long)sel * 262144)
                             : (woT6 + (long long)layer * 262144);
        tr64(src, 512, (long long)layer * 262144, dst, 512,
             512, 512, 512, flag, bx * 64, by * 64, t, tile);
        return;
    }
    blk -= 1536;
    if (blk < 1536) {  // ---- W1 transpose (6 z x 8 by x 32 bx) ----
        int z = (int)(blk >> 8);
        int rem = (int)(blk & 255);
        int bx = rem & 31, by = rem >> 5;
        tr64(W1, 2048, (long long)z * 1048576, w1T6 + (long long)z * 1048576, 512,
             512, 512, 2048, flag, bx * 64, by * 64, t, tile);
        return;
    }
    blk -= 1536;
    if (blk < 1536) {  // ---- W2 transpose (6 z x 32 by x 8 bx) ----
        int z = (int)(blk >> 8);
        int rem = (int)(blk & 255);
        int bx = rem & 7, by = rem >> 3;
        tr64(W2, 512, (long long)z * 1048576, w2T6 + (long long)z * 1048576, 2048,
             2048, 2048, 512, flag, bx * 64, by * 64, t, tile);
        return;
    }
    blk -= 1536;
    if (blk < 40) {  // ---- candW -> encW transpose (5 by x 8 bx) ----
        int bx = (int)(blk & 7), by = (int)(blk >> 3);
        tr64(candW, 512, 0, encW, 288,
             288, 257, 512, flag, bx * 64, by * 64, t, tile);
        return;
    }
    blk -= 40;
    {  // ---- gather_xin (4096 rows) ----
        int row = (int)blk;
        int b = row >> 9, s = row & 511;
        float idxf = ldin(sol, (size_t)row * 4, flag);
        int idx = (int)(idxf + 0.5f);
        if (idx < 0) idx = 0;
        if (idx > 9999) idx = 9999;
        xin[(size_t)row * 288 + t] = f2h_bits(ldin(emb, (size_t)idx * 256 + t, flag));
        if (t < 32) {
            float v = 0.f;
            if (t == 0 && s != 0) {
                float rem = ldin(sol, ((size_t)b * 512) * 4 + 3, flag);
                float cap = ldin(caps, b, flag);
                float dem = ldin(sol, (size_t)row * 4 + 2, flag);
                v = 2.f * (dem - rem) / cap;
            }
            xin[(size_t)row * 288 + 256 + t] = f2h_bits(v);
        }
    }
}

__global__ __launch_bounds__(256) void fixup_enc_k(
    const void* __restrict__ sol, const void* __restrict__ caps, const void* __restrict__ emb,
    const float* __restrict__ arena, float* __restrict__ xf, u16* __restrict__ xb)
{
    const int blk = blockIdx.x;
    const int b = blk & 7;
    const int s = (blk >> 3) ? 511 : 0;
    const int row = b * 512 + s;
    const int t = threadIdx.x;
    __shared__ float e[256];
    __shared__ float nds;
    const int flag = detect_bf16(caps);
    float idxf = ldin(sol, (size_t)row * 4, flag);
    int idx = (int)(idxf + 0.5f);
    if (idx < 0) idx = 0;
    if (idx > 9999) idx = 9999;
    e[t] = ldin(emb, (size_t)idx * 256 + t, flag);
    if (t == 0) {
        float rem = ldin(sol, ((size_t)b * 512) * 4 + 3, flag);
        float cap = ldin(caps, b, flag);
        float dem = ldin(sol, (size_t)row * 4 + 2, flag);
        nds = (s == 0) ? 0.f : 2.f * (dem - rem) / cap;
    }
    __syncthreads();
    const float* W  = (s == 0) ? arena + A_SRCW : arena + A_DEPW;
    const float* Bb = (s == 0) ? arena + A_SRCB : arena + A_DEPB;
    float a0 = 0.f, a1 = 0.f;
    for (int c = 0; c < 256; ++c) {
        float ev = e[c];
        a0 += ev * W[(size_t)c * 512 + t];
        a1 += ev * W[(size_t)c * 512 + t + 256];
    }
    float nd = nds;
    a0 += nd * W[256 * 512 + t] + Bb[t];
    a1 += nd * W[256 * 512 + t + 256] + Bb[t + 256];
    size_t o = (size_t)row * 512;
    xf[o + t] = a0;        xb[o + t] = f2h_bits(a0);
    xf[o + t + 256] = a1;  xb[o + t + 256] = f2h_bits(a1);
}

__global__ __launch_bounds__(256) void feas_k(const float* __restrict__ xf,
                                              const float* __restrict__ arena,
                                              float* __restrict__ out)
{
    int w = blockIdx.x * 4 + (threadIdx.x >> 6);
    if (w >= 8 * 510) return;
    int lane = threadIdx.x & 63;
    int b = w / 510, j = w - b * 510;
    const float* xr = xf + ((size_t)(b * 512 + 1 + j)) * 512;
    const float* fW = arena + A_FEASW;
    float a = 0.f;
#pragma unroll
    for (int i = 0; i < 8; ++i) { int d = lane + 64 * i; a += xr[d] * fW[d]; }
#pragma unroll
    for (int o = 1; o < 64; o <<= 1) a += __shfl_xor(a, o, 64);
    if (lane == 0) out[8160 + b * 510 + j] = a + arena[A_FEASB];
}

__global__ __launch_bounds__(256) void ptr_k(const float* __restrict__ xf,
                                             const float* __restrict__ arena,
                                             float* __restrict__ out)
{
    int w = blockIdx.x * 4 + (threadIdx.x >> 6);
    if (w >= 8 * 510) return;
    int lane = threadIdx.x & 63;
    int b = w / 510, j = w - b * 510;
    const float* xr = xf + ((size_t)(b * 512 + 1 + j)) * 512;
    const float* pWa = arena + A_PW;
    float a0 = 0.f, a1 = 0.f;
#pragma unroll
    for (int i = 0; i < 8; ++i) {
        int d = lane + 64 * i;
        float x = xr[d];
        a0 += x * pWa[d * 2];
        a1 += x * pWa[d * 2 + 1];
    }
#pragma unroll
    for (int o = 1; o < 64; o <<= 1) { a0 += __shfl_xor(a0, o, 64); a1 += __shfl_xor(a1, o, 64); }
    if (lane == 0) {
        out[(size_t)b * 1020 + j]       = a0 + arena[A_PB];
        out[(size_t)b * 1020 + 510 + j] = a1 + arena[A_PB + 1];
    }
}

extern "C" void kernel_launch(void* const* d_in, const int* in_sizes, int n_in,
                              void* d_out, int out_size, void* d_ws, size_t ws_size,
                              hipStream_t stream)
{
    const void* sol   = d_in[0];
    const void* caps  = d_in[1];
    const void* emb   = d_in[2];
    const void* srcW  = d_in[3];
    const void* srcB  = d_in[4];
    const void* candW = d_in[5];
    const void* candB = d_in[6];
    const void* depW  = d_in[7];
    const void* depB  = d_in[8];
    const void* feasW = d_in[9];
    const void* feasB = d_in[10];
    const void* Wq  = d_in[11];
    const void* bq  = d_in[12];
    const void* Wk  = d_in[13];
    const void* bk  = d_in[14];
    const void* Wv  = d_in[15];
    const void* bv  = d_in[16];
    const void* Wo  = d_in[17];
    const void* boi = d_in[18];
    // d_in[19] = s_scale: softmax shift no-op
    const void* W1  = d_in[20];
    const void* b1i = d_in[21];
    const void* W2  = d_in[22];
    const void* b2i = d_in[23];
    const void* pW  = d_in[24];
    const void* pb  = d_in[25];
    float* out = (float*)d_out;

    // workspace
    char* w = (char*)d_ws;
    float* xf    = (float*)w; w += 8388608;   // 4096x512 fp32 residual master
    u16* xb      = (u16*)w;   w += 4194304;   // 4096x512 fp16
    u16* qkvb    = (u16*)w;   w += 12582912;  // 4096x1536 fp16 (q|k|v; v region unused)
    u16* vt      = (u16*)w;   w += 4194304;   // 64x64x512 fp16 (v^T per slice)
    u16* hb      = (u16*)w;   w += 16777216;  // 4096x2048 fp16 FFN hidden
    u16* xin     = hb;                        //  ALIAS: 4096x288 fp16 encoder input
    u16* encW    = hb + 4096 * 288;           //  ALIAS: 512x288 fp16 candW^T
    u16* ob      = (u16*)w;   w += 4194304;   // 4096x512 fp16 attention out
    u16* wqkvT6  = (u16*)w;   w += 9437184;   // 6x 1536x512 fp16
    u16* woT6    = (u16*)w;   w += 3145728;   // 6x 512x512 fp16
    u16* w1T6    = (u16*)w;   w += 12582912;  // 6x 2048x512 fp16
    u16* w2T6    = (u16*)w;   w += 12582912;  // 6x 512x2048 fp16
    float* bqkvf = (float*)w; w += 36864;     // 6x1536 fp32
    float* arena = (float*)w; w += A_TOTAL * 4;

    // ALL setup work in one dispatch: 1627+36+1536+1536+1536+40+4096 = 10407.
    prep_k<<<dim3(10407), 256, 0, stream>>>(
        srcW, srcB, candW, candB, depW, depB, feasW, feasB, pW, pb, boi, b1i, b2i,
        bq, bk, bv, Wq, Wk, Wv, Wo, W1, W2, sol, caps, emb,
        arena, bqkvf, wqkvT6, woT6, w1T6, w2T6, encW, xin);

    // Encoder via MFMA + 16-row fixup.
    gemm_f16<2, 64, 64, 32><<<dim3(8, 64), 256, 0, stream>>>(
        xin, 288, encW, 288,
        xb, 512, arena + A_CANDB, xf, nullptr, 1.f, 0, 512, 288);
    fixup_enc_k<<<dim3(16), 256, 0, stream>>>(sol, caps, emb, arena, xf, xb);

    for (int i = 0; i < 6; ++i) {
        // QKV projection; V columns stream directly into vt (fused transpose).
        gemm_f16<0, 64, 64, 128><<<dim3(24, 64), 256, 0, stream>>>(
            xb, 512, wqkvT6 + (long long)i * 786432, 512,
            qkvb, 1536, bqkvf + i * 1536, nullptr, vt, 1.f, 0, 1536, 512);

        // Fused attention: 8 waves x 16 Q-rows.
        flash_k<<<dim3(4, 64), 512, 0, stream>>>(qkvb, vt, ob);

        // Wo projection + residual into xf/xb.
        gemm_f16<0, 64, 64, 128><<<dim3(8, 64), 256, 0, stream>>>(
            ob, 512, woT6 + (long long)i * 262144, 512,
            xb, 512, arena + A_BO + i * 512, xf, nullptr, 1.f, 0, 512, 512);
        if (i == 0)
            feas_k<<<dim3(1020), 256, 0, stream>>>(xf, arena, out);

        // FFN1 (relu) -> hb.
        gemm_f16<0, 128, 128, 64><<<dim3(16, 32), 256, 0, stream>>>(
            xb, 512, w1T6 + (long long)i * 1048576, 512,
            hb, 2048, arena + A_B1 + i * 2048, nullptr, nullptr, 1.f, 1, 2048, 512);

        // FFN2 full-K.
        gemm_f16<0, 64, 64, 128><<<dim3(8, 64), 256, 0, stream>>>(
            hb, 2048, w2T6 + (long long)i * 1048576, 2048,
            xb, 512, arena + A_B2 + i * 512, xf, nullptr, 1.f, 0, 512, 2048);
    }
    ptr_k<<<dim3(1020), 256, 0, stream>>>(xf, arena, out);
}